// Round 1
// baseline (2940.880 us; speedup 1.0000x reference)
//
#include <hip/hip_runtime.h>
#include <stdint.h>

#pragma clang fp contract(off)

typedef unsigned int u32;
typedef unsigned short u16;
typedef unsigned long long u64;
typedef float f32x4 __attribute__((ext_vector_type(4)));
typedef u16 u16x8 __attribute__((ext_vector_type(8)));

#define DEV __device__ __forceinline__

DEV float bf2f(u16 u){ union{u32 i; float f;} v; v.i=((u32)u)<<16; return v.f; }
DEV u16 f2bf(float f){ union{float f; u32 i;} v; v.f=f; u32 b=v.i; return (u16)((b + 0x7fffu + ((b>>16)&1u))>>16); }
DEV u32 fkey(float f){ union{float f; u32 i;} v; v.f=f; u32 b=v.i; return (b&0x80000000u)? ~b : (b|0x80000000u); }
DEV float exp_cr(float x){ return (float)exp((double)x); }

DEV void mfma16(f32x4& d, u16x8 a, u16x8 b){
  asm volatile("v_mfma_f32_16x16x32_bf16 %0, %1, %2, %0" : "+v"(d) : "v"(a), "v"(b));
}

// ---------------- RPN: softmax score + decode + clip + filter + histogram ----------------
__global__ void k_rpn(const float* __restrict__ logits, const float* __restrict__ deltas,
                      const float* __restrict__ anchors, float* __restrict__ scores,
                      float* __restrict__ rois_all, u32* __restrict__ hist){
  int i=blockIdx.x*256+threadIdx.x;
  if(i>=144000) return;
  float l0=logits[2*i], l1=logits[2*i+1];
  float m=fmaxf(l0,l1);
  float e0=exp_cr(l0-m), e1=exp_cr(l1-m);
  float s=e1/(e0+e1);
  float a0=anchors[4*i],a1=anchors[4*i+1],a2=anchors[4*i+2],a3=anchors[4*i+3];
  float w=a2-a0, hh=a3-a1;
  float cx=a0+0.5f*w, cy=a1+0.5f*hh;
  float dx=deltas[4*i],dy=deltas[4*i+1],dwv=deltas[4*i+2],dhv=deltas[4*i+3];
  float pcx=dx*w+cx, pcy=dy*hh+cy;
  float pw=w*exp_cr(fminf(dwv,4.f)), ph=hh*exp_cr(fminf(dhv,4.f));
  float x1=fminf(fmaxf(pcx-0.5f*pw,0.f),2560.f);
  float y1=fminf(fmaxf(pcy-0.5f*ph,0.f),1600.f);
  float x2=fminf(fmaxf(pcx+0.5f*pw,0.f),2560.f);
  float y2=fminf(fmaxf(pcy+0.5f*ph,0.f),1600.f);
  float4 bb; bb.x=x1;bb.y=y1;bb.z=x2;bb.w=y2;
  *(float4*)(rois_all+4*i)=bb;
  bool ok=(x2-x1>=16.f)&&(y2-y1>=16.f);
  float sc=ok? s : -INFINITY;
  scores[i]=sc;
  if(ok) atomicAdd(&hist[fkey(sc)>>16],1u);
}

// ---------------- find 6000th-rank histogram bin ----------------
__global__ void k_findbin(const u32* __restrict__ hist, u32* __restrict__ cnt){
  __shared__ u32 cs[1024];
  int t=threadIdx.x;
  u32 s=0;
  for(int b=0;b<64;b++) s+=hist[t*64+b];
  cs[t]=s;
  __syncthreads();
  if(t==0){
    u32 acc=0; int tc=1023;
    for(; tc>=0; tc--){ if(acc+cs[tc]>=6000u) break; acc+=cs[tc]; }
    if(tc<0) tc=0;
    u32 B=(u32)tc*64u;
    for(int b=63;b>=0;b--){
      u32 hb=hist[tc*64+b];
      if(acc+hb>=6000u){ B=(u32)(tc*64+b); break; }
      acc+=hb;
    }
    cnt[2]=B;
  }
}

__global__ void k_compact(const float* __restrict__ scores, u32* __restrict__ cnt, u64* __restrict__ keys){
  int i=blockIdx.x*256+threadIdx.x;
  if(i>=144000) return;
  u32 u=fkey(scores[i]);
  if((u>>16) >= cnt[2]){
    u32 pos=atomicAdd(&cnt[0],1u);
    if(pos<8192u) keys[pos]=((u64)u<<32)|(u64)(~(u32)i);
  }
}

// ---------------- single-block bitonic sort (8192, descending), emit top-6000 indices ----------------
template<bool FROMCNT>
__global__ __launch_bounds__(1024) void k_sort8k(const u64* __restrict__ keys, const u32* __restrict__ cnt,
                                                 int n_fixed, u32* __restrict__ out_idx){
  __shared__ u64 K[8192];
  int n = FROMCNT ? (int)cnt[0] : n_fixed;
  if(n>8192) n=8192;
  for(int i=threadIdx.x;i<8192;i+=1024) K[i]=(i<n)? keys[i] : 0ull;
  __syncthreads();
  for(int k=2;k<=8192;k<<=1){
    for(int j=k>>1;j>0;j>>=1){
      for(int t=threadIdx.x;t<8192;t+=1024){
        int p=t^j;
        if(p>t){
          u64 a=K[t], b=K[p];
          bool up=((t&k)==0);
          if((a<b)==up){ K[t]=b; K[p]=a; }
        }
      }
      __syncthreads();
    }
  }
  for(int i=threadIdx.x;i<6000;i+=1024) out_idx[i]=~((u32)K[i]);
}

__global__ void k_gather6k(const u32* __restrict__ selidx, const float* __restrict__ rois_all,
                           float* __restrict__ boxes6k){
  int i=blockIdx.x*256+threadIdx.x;
  if(i>=6000) return;
  u32 g=selidx[i];
  float4 b=*(const float4*)(rois_all+4*g);
  *(float4*)(boxes6k+4*i)=b;
}

// ---------------- NMS bitmask build (grid-stride over row-words) ----------------
__global__ void k_masks(const float* __restrict__ boxes, const u32* __restrict__ limitPtr, int limitFixed,
                        float thresh, u64* __restrict__ masks){
  int limit = limitPtr? (int)*limitPtr : limitFixed;
  if(limit>6000) limit=6000;
  long total=(long)limit*94;
  int lane=threadIdx.x&63;
  long w0=(long)blockIdx.x*4 + (threadIdx.x>>6);
  long stride=(long)gridDim.x*4;
  for(long w=w0; w<total; w+=stride){
    int row=(int)(w/94), wrd=(int)(w-(long)row*94);
    int j=wrd*64+lane;
    float4 a=*(const float4*)(boxes+4*row);
    bool bit=false;
    if(j<limit && j>row){
      float4 b=*(const float4*)(boxes+4*j);
      float area_a=(a.z-a.x)*(a.w-a.y);
      float area_b=(b.z-b.x)*(b.w-b.y);
      float ltx=fmaxf(a.x,b.x), lty=fmaxf(a.y,b.y);
      float rbx=fminf(a.z,b.z), rby=fminf(a.w,b.w);
      float wv=fmaxf(rbx-ltx,0.f), hv=fmaxf(rby-lty,0.f);
      float inter=wv*hv;
      float iou=inter/(area_a+area_b-inter+1e-9f);
      bit = iou>thresh;
    }
    u64 mword=__ballot(bit);
    if(lane==0) masks[(size_t)row*94+wrd]=mword;
  }
}

// ---------------- sequential greedy NMS scan (1 wave) + pick 300 ROIs ----------------
__global__ __launch_bounds__(64) void k_scan1(const u64* __restrict__ masks, const float* __restrict__ boxes6k,
                                              float* __restrict__ rois300){
  int lane=threadIdx.x;
  bool ld=lane<47;
  const u64* mrow=masks+lane*2;
  u64 r0=0,r1=0;
  u64 pa[8],pb[8];
#pragma unroll
  for(int d=0;d<8;d++){
    pa[d]=ld? mrow[(size_t)d*94]:0ull;
    pb[d]=ld? mrow[(size_t)d*94+1]:0ull;
  }
  for(int ib=0;ib<6000;ib+=8){
#pragma unroll
    for(int s=0;s<8;s++){
      int i=ib+s;
      u64 a=pa[s], b=pb[s];
      int nx=i+8;
      if(ld&&nx<6000){ pa[s]=mrow[(size_t)nx*94]; pb[s]=mrow[(size_t)nx*94+1]; }
      int w=i>>6;
      u64 v0=__shfl(r0,w>>1);
      u64 v1=__shfl(r1,w>>1);
      u64 word=(w&1)? v1:v0;
      if(!((word>>(i&63))&1ull)){ r0|=a; r1|=b; }
    }
  }
  __shared__ u64 rem[94];
  __shared__ u32 rsel[304];
  if(ld){ rem[2*lane]=r0; rem[2*lane+1]=r1; }
  __syncthreads();
  if(lane==0){
    int cnt=0;
    for(int c=0;c<94&&cnt<300;c++){
      u64 kw=~rem[c];
      if(c==93) kw&=0x0000FFFFFFFFFFFFull;
      while(kw&&cnt<300){ int b=__builtin_ctzll(kw); rsel[cnt++]=(u32)(c*64+b); kw&=kw-1; }
    }
    for(int c=0;c<94&&cnt<300;c++){
      u64 kw=rem[c];
      if(c==93) kw&=0x0000FFFFFFFFFFFFull;
      while(kw&&cnt<300){ int b=__builtin_ctzll(kw); rsel[cnt++]=(u32)(c*64+b); kw&=kw-1; }
    }
  }
  __syncthreads();
  for(int s2=lane;s2<300;s2+=64){
    u32 g=rsel[s2];
    float4 b=*(const float4*)(boxes6k+4*g);
    *(float4*)(rois300+4*s2)=b;
  }
}

__global__ __launch_bounds__(64) void k_scan2(const u64* __restrict__ masks, const u32* __restrict__ cnt,
                                              const float* __restrict__ dv, float* __restrict__ out){
  int lane=threadIdx.x;
  int V=(int)cnt[1]; if(V>6000)V=6000;
  bool ld=lane<47;
  const u64* mrow=masks+lane*2;
  u64 r0=0,r1=0;
  for(int i=0;i<V;i++){
    int w=i>>6;
    u64 v0=__shfl(r0,w>>1);
    u64 v1=__shfl(r1,w>>1);
    u64 word=(w&1)?v1:v0;
    if(!((word>>(i&63))&1ull)){
      if(ld){ r0|=mrow[(size_t)i*94]; r1|=mrow[(size_t)i*94+1]; }
    }
  }
  __shared__ u64 rem[94];
  if(ld){ rem[2*lane]=r0; rem[2*lane+1]=r1; }
  __syncthreads();
  for(int i=lane;i<6000;i+=64){
    bool kept=(i<V)&&!((rem[i>>6]>>(i&63))&1ull);
    out[i]=kept? dv[i]:0.0f;
    out[36000+i]=kept?1.0f:0.0f;
  }
}

// ---------------- feature transpose (C,H,W) f32 -> (H*W, C) bf16 ----------------
__global__ void k_featT(const float* __restrict__ feat, u16* __restrict__ featT){
  __shared__ float tile[32][65];
  int p0=blockIdx.x*64, c0=blockIdx.y*32;
  int t=threadIdx.x;
  int pp=t&63, cc=t>>6;
#pragma unroll
  for(int s=0;s<8;s++)
    tile[cc+s*4][pp]=feat[(size_t)(c0+cc+s*4)*16000+p0+pp];
  __syncthreads();
  int cw=t&31, pw=t>>5;
#pragma unroll
  for(int s=0;s<8;s++)
    featT[(size_t)(p0+pw+s*8)*256+c0+cw]=f2bf(tile[cw][pw+s*8]);
}

// ---------------- ROI align: one wave per sample point, 256 channels ----------------
template<int OUT>
__global__ void k_roialign(const float* __restrict__ rois, const u16* __restrict__ featT,
                           u16* __restrict__ outbuf){
  int wid=threadIdx.x>>6, lane=threadIdx.x&63;
  int gw=blockIdx.x*4+wid;
  if(gw>=300*OUT*OUT) return;
  int r=gw/(OUT*OUT), q=gw-r*(OUT*OUT), py=q/OUT, px=q-py*OUT;
  float x1=rois[4*r]*0.0625f;
  float y1=rois[4*r+1]*0.0625f;
  float x2=rois[4*r+2]*0.0625f;
  float y2=rois[4*r+3]*0.0625f;
  float bw=(x2-x1)/(float)OUT, bh=(y2-y1)/(float)OUT;
  float xx=x1+((float)px+0.5f)*bw-0.5f;
  float yy=y1+((float)py+0.5f)*bh-0.5f;
  float x0f=fminf(fmaxf(floorf(xx),0.f),158.f);
  float y0f=fminf(fmaxf(floorf(yy),0.f),98.f);
  float fx=fminf(fmaxf(xx-x0f,0.f),1.f);
  float fy=fminf(fmaxf(yy-y0f,0.f),1.f);
  int x0=(int)x0f, y0=(int)y0f;
  float w00=(1.f-fy)*(1.f-fx), w01=(1.f-fy)*fx, w10=fy*(1.f-fx), w11=fy*fx;
  const u16* p00=featT+((size_t)(y0*160+x0))*256+lane*4;
  ushort4 u00=*(const ushort4*)p00;
  ushort4 u01=*(const ushort4*)(p00+256);
  ushort4 u10=*(const ushort4*)(p00+40960);
  ushort4 u11=*(const ushort4*)(p00+41216);
  ushort4 o;
  o.x=f2bf(((bf2f(u00.x)*w00+bf2f(u01.x)*w01)+bf2f(u10.x)*w10)+bf2f(u11.x)*w11);
  o.y=f2bf(((bf2f(u00.y)*w00+bf2f(u01.y)*w01)+bf2f(u10.y)*w10)+bf2f(u11.y)*w11);
  o.z=f2bf(((bf2f(u00.z)*w00+bf2f(u01.z)*w01)+bf2f(u10.z)*w10)+bf2f(u11.z)*w11);
  o.w=f2bf(((bf2f(u00.w)*w00+bf2f(u01.w)*w01)+bf2f(u10.w)*w10)+bf2f(u11.w)*w11);
  *(ushort4*)(outbuf+(size_t)gw*256+lane*4)=o;
}

// ---------------- weight prep ----------------
__global__ void k_prep(const float* __restrict__ mw1, const float* __restrict__ mwd,
                       const float* __restrict__ Wc, const float* __restrict__ Wr,
                       u16* __restrict__ Bc1, u16* __restrict__ B3t, float* __restrict__ WT){
  int i=blockIdx.x*256+threadIdx.x;
  if(i<294912){
    int o=i/2304, rem=i-o*2304, c=rem/9, t=rem-(rem/9)*9;
    Bc1[((size_t)t*256+c)*128+o]=f2bf(mw1[i]);
  }
  if(i<65536){
    int co=i>>9, ci=(i>>2)&127, ky=(i>>1)&1, kxx=i&1;
    int z=ky*2+kxx;
    B3t[((size_t)z*128+co)*128+ci]=f2bf(mwd[i]);
  }
  if(i<107520){
    int j=i>>10, k=i&1023;
    WT[(size_t)j*1024+k]=(j<21)? Wc[(size_t)k*21+j] : Wr[(size_t)k*84+(j-21)];
  }
}

// ---------------- FC1: (300 x 12544) @ (12544 x 1024) bf16 MFMA, bias+relu ----------------
__global__ __launch_bounds__(256) void k_fc1(const u16* __restrict__ roi7, const float* __restrict__ W1,
                                             const float* __restrict__ b1, float* __restrict__ h){
  __shared__ u16 Asm[64][80];
  __shared__ u16 Bsm[64][80];
  int m0=blockIdx.x*64, n0=blockIdx.y*64;
  int tid=threadIdx.x, lane=tid&63, wid=tid>>6;
  int wr=wid>>1, wc=wid&1;
  f32x4 acc[2][2]={};
  for(int k0=0;k0<12544;k0+=64){
    {
      int row=tid>>2, seg=(tid&3)*16;
      int m=m0+row;
      u16x8 v0={0,0,0,0,0,0,0,0}, v1={0,0,0,0,0,0,0,0};
      if(m<300){
        const u16x8* s=(const u16x8*)(roi7+(size_t)m*12544+k0+seg);
        v0=s[0]; v1=s[1];
      }
      *(u16x8*)&Asm[row][seg]=v0;
      *(u16x8*)&Asm[row][seg+8]=v1;
    }
    {
      int kk=tid>>2, nseg=(tid&3)*16;
      int kg=k0+kk, p=kg>>8, c=kg&255;
      const float* src=W1+(size_t)(c*49+p)*1024+n0+nseg;
      float fv[16];
      *(float4*)(fv+0)=((const float4*)src)[0];
      *(float4*)(fv+4)=((const float4*)src)[1];
      *(float4*)(fv+8)=((const float4*)src)[2];
      *(float4*)(fv+12)=((const float4*)src)[3];
#pragma unroll
      for(int ii=0;ii<16;ii++) Bsm[nseg+ii][kk]=f2bf(fv[ii]);
    }
    __syncthreads();
#pragma unroll
    for(int ks=0;ks<2;ks++){
      int kb=ks*32+(lane>>4)*8;
      u16x8 a0=*(const u16x8*)&Asm[wr*32+(lane&15)][kb];
      u16x8 a1=*(const u16x8*)&Asm[wr*32+16+(lane&15)][kb];
      u16x8 b0=*(const u16x8*)&Bsm[wc*32+(lane&15)][kb];
      u16x8 b1v=*(const u16x8*)&Bsm[wc*32+16+(lane&15)][kb];
      mfma16(acc[0][0],a0,b0); mfma16(acc[0][1],a0,b1v);
      mfma16(acc[1][0],a1,b0); mfma16(acc[1][1],a1,b1v);
    }
    __syncthreads();
  }
  asm volatile("s_nop 7\ns_nop 7");
#pragma unroll
  for(int fm=0;fm<2;fm++)
#pragma unroll
  for(int fn=0;fn<2;fn++){
    int col=n0+wc*32+fn*16+(lane&15);
    float bias=b1[col];
#pragma unroll
    for(int j=0;j<4;j++){
      int row=m0+wr*32+fm*16+(lane>>4)*4+j;
      if(row<300) h[(size_t)row*1024+col]=fmaxf(acc[fm][fn][j]+bias,0.f);
    }
  }
}

// ---------------- conv1 3x3 pad1 as implicit GEMM: rows=300*196, K=2304, N=128 ----------------
__global__ __launch_bounds__(256) void k_conv1(const u16* __restrict__ roi14, const u16* __restrict__ Bc1,
                                               const float* __restrict__ mb1, u16* __restrict__ x1){
  __shared__ u16 Asm[64][48];
  __shared__ u16 Bsm[128][48];
  __shared__ int rowinf[64];
  int m0=blockIdx.x*64;
  int tid=threadIdx.x, lane=tid&63, wid=tid>>6;
  int wr=wid>>1, wc=wid&1;
  if(tid<64){
    int p=m0+tid;
    if(p<58800){ int r=p/196, q=p-r*196, y=q/14, x=q-y*14; rowinf[tid]=(r<<8)|(y<<4)|x; }
    else rowinf[tid]=-1;
  }
  __syncthreads();
  f32x4 acc[2][4]={};
  for(int it=0; it<72; ++it){
    int kg=it*32;
    int tap=kg>>8, c0=kg&255;
    int ky=tap/3, kx=tap-ky*3;
    {
      int ri=tid>>2, cl=(tid&3)*8;
      int rb=rowinf[ri];
      u16x8 v={0,0,0,0,0,0,0,0};
      if(rb>=0){
        int rr=rb>>8, y=(rb>>4)&15, x=rb&15;
        int yy=y+ky-1, xx=x+kx-1;
        if(yy>=0&&yy<14&&xx>=0&&xx<14)
          v=*(const u16x8*)(roi14+((size_t)((rr*14+yy)*14+xx))*256+c0+cl);
      }
      *(u16x8*)&Asm[ri][cl]=v;
    }
    {
      int kr=tid&31, cs2=(tid>>5)*16;
      const u16x8* s=(const u16x8*)(Bc1+(size_t)(kg+kr)*128+cs2);
      u16x8 v0=s[0], v1=s[1];
#pragma unroll
      for(int ii=0;ii<8;ii++){ Bsm[cs2+ii][kr]=v0[ii]; Bsm[cs2+8+ii][kr]=v1[ii]; }
    }
    __syncthreads();
    int kb=(lane>>4)*8;
    u16x8 a0=*(const u16x8*)&Asm[wr*32+(lane&15)][kb];
    u16x8 a1=*(const u16x8*)&Asm[wr*32+16+(lane&15)][kb];
#pragma unroll
    for(int fn=0;fn<4;fn++){
      u16x8 bv=*(const u16x8*)&Bsm[wc*64+fn*16+(lane&15)][kb];
      mfma16(acc[0][fn],a0,bv);
      mfma16(acc[1][fn],a1,bv);
    }
    __syncthreads();
  }
  asm volatile("s_nop 7\ns_nop 7");
#pragma unroll
  for(int fm=0;fm<2;fm++)
#pragma unroll
  for(int fn=0;fn<4;fn++){
    int col=wc*64+fn*16+(lane&15);
    float bias=mb1[col];
#pragma unroll
    for(int j=0;j<4;j++){
      int row=wr*32+fm*16+(lane>>4)*4+j;
      int p=m0+row;
      if(p<58800) x1[(size_t)p*128+col]=f2bf(fmaxf(acc[fm][fn][j]+bias,0.f));
    }
  }
}

// ---------------- conv2(deconv, per parity class) fused with conv3 1x1 ----------------
__global__ __launch_bounds__(256) void k_conv2f(const u16* __restrict__ x1, const u16* __restrict__ B3t,
                                                const float* __restrict__ mbd, const float* __restrict__ mwo,
                                                const float* __restrict__ mbo, float* __restrict__ m3){
  __shared__ u16 Asm[64][48];
  __shared__ u16 Bsm[128][48];
  __shared__ u16 X2[64][144];
  __shared__ u16 B4[32][144];
  int m0=blockIdx.x*64, z=blockIdx.y;
  int ky=z>>1, kx=z&1;
  int tid=threadIdx.x, lane=tid&63, wid=tid>>6;
  int wr=wid>>1, wc=wid&1;
  for(int i=tid;i<32*128;i+=256){
    int n=i>>7, k=i&127;
    B4[n][k]=(n<21)? f2bf(mwo[n*128+k]) : (u16)0;
  }
  f32x4 acc[2][4]={};
  for(int it=0;it<4;it++){
    int c0=it*32;
    {
      int ri=tid>>2, cl=(tid&3)*8;
      int p=m0+ri;
      u16x8 v={0,0,0,0,0,0,0,0};
      if(p<58800) v=*(const u16x8*)(x1+(size_t)p*128+c0+cl);
      *(u16x8*)&Asm[ri][cl]=v;
    }
    {
      int n=tid>>1, hf=tid&1;
      const u16x8* s=(const u16x8*)(B3t+((size_t)z*128+n)*128+c0+hf*16);
      u16x8 v0=s[0], v1=s[1];
      *(u16x8*)&Bsm[n][hf*16]=v0;
      *(u16x8*)&Bsm[n][hf*16+8]=v1;
    }
    __syncthreads();
    int kb=(lane>>4)*8;
    u16x8 a0=*(const u16x8*)&Asm[wr*32+(lane&15)][kb];
    u16x8 a1=*(const u16x8*)&Asm[wr*32+16+(lane&15)][kb];
#pragma unroll
    for(int fn=0;fn<4;fn++){
      u16x8 bv=*(const u16x8*)&Bsm[wc*64+fn*16+(lane&15)][kb];
      mfma16(acc[0][fn],a0,bv);
      mfma16(acc[1][fn],a1,bv);
    }
    __syncthreads();
  }
  asm volatile("s_nop 7\ns_nop 7");
#pragma unroll
  for(int fm=0;fm<2;fm++)
#pragma unroll
  for(int fn=0;fn<4;fn++){
    int col=wc*64+fn*16+(lane&15);
    float bias=mbd[col];
#pragma unroll
    for(int j=0;j<4;j++){
      int row=wr*32+fm*16+(lane>>4)*4+j;
      X2[row][col]=f2bf(fmaxf(acc[fm][fn][j]+bias,0.f));
    }
  }
  __syncthreads();
  f32x4 acc2[2]={};
#pragma unroll
  for(int ks=0;ks<4;ks++){
    int kb=ks*32+(lane>>4)*8;
    u16x8 a=*(const u16x8*)&X2[wid*16+(lane&15)][kb];
    u16x8 b0=*(const u16x8*)&B4[(lane&15)][kb];
    u16x8 b1v=*(const u16x8*)&B4[16+(lane&15)][kb];
    mfma16(acc2[0],a,b0);
    mfma16(acc2[1],a,b1v);
  }
  asm volatile("s_nop 7\ns_nop 7");
#pragma unroll
  for(int fn=0;fn<2;fn++){
    int n=fn*16+(lane&15);
    if(n<21){
      float bias=mbo[n];
#pragma unroll
      for(int j=0;j<4;j++){
        int row=wid*16+(lane>>4)*4+j;
        int p=m0+row;
        if(p<58800){
          int r=p/196, q=p-r*196, iy=q/14, ix=q-iy*14;
          int oy=2*iy+(1-ky), ox=2*ix+(1-kx);
          m3[(((size_t)r*28+oy)*28+ox)*21+n]=acc2[fn][j]+bias;
        }
      }
    }
  }
}

// ---------------- per-ROI head: logits, softmax, box decode, det keys ----------------
__global__ void k_head(const float* __restrict__ h, const float* __restrict__ WT,
                       const float* __restrict__ bc, const float* __restrict__ br,
                       const float* __restrict__ rois300, float* __restrict__ bxb,
                       float* __restrict__ scm, u64* __restrict__ keys2, u32* __restrict__ cnt){
  __shared__ float hs[1024];
  __shared__ float lg[105];
  __shared__ float scs[21];
  int r=blockIdx.x, t=threadIdx.x;
  for(int i=t;i<1024;i+=256) hs[i]=h[(size_t)r*1024+i];
  __syncthreads();
  if(t<105){
    const float* wrow=WT+(size_t)t*1024;
    float s=0.f;
    for(int k=0;k<1024;k+=4){
      float4 wv=*(const float4*)(wrow+k);
      s+=hs[k]*wv.x; s+=hs[k+1]*wv.y; s+=hs[k+2]*wv.z; s+=hs[k+3]*wv.w;
    }
    lg[t]=s+((t<21)?bc[t]:br[t-21]);
  }
  __syncthreads();
  if(t==0){
    float m=lg[0];
    for(int c=1;c<21;c++) m=fmaxf(m,lg[c]);
    float sum=0.f;
    for(int c=0;c<21;c++){ float e=exp_cr(lg[c]-m); scs[c]=e; sum+=e; }
    for(int c=0;c<21;c++) scs[c]=scs[c]/sum;
  }
  __syncthreads();
  if(t<20){
    int c=t+1;
    float rx1=rois300[4*r],ry1=rois300[4*r+1],rx2=rois300[4*r+2],ry2=rois300[4*r+3];
    float w=rx2-rx1, hh=ry2-ry1;
    float cx=rx1+0.5f*w, cy=ry1+0.5f*hh;
    float dx=lg[21+c*4+0], dy=lg[21+c*4+1], dwv=lg[21+c*4+2], dhv=lg[21+c*4+3];
    float pcx=dx*w+cx, pcy=dy*hh+cy;
    float pw=w*exp_cr(fminf(dwv,4.f)), ph=hh*exp_cr(fminf(dhv,4.f));
    float bx1=fminf(fmaxf(pcx-0.5f*pw,0.f),2560.f);
    float by1=fminf(fmaxf(pcy-0.5f*ph,0.f),1600.f);
    float bx2=fminf(fmaxf(pcx+0.5f*pw,0.f),2560.f);
    float by2=fminf(fmaxf(pcy+0.5f*ph,0.f),1600.f);
    int e=r*20+t;
    bxb[4*e]=bx1; bxb[4*e+1]=by1; bxb[4*e+2]=bx2; bxb[4*e+3]=by2;
    float sc=scs[c];
    bool valid=(sc>0.5f)&&(bx2-bx1>=1.f)&&(by2-by1>=1.f);
    float sv=valid? sc : -INFINITY;
    scm[e]=sv;
    keys2[e]=((u64)fkey(sv)<<32)|(u64)(~(u32)e);
    if(valid) atomicAdd(&cnt[1],1u);
  }
}

__global__ void k_detprep(const u32* __restrict__ order, const float* __restrict__ scm,
                          const float* __restrict__ bxb, float* __restrict__ dv,
                          float* __restrict__ dbx, float* __restrict__ out){
  int i=blockIdx.x*256+threadIdx.x;
  if(i>=6000) return;
  u32 g=order[i];
  float4 b=*(const float4*)(bxb+4*g);
  *(float4*)(dbx+4*i)=b;
  dv[i]=scm[g];
  *(float4*)(out+6000+4*i)=b;
  out[30000+i]=(float)(g%20u);
}

__global__ void k_dml(const u32* __restrict__ order, const float* __restrict__ m3, float* __restrict__ out){
  int idx=blockIdx.x*256+threadIdx.x;
  if(idx>=4704000) return;
  int e=idx/784, q=idx-e*784;
  u32 g=order[e];
  int r=(int)(g/20u), c=(int)(g%20u)+1;
  out[42000+idx]=m3[((size_t)r*784+q)*21+c];
}

extern "C" void kernel_launch(void* const* d_in, const int* in_sizes, int n_in,
                              void* d_out, int out_size, void* d_ws, size_t ws_size,
                              hipStream_t stream){
  (void)in_sizes; (void)n_in; (void)out_size;
  const float* features =(const float*)d_in[0];
  const float* rpn_logits=(const float*)d_in[1];
  const float* rpn_deltas=(const float*)d_in[2];
  const float* anchors  =(const float*)d_in[3];
  const float* W1=(const float*)d_in[4];
  const float* b1=(const float*)d_in[5];
  const float* Wc=(const float*)d_in[6];
  const float* bc=(const float*)d_in[7];
  const float* Wr=(const float*)d_in[8];
  const float* br=(const float*)d_in[9];
  const float* mw1=(const float*)d_in[10];
  const float* mb1=(const float*)d_in[11];
  const float* mwd=(const float*)d_in[12];
  const float* mbd=(const float*)d_in[13];
  const float* mwo=(const float*)d_in[14];
  const float* mbo=(const float*)d_in[15];
  float* out=(float*)d_out;

  char* base=(char*)d_ws; size_t off=0;
  auto alloc=[&](size_t bytes)->void*{ off=(off+255)&~(size_t)255; void* p=base+off; off+=bytes; return p; };
  u32* hist     =(u32*)alloc(65536*4);
  u32* cnt      =(u32*)alloc(64);
  float* scores =(float*)alloc(144000*4);
  float* rois_all=(float*)alloc((size_t)144000*16);
  u64* keys1    =(u64*)alloc(8192*8);
  u32* selidx   =(u32*)alloc(6000*4);
  float* boxes6k=(float*)alloc(6000*16);
  u64* masks    =(u64*)alloc((size_t)6000*94*8);
  float* rois300=(float*)alloc(300*16);
  u16* featT    =(u16*)alloc((size_t)16000*256*2);
  u16* roi7     =(u16*)alloc((size_t)300*49*256*2);
  u16* roi14    =(u16*)alloc((size_t)300*196*256*2);
  float* hbuf   =(float*)alloc((size_t)300*1024*4);
  float* WT     =(float*)alloc((size_t)105*1024*4);
  float* bxb    =(float*)alloc(6000*16);
  float* scm    =(float*)alloc(6000*4);
  u64* keys2    =(u64*)alloc(8192*8);
  u32* order    =(u32*)alloc(6000*4);
  float* dv     =(float*)alloc(6000*4);
  float* dbx    =(float*)alloc(6000*16);
  u16* x1       =(u16*)alloc((size_t)58800*128*2);
  u16* Bc1      =(u16*)alloc((size_t)2304*128*2);
  u16* B3t      =(u16*)alloc((size_t)4*128*128*2);
  float* m3     =(float*)alloc((size_t)58800*21*4);
  if(off > ws_size) return; // workspace too small; fail visibly

  hipMemsetAsync(hist,0,65536*4,stream);
  hipMemsetAsync(cnt,0,64,stream);

  k_prep<<<1152,256,0,stream>>>(mw1,mwd,Wc,Wr,Bc1,B3t,WT);
  k_featT<<<dim3(250,8),256,0,stream>>>(features,featT);

  k_rpn<<<563,256,0,stream>>>(rpn_logits,rpn_deltas,anchors,scores,rois_all,hist);
  k_findbin<<<1,1024,0,stream>>>(hist,cnt);
  k_compact<<<563,256,0,stream>>>(scores,cnt,keys1);
  k_sort8k<true><<<1,1024,0,stream>>>(keys1,cnt,0,selidx);
  k_gather6k<<<24,256,0,stream>>>(selidx,rois_all,boxes6k);
  k_masks<<<2048,256,0,stream>>>(boxes6k,nullptr,6000,0.7f,masks);
  k_scan1<<<1,64,0,stream>>>(masks,boxes6k,rois300);

  k_roialign<7><<<3675,256,0,stream>>>(rois300,featT,roi7);
  k_roialign<14><<<14700,256,0,stream>>>(rois300,featT,roi14);

  k_fc1<<<dim3(5,16),256,0,stream>>>(roi7,W1,b1,hbuf);
  k_conv1<<<919,256,0,stream>>>(roi14,Bc1,mb1,x1);
  k_conv2f<<<dim3(919,4),256,0,stream>>>(x1,B3t,mbd,mwo,mbo,m3);

  k_head<<<300,256,0,stream>>>(hbuf,WT,bc,br,rois300,bxb,scm,keys2,cnt);
  k_sort8k<false><<<1,1024,0,stream>>>(keys2,nullptr,6000,order);
  k_detprep<<<24,256,0,stream>>>(order,scm,bxb,dv,dbx,out);
  k_masks<<<512,256,0,stream>>>(dbx,cnt+1,0,0.5f,masks);
  k_scan2<<<1,64,0,stream>>>(masks,cnt,dv,out);
  k_dml<<<18375,256,0,stream>>>(order,m3,out);
}

// Round 2
// 1309.346 us; speedup vs baseline: 2.2461x; 2.2461x over previous
//
#include <hip/hip_runtime.h>
#include <stdint.h>

#pragma clang fp contract(off)

typedef unsigned int u32;
typedef unsigned short u16;
typedef unsigned long long u64;
typedef float f32x4 __attribute__((ext_vector_type(4)));
typedef u16 u16x8 __attribute__((ext_vector_type(8)));
typedef u64 u64x2 __attribute__((ext_vector_type(2)));

#define DEV __device__ __forceinline__

DEV float bf2f(u16 u){ union{u32 i; float f;} v; v.i=((u32)u)<<16; return v.f; }
DEV u16 f2bf(float f){ union{float f; u32 i;} v; v.f=f; u32 b=v.i; return (u16)((b + 0x7fffu + ((b>>16)&1u))>>16); }
DEV u32 fkey(float f){ union{float f; u32 i;} v; v.f=f; u32 b=v.i; return (b&0x80000000u)? ~b : (b|0x80000000u); }
DEV float exp_cr(float x){ return (float)exp((double)x); }

DEV void mfma16(f32x4& d, u16x8 a, u16x8 b){
  asm volatile("v_mfma_f32_16x16x32_bf16 %0, %1, %2, %0" : "+v"(d) : "v"(a), "v"(b));
}

// ---------------- RPN: softmax score + decode + clip + filter + histogram ----------------
__global__ void k_rpn(const float* __restrict__ logits, const float* __restrict__ deltas,
                      const float* __restrict__ anchors, float* __restrict__ scores,
                      float* __restrict__ rois_all, u32* __restrict__ hist){
  int i=blockIdx.x*256+threadIdx.x;
  if(i>=144000) return;
  float l0=logits[2*i], l1=logits[2*i+1];
  float m=fmaxf(l0,l1);
  float e0=exp_cr(l0-m), e1=exp_cr(l1-m);
  float s=e1/(e0+e1);
  float a0=anchors[4*i],a1=anchors[4*i+1],a2=anchors[4*i+2],a3=anchors[4*i+3];
  float w=a2-a0, hh=a3-a1;
  float cx=a0+0.5f*w, cy=a1+0.5f*hh;
  float dx=deltas[4*i],dy=deltas[4*i+1],dwv=deltas[4*i+2],dhv=deltas[4*i+3];
  float pcx=dx*w+cx, pcy=dy*hh+cy;
  float pw=w*exp_cr(fminf(dwv,4.f)), ph=hh*exp_cr(fminf(dhv,4.f));
  float x1=fminf(fmaxf(pcx-0.5f*pw,0.f),2560.f);
  float y1=fminf(fmaxf(pcy-0.5f*ph,0.f),1600.f);
  float x2=fminf(fmaxf(pcx+0.5f*pw,0.f),2560.f);
  float y2=fminf(fmaxf(pcy+0.5f*ph,0.f),1600.f);
  float4 bb; bb.x=x1;bb.y=y1;bb.z=x2;bb.w=y2;
  *(float4*)(rois_all+4*i)=bb;
  bool ok=(x2-x1>=16.f)&&(y2-y1>=16.f);
  float sc=ok? s : -INFINITY;
  scores[i]=sc;
  if(ok) atomicAdd(&hist[fkey(sc)>>16],1u);
}

// ---------------- find 6000th-rank histogram bin ----------------
__global__ void k_findbin(const u32* __restrict__ hist, u32* __restrict__ cnt){
  __shared__ u32 cs[1024];
  int t=threadIdx.x;
  u32 s=0;
  for(int b=0;b<64;b++) s+=hist[t*64+b];
  cs[t]=s;
  __syncthreads();
  if(t==0){
    u32 acc=0; int tc=1023;
    for(; tc>=0; tc--){ if(acc+cs[tc]>=6000u) break; acc+=cs[tc]; }
    if(tc<0) tc=0;
    u32 B=(u32)tc*64u;
    for(int b=63;b>=0;b--){
      u32 hb=hist[tc*64+b];
      if(acc+hb>=6000u){ B=(u32)(tc*64+b); break; }
      acc+=hb;
    }
    cnt[2]=B;
  }
}

__global__ void k_compact(const float* __restrict__ scores, u32* __restrict__ cnt, u64* __restrict__ keys){
  int i=blockIdx.x*256+threadIdx.x;
  if(i>=144000) return;
  u32 u=fkey(scores[i]);
  if((u>>16) >= cnt[2]){
    u32 pos=atomicAdd(&cnt[0],1u);
    if(pos<8192u) keys[pos]=((u64)u<<32)|(u64)(~(u32)i);
  }
}

// ---------------- single-block bitonic sort (8192, descending), emit top-6000 indices ----------------
template<bool FROMCNT>
__global__ __launch_bounds__(1024) void k_sort8k(const u64* __restrict__ keys, const u32* __restrict__ cnt,
                                                 int n_fixed, u32* __restrict__ out_idx){
  __shared__ u64 K[8192];
  int n = FROMCNT ? (int)cnt[0] : n_fixed;
  if(n>8192) n=8192;
  for(int i=threadIdx.x;i<8192;i+=1024) K[i]=(i<n)? keys[i] : 0ull;
  __syncthreads();
  for(int k=2;k<=8192;k<<=1){
    for(int j=k>>1;j>0;j>>=1){
      for(int t=threadIdx.x;t<8192;t+=1024){
        int p=t^j;
        if(p>t){
          u64 a=K[t], b=K[p];
          bool up=((t&k)==0);
          if((a<b)==up){ K[t]=b; K[p]=a; }
        }
      }
      __syncthreads();
    }
  }
  for(int i=threadIdx.x;i<6000;i+=1024) out_idx[i]=~((u32)K[i]);
}

__global__ void k_gather6k(const u32* __restrict__ selidx, const float* __restrict__ rois_all,
                           float* __restrict__ boxes6k){
  int i=blockIdx.x*256+threadIdx.x;
  if(i>=6000) return;
  u32 g=selidx[i];
  float4 b=*(const float4*)(rois_all+4*g);
  *(float4*)(boxes6k+4*i)=b;
}

// ---------------- NMS bitmask build (grid-stride over row-words) ----------------
__global__ void k_masks(const float* __restrict__ boxes, const u32* __restrict__ limitPtr, int limitFixed,
                        float thresh, u64* __restrict__ masks){
  int limit = limitPtr? (int)*limitPtr : limitFixed;
  if(limit>6000) limit=6000;
  long total=(long)limit*94;
  int lane=threadIdx.x&63;
  long w0=(long)blockIdx.x*4 + (threadIdx.x>>6);
  long stride=(long)gridDim.x*4;
  for(long w=w0; w<total; w+=stride){
    int row=(int)(w/94), wrd=(int)(w-(long)row*94);
    int j=wrd*64+lane;
    float4 a=*(const float4*)(boxes+4*row);
    bool bit=false;
    if(j<limit && j>row){
      float4 b=*(const float4*)(boxes+4*j);
      float area_a=(a.z-a.x)*(a.w-a.y);
      float area_b=(b.z-b.x)*(b.w-b.y);
      float ltx=fmaxf(a.x,b.x), lty=fmaxf(a.y,b.y);
      float rbx=fminf(a.z,b.z), rby=fminf(a.w,b.w);
      float wv=fmaxf(rbx-ltx,0.f), hv=fmaxf(rby-lty,0.f);
      float inter=wv*hv;
      float iou=inter/(area_a+area_b-inter+1e-9f);
      bit = iou>thresh;
    }
    u64 mword=__ballot(bit);
    if(lane==0) masks[(size_t)row*94+wrd]=mword;
  }
}

// ---------------- chunked greedy NMS scan (94 chunks of 64) + pick 300 ROIs ----------------
__global__ __launch_bounds__(128) void k_scan1(const u64* __restrict__ masks, const float* __restrict__ boxes6k,
                                               float* __restrict__ rois300){
  __shared__ __align__(16) u64 stage[2][6016];
  __shared__ u64 remv[94];
  __shared__ u64 keepw[94];
  __shared__ u32 rsel[304];
  int tid=threadIdx.x;
  if(tid<94) remv[tid]=0ull;
  u64x2 rg[24];
  // prologue: stage chunk 0 (rows 0..63, 3008 16B pairs)
  {
    const u64x2* src0=(const u64x2*)masks;
#pragma unroll
    for(int k=0;k<24;k++){ int idx=tid+k*128; if(idx<3008) rg[k]=src0[idx]; }
    u64x2* dst0=(u64x2*)&stage[0][0];
#pragma unroll
    for(int k=0;k<24;k++){ int idx=tid+k*128; if(idx<3008) dst0[idx]=rg[k]; }
  }
  __syncthreads();
  for(int c=0;c<94;c++){
    int cur=c&1, nxt=cur^1;
    int npn=(c+1==93)?2256:3008;
    // 1) issue next-chunk global loads early (latency hides under 2/3)
    if(c<93){
      const u64x2* srcn=(const u64x2*)(masks+(size_t)(c+1)*64*94);
#pragma unroll
      for(int k=0;k<24;k++){ int idx=tid+k*128; if(idx<npn) rg[k]=srcn[idx]; }
    }
    // 2) intra-chunk greedy resolution (redundant in all threads; register-only chain)
    u64 keep=~remv[c];
    if(c==93) keep&=0x0000FFFFFFFFFFFFull;
    const u64* sb=&stage[cur][0];
#pragma unroll
    for(int g=0;g<64;g+=8){
      u64 r[8];
#pragma unroll
      for(int j=0;j<8;j++) r[j]=sb[(size_t)(g+j)*94+c];
#pragma unroll
      for(int j=0;j<8;j++) if((keep>>(g+j))&1ull) keep&=~r[j];
    }
    // 3) word-parallel remv update with kept rows
    if(tid<94){
      u64 acc=0ull;
#pragma unroll 8
      for(int i=0;i<64;i++){
        u64 msk=(u64)0-((keep>>i)&1ull);
        acc|=sb[(size_t)i*94+tid]&msk;
      }
      remv[tid]|=acc;
    }
    if(tid==0) keepw[c]=keep;
    // 4) commit staged next chunk
    if(c<93){
      u64x2* dstn=(u64x2*)&stage[nxt][0];
#pragma unroll
      for(int k=0;k<24;k++){ int idx=tid+k*128; if(idx<npn) dstn[idx]=rg[k]; }
    }
    __syncthreads();
  }
  // selection: first 300 kept (index order), then pad with suppressed (index order)
  if(tid==0){
    int cntk=0;
    for(int c=0;c<94&&cntk<300;c++){
      u64 kw=keepw[c];
      while(kw&&cntk<300){ int b=__builtin_ctzll(kw); rsel[cntk++]=(u32)(c*64+b); kw&=kw-1; }
    }
    for(int c=0;c<94&&cntk<300;c++){
      u64 kw=~keepw[c];
      if(c==93) kw&=0x0000FFFFFFFFFFFFull;
      while(kw&&cntk<300){ int b=__builtin_ctzll(kw); rsel[cntk++]=(u32)(c*64+b); kw&=kw-1; }
    }
  }
  __syncthreads();
  for(int s2=tid;s2<300;s2+=128){
    u32 g=rsel[s2];
    float4 b=*(const float4*)(boxes6k+4*g);
    *(float4*)(rois300+4*s2)=b;
  }
}

__global__ __launch_bounds__(64) void k_scan2(const u64* __restrict__ masks, const u32* __restrict__ cnt,
                                              const float* __restrict__ dv, float* __restrict__ out){
  int lane=threadIdx.x;
  int V=(int)cnt[1]; if(V>6000)V=6000;
  bool ld=lane<47;
  const u64* mrow=masks+lane*2;
  u64 r0=0,r1=0;
  for(int i=0;i<V;i++){
    int w=i>>6;
    u64 v0=__shfl(r0,w>>1);
    u64 v1=__shfl(r1,w>>1);
    u64 word=(w&1)?v1:v0;
    if(!((word>>(i&63))&1ull)){
      if(ld){ r0|=mrow[(size_t)i*94]; r1|=mrow[(size_t)i*94+1]; }
    }
  }
  __shared__ u64 rem[94];
  if(ld){ rem[2*lane]=r0; rem[2*lane+1]=r1; }
  __syncthreads();
  for(int i=lane;i<6000;i+=64){
    bool kept=(i<V)&&!((rem[i>>6]>>(i&63))&1ull);
    out[i]=kept? dv[i]:0.0f;
    out[36000+i]=kept?1.0f:0.0f;
  }
}

// ---------------- feature transpose (C,H,W) f32 -> (H*W, C) bf16 ----------------
__global__ void k_featT(const float* __restrict__ feat, u16* __restrict__ featT){
  __shared__ float tile[32][65];
  int p0=blockIdx.x*64, c0=blockIdx.y*32;
  int t=threadIdx.x;
  int pp=t&63, cc=t>>6;
#pragma unroll
  for(int s=0;s<8;s++)
    tile[cc+s*4][pp]=feat[(size_t)(c0+cc+s*4)*16000+p0+pp];
  __syncthreads();
  int cw=t&31, pw=t>>5;
#pragma unroll
  for(int s=0;s<8;s++)
    featT[(size_t)(p0+pw+s*8)*256+c0+cw]=f2bf(tile[cw][pw+s*8]);
}

// ---------------- ROI align: one wave per sample point, 256 channels ----------------
template<int OUT>
__global__ void k_roialign(const float* __restrict__ rois, const u16* __restrict__ featT,
                           u16* __restrict__ outbuf){
  int wid=threadIdx.x>>6, lane=threadIdx.x&63;
  int gw=blockIdx.x*4+wid;
  if(gw>=300*OUT*OUT) return;
  int r=gw/(OUT*OUT), q=gw-r*(OUT*OUT), py=q/OUT, px=q-py*OUT;
  float x1=rois[4*r]*0.0625f;
  float y1=rois[4*r+1]*0.0625f;
  float x2=rois[4*r+2]*0.0625f;
  float y2=rois[4*r+3]*0.0625f;
  float bw=(x2-x1)/(float)OUT, bh=(y2-y1)/(float)OUT;
  float xx=x1+((float)px+0.5f)*bw-0.5f;
  float yy=y1+((float)py+0.5f)*bh-0.5f;
  float x0f=fminf(fmaxf(floorf(xx),0.f),158.f);
  float y0f=fminf(fmaxf(floorf(yy),0.f),98.f);
  float fx=fminf(fmaxf(xx-x0f,0.f),1.f);
  float fy=fminf(fmaxf(yy-y0f,0.f),1.f);
  int x0=(int)x0f, y0=(int)y0f;
  float w00=(1.f-fy)*(1.f-fx), w01=(1.f-fy)*fx, w10=fy*(1.f-fx), w11=fy*fx;
  const u16* p00=featT+((size_t)(y0*160+x0))*256+lane*4;
  ushort4 u00=*(const ushort4*)p00;
  ushort4 u01=*(const ushort4*)(p00+256);
  ushort4 u10=*(const ushort4*)(p00+40960);
  ushort4 u11=*(const ushort4*)(p00+41216);
  ushort4 o;
  o.x=f2bf(((bf2f(u00.x)*w00+bf2f(u01.x)*w01)+bf2f(u10.x)*w10)+bf2f(u11.x)*w11);
  o.y=f2bf(((bf2f(u00.y)*w00+bf2f(u01.y)*w01)+bf2f(u10.y)*w10)+bf2f(u11.y)*w11);
  o.z=f2bf(((bf2f(u00.z)*w00+bf2f(u01.z)*w01)+bf2f(u10.z)*w10)+bf2f(u11.z)*w11);
  o.w=f2bf(((bf2f(u00.w)*w00+bf2f(u01.w)*w01)+bf2f(u10.w)*w10)+bf2f(u11.w)*w11);
  *(ushort4*)(outbuf+(size_t)gw*256+lane*4)=o;
}

// ---------------- weight prep ----------------
__global__ void k_prep(const float* __restrict__ mw1, const float* __restrict__ mwd,
                       const float* __restrict__ Wc, const float* __restrict__ Wr,
                       u16* __restrict__ Bc1, u16* __restrict__ B3t, float* __restrict__ WT){
  int i=blockIdx.x*256+threadIdx.x;
  if(i<294912){
    int o=i/2304, rem=i-o*2304, c=rem/9, t=rem-(rem/9)*9;
    Bc1[((size_t)t*256+c)*128+o]=f2bf(mw1[i]);
  }
  if(i<65536){
    int co=i>>9, ci=(i>>2)&127, ky=(i>>1)&1, kxx=i&1;
    int z=ky*2+kxx;
    B3t[((size_t)z*128+co)*128+ci]=f2bf(mwd[i]);
  }
  if(i<107520){
    int j=i>>10, k=i&1023;
    WT[(size_t)j*1024+k]=(j<21)? Wc[(size_t)k*21+j] : Wr[(size_t)k*84+(j-21)];
  }
}

// ---------------- FC1: (300 x 12544) @ (12544 x 1024) bf16 MFMA, bias+relu ----------------
__global__ __launch_bounds__(256) void k_fc1(const u16* __restrict__ roi7, const float* __restrict__ W1,
                                             const float* __restrict__ b1, float* __restrict__ h){
  __shared__ u16 Asm[64][80];
  __shared__ u16 Bsm[64][80];
  int m0=blockIdx.x*64, n0=blockIdx.y*64;
  int tid=threadIdx.x, lane=tid&63, wid=tid>>6;
  int wr=wid>>1, wc=wid&1;
  f32x4 acc[2][2]={};
  for(int k0=0;k0<12544;k0+=64){
    {
      int row=tid>>2, seg=(tid&3)*16;
      int m=m0+row;
      u16x8 v0={0,0,0,0,0,0,0,0}, v1={0,0,0,0,0,0,0,0};
      if(m<300){
        const u16x8* s=(const u16x8*)(roi7+(size_t)m*12544+k0+seg);
        v0=s[0]; v1=s[1];
      }
      *(u16x8*)&Asm[row][seg]=v0;
      *(u16x8*)&Asm[row][seg+8]=v1;
    }
    {
      int kk=tid>>2, nseg=(tid&3)*16;
      int kg=k0+kk, p=kg>>8, c=kg&255;
      const float* src=W1+(size_t)(c*49+p)*1024+n0+nseg;
      float fv[16];
      *(float4*)(fv+0)=((const float4*)src)[0];
      *(float4*)(fv+4)=((const float4*)src)[1];
      *(float4*)(fv+8)=((const float4*)src)[2];
      *(float4*)(fv+12)=((const float4*)src)[3];
#pragma unroll
      for(int ii=0;ii<16;ii++) Bsm[nseg+ii][kk]=f2bf(fv[ii]);
    }
    __syncthreads();
#pragma unroll
    for(int ks=0;ks<2;ks++){
      int kb=ks*32+(lane>>4)*8;
      u16x8 a0=*(const u16x8*)&Asm[wr*32+(lane&15)][kb];
      u16x8 a1=*(const u16x8*)&Asm[wr*32+16+(lane&15)][kb];
      u16x8 b0=*(const u16x8*)&Bsm[wc*32+(lane&15)][kb];
      u16x8 b1v=*(const u16x8*)&Bsm[wc*32+16+(lane&15)][kb];
      mfma16(acc[0][0],a0,b0); mfma16(acc[0][1],a0,b1v);
      mfma16(acc[1][0],a1,b0); mfma16(acc[1][1],a1,b1v);
    }
    __syncthreads();
  }
  asm volatile("s_nop 7\ns_nop 7");
#pragma unroll
  for(int fm=0;fm<2;fm++)
#pragma unroll
  for(int fn=0;fn<2;fn++){
    int col=n0+wc*32+fn*16+(lane&15);
    float bias=b1[col];
#pragma unroll
    for(int j=0;j<4;j++){
      int row=m0+wr*32+fm*16+(lane>>4)*4+j;
      if(row<300) h[(size_t)row*1024+col]=fmaxf(acc[fm][fn][j]+bias,0.f);
    }
  }
}

// ---------------- conv1 3x3 pad1 as implicit GEMM: rows=300*196, K=2304, N=128 ----------------
__global__ __launch_bounds__(256) void k_conv1(const u16* __restrict__ roi14, const u16* __restrict__ Bc1,
                                               const float* __restrict__ mb1, u16* __restrict__ x1){
  __shared__ u16 Asm[64][48];
  __shared__ u16 Bsm[128][48];
  __shared__ int rowinf[64];
  int m0=blockIdx.x*64;
  int tid=threadIdx.x, lane=tid&63, wid=tid>>6;
  int wr=wid>>1, wc=wid&1;
  if(tid<64){
    int p=m0+tid;
    if(p<58800){ int r=p/196, q=p-r*196, y=q/14, x=q-y*14; rowinf[tid]=(r<<8)|(y<<4)|x; }
    else rowinf[tid]=-1;
  }
  __syncthreads();
  f32x4 acc[2][4]={};
  for(int it=0; it<72; ++it){
    int kg=it*32;
    int tap=kg>>8, c0=kg&255;
    int ky=tap/3, kx=tap-ky*3;
    {
      int ri=tid>>2, cl=(tid&3)*8;
      int rb=rowinf[ri];
      u16x8 v={0,0,0,0,0,0,0,0};
      if(rb>=0){
        int rr=rb>>8, y=(rb>>4)&15, x=rb&15;
        int yy=y+ky-1, xx=x+kx-1;
        if(yy>=0&&yy<14&&xx>=0&&xx<14)
          v=*(const u16x8*)(roi14+((size_t)((rr*14+yy)*14+xx))*256+c0+cl);
      }
      *(u16x8*)&Asm[ri][cl]=v;
    }
    {
      int kr=tid&31, cs2=(tid>>5)*16;
      const u16x8* s=(const u16x8*)(Bc1+(size_t)(kg+kr)*128+cs2);
      u16x8 v0=s[0], v1=s[1];
#pragma unroll
      for(int ii=0;ii<8;ii++){ Bsm[cs2+ii][kr]=v0[ii]; Bsm[cs2+8+ii][kr]=v1[ii]; }
    }
    __syncthreads();
    int kb=(lane>>4)*8;
    u16x8 a0=*(const u16x8*)&Asm[wr*32+(lane&15)][kb];
    u16x8 a1=*(const u16x8*)&Asm[wr*32+16+(lane&15)][kb];
#pragma unroll
    for(int fn=0;fn<4;fn++){
      u16x8 bv=*(const u16x8*)&Bsm[wc*64+fn*16+(lane&15)][kb];
      mfma16(acc[0][fn],a0,bv);
      mfma16(acc[1][fn],a1,bv);
    }
    __syncthreads();
  }
  asm volatile("s_nop 7\ns_nop 7");
#pragma unroll
  for(int fm=0;fm<2;fm++)
#pragma unroll
  for(int fn=0;fn<4;fn++){
    int col=wc*64+fn*16+(lane&15);
    float bias=mb1[col];
#pragma unroll
    for(int j=0;j<4;j++){
      int row=wr*32+fm*16+(lane>>4)*4+j;
      int p=m0+row;
      if(p<58800) x1[(size_t)p*128+col]=f2bf(fmaxf(acc[fm][fn][j]+bias,0.f));
    }
  }
}

// ---------------- conv2(deconv, per parity class) fused with conv3 1x1 ----------------
__global__ __launch_bounds__(256) void k_conv2f(const u16* __restrict__ x1, const u16* __restrict__ B3t,
                                                const float* __restrict__ mbd, const float* __restrict__ mwo,
                                                const float* __restrict__ mbo, float* __restrict__ m3){
  __shared__ u16 Asm[64][48];
  __shared__ u16 Bsm[128][48];
  __shared__ u16 X2[64][144];
  __shared__ u16 B4[32][144];
  int m0=blockIdx.x*64, z=blockIdx.y;
  int ky=z>>1, kx=z&1;
  int tid=threadIdx.x, lane=tid&63, wid=tid>>6;
  int wr=wid>>1, wc=wid&1;
  for(int i=tid;i<32*128;i+=256){
    int n=i>>7, k=i&127;
    B4[n][k]=(n<21)? f2bf(mwo[n*128+k]) : (u16)0;
  }
  f32x4 acc[2][4]={};
  for(int it=0;it<4;it++){
    int c0=it*32;
    {
      int ri=tid>>2, cl=(tid&3)*8;
      int p=m0+ri;
      u16x8 v={0,0,0,0,0,0,0,0};
      if(p<58800) v=*(const u16x8*)(x1+(size_t)p*128+c0+cl);
      *(u16x8*)&Asm[ri][cl]=v;
    }
    {
      int n=tid>>1, hf=tid&1;
      const u16x8* s=(const u16x8*)(B3t+((size_t)z*128+n)*128+c0+hf*16);
      u16x8 v0=s[0], v1=s[1];
      *(u16x8*)&Bsm[n][hf*16]=v0;
      *(u16x8*)&Bsm[n][hf*16+8]=v1;
    }
    __syncthreads();
    int kb=(lane>>4)*8;
    u16x8 a0=*(const u16x8*)&Asm[wr*32+(lane&15)][kb];
    u16x8 a1=*(const u16x8*)&Asm[wr*32+16+(lane&15)][kb];
#pragma unroll
    for(int fn=0;fn<4;fn++){
      u16x8 bv=*(const u16x8*)&Bsm[wc*64+fn*16+(lane&15)][kb];
      mfma16(acc[0][fn],a0,bv);
      mfma16(acc[1][fn],a1,bv);
    }
    __syncthreads();
  }
  asm volatile("s_nop 7\ns_nop 7");
#pragma unroll
  for(int fm=0;fm<2;fm++)
#pragma unroll
  for(int fn=0;fn<4;fn++){
    int col=wc*64+fn*16+(lane&15);
    float bias=mbd[col];
#pragma unroll
    for(int j=0;j<4;j++){
      int row=wr*32+fm*16+(lane>>4)*4+j;
      X2[row][col]=f2bf(fmaxf(acc[fm][fn][j]+bias,0.f));
    }
  }
  __syncthreads();
  f32x4 acc2[2]={};
#pragma unroll
  for(int ks=0;ks<4;ks++){
    int kb=ks*32+(lane>>4)*8;
    u16x8 a=*(const u16x8*)&X2[wid*16+(lane&15)][kb];
    u16x8 b0=*(const u16x8*)&B4[(lane&15)][kb];
    u16x8 b1v=*(const u16x8*)&B4[16+(lane&15)][kb];
    mfma16(acc2[0],a,b0);
    mfma16(acc2[1],a,b1v);
  }
  asm volatile("s_nop 7\ns_nop 7");
#pragma unroll
  for(int fn=0;fn<2;fn++){
    int n=fn*16+(lane&15);
    if(n<21){
      float bias=mbo[n];
#pragma unroll
      for(int j=0;j<4;j++){
        int row=wid*16+(lane>>4)*4+j;
        int p=m0+row;
        if(p<58800){
          int r=p/196, q=p-r*196, iy=q/14, ix=q-iy*14;
          int oy=2*iy+(1-ky), ox=2*ix+(1-kx);
          m3[(((size_t)r*28+oy)*28+ox)*21+n]=acc2[fn][j]+bias;
        }
      }
    }
  }
}

// ---------------- per-ROI head: logits, softmax, box decode, det keys ----------------
__global__ void k_head(const float* __restrict__ h, const float* __restrict__ WT,
                       const float* __restrict__ bc, const float* __restrict__ br,
                       const float* __restrict__ rois300, float* __restrict__ bxb,
                       float* __restrict__ scm, u64* __restrict__ keys2, u32* __restrict__ cnt){
  __shared__ float hs[1024];
  __shared__ float lg[105];
  __shared__ float scs[21];
  int r=blockIdx.x, t=threadIdx.x;
  for(int i=t;i<1024;i+=256) hs[i]=h[(size_t)r*1024+i];
  __syncthreads();
  if(t<105){
    const float* wrow=WT+(size_t)t*1024;
    float s=0.f;
    for(int k=0;k<1024;k+=4){
      float4 wv=*(const float4*)(wrow+k);
      s+=hs[k]*wv.x; s+=hs[k+1]*wv.y; s+=hs[k+2]*wv.z; s+=hs[k+3]*wv.w;
    }
    lg[t]=s+((t<21)?bc[t]:br[t-21]);
  }
  __syncthreads();
  if(t==0){
    float m=lg[0];
    for(int c=1;c<21;c++) m=fmaxf(m,lg[c]);
    float sum=0.f;
    for(int c=0;c<21;c++){ float e=exp_cr(lg[c]-m); scs[c]=e; sum+=e; }
    for(int c=0;c<21;c++) scs[c]=scs[c]/sum;
  }
  __syncthreads();
  if(t<20){
    int c=t+1;
    float rx1=rois300[4*r],ry1=rois300[4*r+1],rx2=rois300[4*r+2],ry2=rois300[4*r+3];
    float w=rx2-rx1, hh=ry2-ry1;
    float cx=rx1+0.5f*w, cy=ry1+0.5f*hh;
    float dx=lg[21+c*4+0], dy=lg[21+c*4+1], dwv=lg[21+c*4+2], dhv=lg[21+c*4+3];
    float pcx=dx*w+cx, pcy=dy*hh+cy;
    float pw=w*exp_cr(fminf(dwv,4.f)), ph=hh*exp_cr(fminf(dhv,4.f));
    float bx1=fminf(fmaxf(pcx-0.5f*pw,0.f),2560.f);
    float by1=fminf(fmaxf(pcy-0.5f*ph,0.f),1600.f);
    float bx2=fminf(fmaxf(pcx+0.5f*pw,0.f),2560.f);
    float by2=fminf(fmaxf(pcy+0.5f*ph,0.f),1600.f);
    int e=r*20+t;
    bxb[4*e]=bx1; bxb[4*e+1]=by1; bxb[4*e+2]=bx2; bxb[4*e+3]=by2;
    float sc=scs[c];
    bool valid=(sc>0.5f)&&(bx2-bx1>=1.f)&&(by2-by1>=1.f);
    float sv=valid? sc : -INFINITY;
    scm[e]=sv;
    keys2[e]=((u64)fkey(sv)<<32)|(u64)(~(u32)e);
    if(valid) atomicAdd(&cnt[1],1u);
  }
}

__global__ void k_detprep(const u32* __restrict__ order, const float* __restrict__ scm,
                          const float* __restrict__ bxb, float* __restrict__ dv,
                          float* __restrict__ dbx, float* __restrict__ out){
  int i=blockIdx.x*256+threadIdx.x;
  if(i>=6000) return;
  u32 g=order[i];
  float4 b=*(const float4*)(bxb+4*g);
  *(float4*)(dbx+4*i)=b;
  dv[i]=scm[g];
  *(float4*)(out+6000+4*i)=b;
  out[30000+i]=(float)(g%20u);
}

__global__ void k_dml(const u32* __restrict__ order, const float* __restrict__ m3, float* __restrict__ out){
  int idx=blockIdx.x*256+threadIdx.x;
  if(idx>=4704000) return;
  int e=idx/784, q=idx-e*784;
  u32 g=order[e];
  int r=(int)(g/20u), c=(int)(g%20u)+1;
  out[42000+idx]=m3[((size_t)r*784+q)*21+c];
}

extern "C" void kernel_launch(void* const* d_in, const int* in_sizes, int n_in,
                              void* d_out, int out_size, void* d_ws, size_t ws_size,
                              hipStream_t stream){
  (void)in_sizes; (void)n_in; (void)out_size;
  const float* features =(const float*)d_in[0];
  const float* rpn_logits=(const float*)d_in[1];
  const float* rpn_deltas=(const float*)d_in[2];
  const float* anchors  =(const float*)d_in[3];
  const float* W1=(const float*)d_in[4];
  const float* b1=(const float*)d_in[5];
  const float* Wc=(const float*)d_in[6];
  const float* bc=(const float*)d_in[7];
  const float* Wr=(const float*)d_in[8];
  const float* br=(const float*)d_in[9];
  const float* mw1=(const float*)d_in[10];
  const float* mb1=(const float*)d_in[11];
  const float* mwd=(const float*)d_in[12];
  const float* mbd=(const float*)d_in[13];
  const float* mwo=(const float*)d_in[14];
  const float* mbo=(const float*)d_in[15];
  float* out=(float*)d_out;

  char* base=(char*)d_ws; size_t off=0;
  auto alloc=[&](size_t bytes)->void*{ off=(off+255)&~(size_t)255; void* p=base+off; off+=bytes; return p; };
  u32* hist     =(u32*)alloc(65536*4);
  u32* cnt      =(u32*)alloc(64);
  float* scores =(float*)alloc(144000*4);
  float* rois_all=(float*)alloc((size_t)144000*16);
  u64* keys1    =(u64*)alloc(8192*8);
  u32* selidx   =(u32*)alloc(6000*4);
  float* boxes6k=(float*)alloc(6000*16);
  u64* masks    =(u64*)alloc((size_t)6000*94*8);
  float* rois300=(float*)alloc(300*16);
  u16* featT    =(u16*)alloc((size_t)16000*256*2);
  u16* roi7     =(u16*)alloc((size_t)300*49*256*2);
  u16* roi14    =(u16*)alloc((size_t)300*196*256*2);
  float* hbuf   =(float*)alloc((size_t)300*1024*4);
  float* WT     =(float*)alloc((size_t)105*1024*4);
  float* bxb    =(float*)alloc(6000*16);
  float* scm    =(float*)alloc(6000*4);
  u64* keys2    =(u64*)alloc(8192*8);
  u32* order    =(u32*)alloc(6000*4);
  float* dv     =(float*)alloc(6000*4);
  float* dbx    =(float*)alloc(6000*16);
  u16* x1       =(u16*)alloc((size_t)58800*128*2);
  u16* Bc1      =(u16*)alloc((size_t)2304*128*2);
  u16* B3t      =(u16*)alloc((size_t)4*128*128*2);
  float* m3     =(float*)alloc((size_t)58800*21*4);
  if(off > ws_size) return; // workspace too small; fail visibly

  hipMemsetAsync(hist,0,65536*4,stream);
  hipMemsetAsync(cnt,0,64,stream);

  k_prep<<<1152,256,0,stream>>>(mw1,mwd,Wc,Wr,Bc1,B3t,WT);
  k_featT<<<dim3(250,8),256,0,stream>>>(features,featT);

  k_rpn<<<563,256,0,stream>>>(rpn_logits,rpn_deltas,anchors,scores,rois_all,hist);
  k_findbin<<<1,1024,0,stream>>>(hist,cnt);
  k_compact<<<563,256,0,stream>>>(scores,cnt,keys1);
  k_sort8k<true><<<1,1024,0,stream>>>(keys1,cnt,0,selidx);
  k_gather6k<<<24,256,0,stream>>>(selidx,rois_all,boxes6k);
  k_masks<<<2048,256,0,stream>>>(boxes6k,nullptr,6000,0.7f,masks);
  k_scan1<<<1,128,0,stream>>>(masks,boxes6k,rois300);

  k_roialign<7><<<3675,256,0,stream>>>(rois300,featT,roi7);
  k_roialign<14><<<14700,256,0,stream>>>(rois300,featT,roi14);

  k_fc1<<<dim3(5,16),256,0,stream>>>(roi7,W1,b1,hbuf);
  k_conv1<<<919,256,0,stream>>>(roi14,Bc1,mb1,x1);
  k_conv2f<<<dim3(919,4),256,0,stream>>>(x1,B3t,mbd,mwo,mbo,m3);

  k_head<<<300,256,0,stream>>>(hbuf,WT,bc,br,rois300,bxb,scm,keys2,cnt);
  k_sort8k<false><<<1,1024,0,stream>>>(keys2,nullptr,6000,order);
  k_detprep<<<24,256,0,stream>>>(order,scm,bxb,dv,dbx,out);
  k_masks<<<512,256,0,stream>>>(dbx,cnt+1,0,0.5f,masks);
  k_scan2<<<1,64,0,stream>>>(masks,cnt,dv,out);
  k_dml<<<18375,256,0,stream>>>(order,m3,out);
}

// Round 3
// 1301.779 us; speedup vs baseline: 2.2591x; 1.0058x over previous
//
#include <hip/hip_runtime.h>
#include <stdint.h>

#pragma clang fp contract(off)

typedef unsigned int u32;
typedef unsigned short u16;
typedef unsigned long long u64;
typedef float f32x4 __attribute__((ext_vector_type(4)));
typedef u16 u16x8 __attribute__((ext_vector_type(8)));

#define DEV __device__ __forceinline__

DEV float bf2f(u16 u){ union{u32 i; float f;} v; v.i=((u32)u)<<16; return v.f; }
DEV u16 f2bf(float f){ union{float f; u32 i;} v; v.f=f; u32 b=v.i; return (u16)((b + 0x7fffu + ((b>>16)&1u))>>16); }
DEV u32 fkey(float f){ union{float f; u32 i;} v; v.f=f; u32 b=v.i; return (b&0x80000000u)? ~b : (b|0x80000000u); }
DEV float exp_cr(float x){ return (float)exp((double)x); }

DEV void mfma16(f32x4& d, u16x8 a, u16x8 b){
  asm volatile("v_mfma_f32_16x16x32_bf16 %0, %1, %2, %0" : "+v"(d) : "v"(a), "v"(b));
}

DEV void gload_lds16(const void* g, void* l){
  __builtin_amdgcn_global_load_lds((const __attribute__((address_space(1))) unsigned int*)g,
                                   (__attribute__((address_space(3))) unsigned int*)l, 16, 0, 0);
}

DEV u64 rfl64(u64 v){
  return ((u64)__builtin_amdgcn_readfirstlane((u32)(v>>32))<<32) |
         (u64)__builtin_amdgcn_readfirstlane((u32)v);
}

// ---------------- RPN: softmax score + decode + clip + filter + histogram ----------------
__global__ void k_rpn(const float* __restrict__ logits, const float* __restrict__ deltas,
                      const float* __restrict__ anchors, float* __restrict__ scores,
                      float* __restrict__ rois_all, u32* __restrict__ hist){
  int i=blockIdx.x*256+threadIdx.x;
  if(i>=144000) return;
  float l0=logits[2*i], l1=logits[2*i+1];
  float m=fmaxf(l0,l1);
  float e0=exp_cr(l0-m), e1=exp_cr(l1-m);
  float s=e1/(e0+e1);
  float a0=anchors[4*i],a1=anchors[4*i+1],a2=anchors[4*i+2],a3=anchors[4*i+3];
  float w=a2-a0, hh=a3-a1;
  float cx=a0+0.5f*w, cy=a1+0.5f*hh;
  float dx=deltas[4*i],dy=deltas[4*i+1],dwv=deltas[4*i+2],dhv=deltas[4*i+3];
  float pcx=dx*w+cx, pcy=dy*hh+cy;
  float pw=w*exp_cr(fminf(dwv,4.f)), ph=hh*exp_cr(fminf(dhv,4.f));
  float x1=fminf(fmaxf(pcx-0.5f*pw,0.f),2560.f);
  float y1=fminf(fmaxf(pcy-0.5f*ph,0.f),1600.f);
  float x2=fminf(fmaxf(pcx+0.5f*pw,0.f),2560.f);
  float y2=fminf(fmaxf(pcy+0.5f*ph,0.f),1600.f);
  float4 bb; bb.x=x1;bb.y=y1;bb.z=x2;bb.w=y2;
  *(float4*)(rois_all+4*i)=bb;
  bool ok=(x2-x1>=16.f)&&(y2-y1>=16.f);
  float sc=ok? s : -INFINITY;
  scores[i]=sc;
  if(ok) atomicAdd(&hist[fkey(sc)>>16],1u);
}

// ---------------- find 6000th-rank histogram bin ----------------
__global__ void k_findbin(const u32* __restrict__ hist, u32* __restrict__ cnt){
  __shared__ u32 cs[1024];
  int t=threadIdx.x;
  u32 s=0;
  for(int b=0;b<64;b++) s+=hist[t*64+b];
  cs[t]=s;
  __syncthreads();
  if(t==0){
    u32 acc=0; int tc=1023;
    for(; tc>=0; tc--){ if(acc+cs[tc]>=6000u) break; acc+=cs[tc]; }
    if(tc<0) tc=0;
    u32 B=(u32)tc*64u;
    for(int b=63;b>=0;b--){
      u32 hb=hist[tc*64+b];
      if(acc+hb>=6000u){ B=(u32)(tc*64+b); break; }
      acc+=hb;
    }
    cnt[2]=B;
  }
}

__global__ void k_compact(const float* __restrict__ scores, u32* __restrict__ cnt, u64* __restrict__ keys){
  int i=blockIdx.x*256+threadIdx.x;
  if(i>=144000) return;
  u32 u=fkey(scores[i]);
  if((u>>16) >= cnt[2]){
    u32 pos=atomicAdd(&cnt[0],1u);
    if(pos<8192u) keys[pos]=((u64)u<<32)|(u64)(~(u32)i);
  }
}

// ---------------- single-block bitonic sort (8192, descending), emit top-6000 indices ----------------
template<bool FROMCNT>
__global__ __launch_bounds__(1024) void k_sort8k(const u64* __restrict__ keys, const u32* __restrict__ cnt,
                                                 int n_fixed, u32* __restrict__ out_idx){
  __shared__ u64 K[8192];
  int n = FROMCNT ? (int)cnt[0] : n_fixed;
  if(n>8192) n=8192;
  for(int i=threadIdx.x;i<8192;i+=1024) K[i]=(i<n)? keys[i] : 0ull;
  __syncthreads();
  for(int k=2;k<=8192;k<<=1){
    for(int j=k>>1;j>0;j>>=1){
      for(int t=threadIdx.x;t<8192;t+=1024){
        int p=t^j;
        if(p>t){
          u64 a=K[t], b=K[p];
          bool up=((t&k)==0);
          if((a<b)==up){ K[t]=b; K[p]=a; }
        }
      }
      __syncthreads();
    }
  }
  for(int i=threadIdx.x;i<6000;i+=1024) out_idx[i]=~((u32)K[i]);
}

__global__ void k_gather6k(const u32* __restrict__ selidx, const float* __restrict__ rois_all,
                           float* __restrict__ boxes6k){
  int i=blockIdx.x*256+threadIdx.x;
  if(i>=6000) return;
  u32 g=selidx[i];
  float4 b=*(const float4*)(rois_all+4*g);
  *(float4*)(boxes6k+4*i)=b;
}

// ---------------- NMS bitmask build (grid-stride over row-words) ----------------
__global__ void k_masks(const float* __restrict__ boxes, const u32* __restrict__ limitPtr, int limitFixed,
                        float thresh, u64* __restrict__ masks){
  int limit = limitPtr? (int)*limitPtr : limitFixed;
  if(limit>6000) limit=6000;
  long total=(long)limit*94;
  int lane=threadIdx.x&63;
  long w0=(long)blockIdx.x*4 + (threadIdx.x>>6);
  long stride=(long)gridDim.x*4;
  for(long w=w0; w<total; w+=stride){
    int row=(int)(w/94), wrd=(int)(w-(long)row*94);
    int j=wrd*64+lane;
    float4 a=*(const float4*)(boxes+4*row);
    bool bit=false;
    if(j<limit && j>row){
      float4 b=*(const float4*)(boxes+4*j);
      float area_a=(a.z-a.x)*(a.w-a.y);
      float area_b=(b.z-b.x)*(b.w-b.y);
      float ltx=fmaxf(a.x,b.x), lty=fmaxf(a.y,b.y);
      float rbx=fminf(a.z,b.z), rby=fminf(a.w,b.w);
      float wv=fmaxf(rbx-ltx,0.f), hv=fmaxf(rby-lty,0.f);
      float inter=wv*hv;
      float iou=inter/(area_a+area_b-inter+1e-9f);
      bit = iou>thresh;
    }
    u64 mword=__ballot(bit);
    if(lane==0) masks[(size_t)row*94+wrd]=mword;
  }
}

// ---------------- chunked greedy NMS scan: DMA-staged, SALU chain, h-split update ----------------
__global__ __launch_bounds__(512) void k_scan1(const u64* __restrict__ masks, const float* __restrict__ boxes6k,
                                               float* __restrict__ rois300){
  __shared__ __align__(16) u64 stage[2][6016];
  __shared__ u64 psum[4][94];
  __shared__ u64 remv[94];
  __shared__ u64 keepw[94];
  __shared__ u32 rsel[304];
  int tid=threadIdx.x, lane=tid&63, wv=tid>>6;
  int w=tid&127, h=tid>>7;
  bool act=(w<94);
  if(tid<94) remv[tid]=0ull;
  const char* mb=(const char*)masks;
  // prologue: DMA chunk 0 (47 KB = 47 x 1KB wave-loads)
#pragma unroll
  for(int k=0;k<6;k++){
    int ins=wv+k*8;
    if(ins<47) gload_lds16(mb+(size_t)ins*1024+lane*16, (char*)&stage[0][0]+ins*1024);
  }
  asm volatile("s_waitcnt vmcnt(0)" ::: "memory");
  __syncthreads();
  int cur=0;
  for(int c=0;c<94;c++){
    int nxt=cur^1;
    // issue DMA for chunk c+1 (overlaps with this chunk's compute)
    if(c<93){
      const char* src=mb+(size_t)(c+1)*48128;
#pragma unroll
      for(int k=0;k<6;k++){
        int ins=wv+k*8;
        if(ins<47) gload_lds16(src+(size_t)ins*1024+lane*16, (char*)&stage[nxt][0]+ins*1024);
      }
    }
    // serial suppression chain on uniform scalars (SALU)
    u64 keep=~rfl64(remv[c]);
    if(c==93) keep&=0x0000FFFFFFFFFFFFull;
    const u64* sb=&stage[cur][0];
#pragma unroll
    for(int g=0;g<64;g+=8){
      u64 rr[8];
#pragma unroll
      for(int j2=0;j2<8;j2++) rr[j2]=rfl64(sb[(size_t)(g+j2)*94+c]);
#pragma unroll
      for(int j2=0;j2<8;j2++){
        u64 sel=(u64)0-((keep>>(g+j2))&1ull);
        keep&=~(rr[j2]&sel);
      }
    }
    // h-split accumulate of kept rows into psum
    if(act){
      u64 racc=0ull;
#pragma unroll
      for(int j2=0;j2<16;j2++){
        u64 v=sb[(size_t)(h*16+j2)*94+w];
        u64 sel=(u64)0-((keep>>(h*16+j2))&1ull);
        racc|=v&sel;
      }
      psum[h][w]=racc;
    }
    if(tid==0) keepw[c]=keep;
    __syncthreads();
    if(tid<94&&tid>c) remv[tid]|=psum[0][tid]|psum[1][tid]|psum[2][tid]|psum[3][tid];
    asm volatile("s_waitcnt vmcnt(0)" ::: "memory");
    __syncthreads();
    cur=nxt;
  }
  // selection: first 300 kept (index order), then pad with suppressed (index order)
  if(tid==0){
    int cntk=0;
    for(int c=0;c<94&&cntk<300;c++){
      u64 kw=keepw[c];
      while(kw&&cntk<300){ int b=__builtin_ctzll(kw); rsel[cntk++]=(u32)(c*64+b); kw&=kw-1; }
    }
    for(int c=0;c<94&&cntk<300;c++){
      u64 kw=~keepw[c];
      if(c==93) kw&=0x0000FFFFFFFFFFFFull;
      while(kw&&cntk<300){ int b=__builtin_ctzll(kw); rsel[cntk++]=(u32)(c*64+b); kw&=kw-1; }
    }
  }
  __syncthreads();
  for(int s2=tid;s2<300;s2+=512){
    u32 g=rsel[s2];
    float4 b=*(const float4*)(boxes6k+4*g);
    *(float4*)(rois300+4*s2)=b;
  }
}

__global__ __launch_bounds__(64) void k_scan2(const u64* __restrict__ masks, const u32* __restrict__ cnt,
                                              const float* __restrict__ dv, float* __restrict__ out){
  int lane=threadIdx.x;
  int V=(int)cnt[1]; if(V>6000)V=6000;
  bool ld=lane<47;
  const u64* mrow=masks+lane*2;
  u64 r0=0,r1=0;
  for(int i=0;i<V;i++){
    int w=i>>6;
    u64 v0=__shfl(r0,w>>1);
    u64 v1=__shfl(r1,w>>1);
    u64 word=(w&1)?v1:v0;
    if(!((word>>(i&63))&1ull)){
      if(ld){ r0|=mrow[(size_t)i*94]; r1|=mrow[(size_t)i*94+1]; }
    }
  }
  __shared__ u64 rem[94];
  if(ld){ rem[2*lane]=r0; rem[2*lane+1]=r1; }
  __syncthreads();
  for(int i=lane;i<6000;i+=64){
    bool kept=(i<V)&&!((rem[i>>6]>>(i&63))&1ull);
    out[i]=kept? dv[i]:0.0f;
    out[36000+i]=kept?1.0f:0.0f;
  }
}

// ---------------- feature transpose (C,H,W) f32 -> (H*W, C) bf16 ----------------
__global__ void k_featT(const float* __restrict__ feat, u16* __restrict__ featT){
  __shared__ float tile[32][65];
  int p0=blockIdx.x*64, c0=blockIdx.y*32;
  int t=threadIdx.x;
  int pp=t&63, cc=t>>6;
#pragma unroll
  for(int s=0;s<8;s++)
    tile[cc+s*4][pp]=feat[(size_t)(c0+cc+s*4)*16000+p0+pp];
  __syncthreads();
  int cw=t&31, pw=t>>5;
#pragma unroll
  for(int s=0;s<8;s++)
    featT[(size_t)(p0+pw+s*8)*256+c0+cw]=f2bf(tile[cw][pw+s*8]);
}

// ---------------- ROI align: one wave per sample point, 256 channels ----------------
template<int OUT>
__global__ void k_roialign(const float* __restrict__ rois, const u16* __restrict__ featT,
                           u16* __restrict__ outbuf){
  int wid=threadIdx.x>>6, lane=threadIdx.x&63;
  int gw=blockIdx.x*4+wid;
  if(gw>=300*OUT*OUT) return;
  int r=gw/(OUT*OUT), q=gw-r*(OUT*OUT), py=q/OUT, px=q-py*OUT;
  float x1=rois[4*r]*0.0625f;
  float y1=rois[4*r+1]*0.0625f;
  float x2=rois[4*r+2]*0.0625f;
  float y2=rois[4*r+3]*0.0625f;
  float bw=(x2-x1)/(float)OUT, bh=(y2-y1)/(float)OUT;
  float xx=x1+((float)px+0.5f)*bw-0.5f;
  float yy=y1+((float)py+0.5f)*bh-0.5f;
  float x0f=fminf(fmaxf(floorf(xx),0.f),158.f);
  float y0f=fminf(fmaxf(floorf(yy),0.f),98.f);
  float fx=fminf(fmaxf(xx-x0f,0.f),1.f);
  float fy=fminf(fmaxf(yy-y0f,0.f),1.f);
  int x0=(int)x0f, y0=(int)y0f;
  float w00=(1.f-fy)*(1.f-fx), w01=(1.f-fy)*fx, w10=fy*(1.f-fx), w11=fy*fx;
  const u16* p00=featT+((size_t)(y0*160+x0))*256+lane*4;
  ushort4 u00=*(const ushort4*)p00;
  ushort4 u01=*(const ushort4*)(p00+256);
  ushort4 u10=*(const ushort4*)(p00+40960);
  ushort4 u11=*(const ushort4*)(p00+41216);
  ushort4 o;
  o.x=f2bf(((bf2f(u00.x)*w00+bf2f(u01.x)*w01)+bf2f(u10.x)*w10)+bf2f(u11.x)*w11);
  o.y=f2bf(((bf2f(u00.y)*w00+bf2f(u01.y)*w01)+bf2f(u10.y)*w10)+bf2f(u11.y)*w11);
  o.z=f2bf(((bf2f(u00.z)*w00+bf2f(u01.z)*w01)+bf2f(u10.z)*w10)+bf2f(u11.z)*w11);
  o.w=f2bf(((bf2f(u00.w)*w00+bf2f(u01.w)*w01)+bf2f(u10.w)*w10)+bf2f(u11.w)*w11);
  *(ushort4*)(outbuf+(size_t)gw*256+lane*4)=o;
}

// ---------------- weight prep ----------------
__global__ void k_prep(const float* __restrict__ mw1, const float* __restrict__ mwd,
                       const float* __restrict__ Wc, const float* __restrict__ Wr,
                       u16* __restrict__ Bc1, u16* __restrict__ B3t, float* __restrict__ WT){
  int i=blockIdx.x*256+threadIdx.x;
  if(i<294912){
    int o=i/2304, rem=i-o*2304, c=rem/9, t=rem-(rem/9)*9;
    Bc1[((size_t)t*256+c)*128+o]=f2bf(mw1[i]);
  }
  if(i<65536){
    int co=i>>9, ci=(i>>2)&127, ky=(i>>1)&1, kxx=i&1;
    int z=ky*2+kxx;
    B3t[((size_t)z*128+co)*128+ci]=f2bf(mwd[i]);
  }
  if(i<107520){
    int j=i>>10, k=i&1023;
    WT[(size_t)j*1024+k]=(j<21)? Wc[(size_t)k*21+j] : Wr[(size_t)k*84+(j-21)];
  }
}

// ---------------- FC1: (300 x 12544) @ (12544 x 1024) bf16 MFMA, bias+relu ----------------
__global__ __launch_bounds__(256) void k_fc1(const u16* __restrict__ roi7, const float* __restrict__ W1,
                                             const float* __restrict__ b1, float* __restrict__ h){
  __shared__ u16 Asm[64][80];
  __shared__ u16 Bsm[64][80];
  int m0=blockIdx.x*64, n0=blockIdx.y*64;
  int tid=threadIdx.x, lane=tid&63, wid=tid>>6;
  int wr=wid>>1, wc=wid&1;
  f32x4 acc[2][2]={};
  for(int k0=0;k0<12544;k0+=64){
    {
      int row=tid>>2, seg=(tid&3)*16;
      int m=m0+row;
      u16x8 v0={0,0,0,0,0,0,0,0}, v1={0,0,0,0,0,0,0,0};
      if(m<300){
        const u16x8* s=(const u16x8*)(roi7+(size_t)m*12544+k0+seg);
        v0=s[0]; v1=s[1];
      }
      *(u16x8*)&Asm[row][seg]=v0;
      *(u16x8*)&Asm[row][seg+8]=v1;
    }
    {
      int kk=tid>>2, nseg=(tid&3)*16;
      int kg=k0+kk, p=kg>>8, c=kg&255;
      const float* src=W1+(size_t)(c*49+p)*1024+n0+nseg;
      float fv[16];
      *(float4*)(fv+0)=((const float4*)src)[0];
      *(float4*)(fv+4)=((const float4*)src)[1];
      *(float4*)(fv+8)=((const float4*)src)[2];
      *(float4*)(fv+12)=((const float4*)src)[3];
#pragma unroll
      for(int ii=0;ii<16;ii++) Bsm[nseg+ii][kk]=f2bf(fv[ii]);
    }
    __syncthreads();
#pragma unroll
    for(int ks=0;ks<2;ks++){
      int kb=ks*32+(lane>>4)*8;
      u16x8 a0=*(const u16x8*)&Asm[wr*32+(lane&15)][kb];
      u16x8 a1=*(const u16x8*)&Asm[wr*32+16+(lane&15)][kb];
      u16x8 b0=*(const u16x8*)&Bsm[wc*32+(lane&15)][kb];
      u16x8 b1v=*(const u16x8*)&Bsm[wc*32+16+(lane&15)][kb];
      mfma16(acc[0][0],a0,b0); mfma16(acc[0][1],a0,b1v);
      mfma16(acc[1][0],a1,b0); mfma16(acc[1][1],a1,b1v);
    }
    __syncthreads();
  }
  asm volatile("s_nop 7\ns_nop 7");
#pragma unroll
  for(int fm=0;fm<2;fm++)
#pragma unroll
  for(int fn=0;fn<2;fn++){
    int col=n0+wc*32+fn*16+(lane&15);
    float bias=b1[col];
#pragma unroll
    for(int j=0;j<4;j++){
      int row=m0+wr*32+fm*16+(lane>>4)*4+j;
      if(row<300) h[(size_t)row*1024+col]=fmaxf(acc[fm][fn][j]+bias,0.f);
    }
  }
}

// ---------------- conv1 3x3 pad1 as implicit GEMM: rows=300*196, K=2304, N=128 ----------------
__global__ __launch_bounds__(256) void k_conv1(const u16* __restrict__ roi14, const u16* __restrict__ Bc1,
                                               const float* __restrict__ mb1, u16* __restrict__ x1){
  __shared__ u16 Asm[64][48];
  __shared__ u16 Bsm[128][48];
  __shared__ int rowinf[64];
  int m0=blockIdx.x*64;
  int tid=threadIdx.x, lane=tid&63, wid=tid>>6;
  int wr=wid>>1, wc=wid&1;
  if(tid<64){
    int p=m0+tid;
    if(p<58800){ int r=p/196, q=p-r*196, y=q/14, x=q-y*14; rowinf[tid]=(r<<8)|(y<<4)|x; }
    else rowinf[tid]=-1;
  }
  __syncthreads();
  f32x4 acc[2][4]={};
  for(int it=0; it<72; ++it){
    int kg=it*32;
    int tap=kg>>8, c0=kg&255;
    int ky=tap/3, kx=tap-ky*3;
    {
      int ri=tid>>2, cl=(tid&3)*8;
      int rb=rowinf[ri];
      u16x8 v={0,0,0,0,0,0,0,0};
      if(rb>=0){
        int rr=rb>>8, y=(rb>>4)&15, x=rb&15;
        int yy=y+ky-1, xx=x+kx-1;
        if(yy>=0&&yy<14&&xx>=0&&xx<14)
          v=*(const u16x8*)(roi14+((size_t)((rr*14+yy)*14+xx))*256+c0+cl);
      }
      *(u16x8*)&Asm[ri][cl]=v;
    }
    {
      int kr=tid&31, cs2=(tid>>5)*16;
      const u16x8* s=(const u16x8*)(Bc1+(size_t)(kg+kr)*128+cs2);
      u16x8 v0=s[0], v1=s[1];
#pragma unroll
      for(int ii=0;ii<8;ii++){ Bsm[cs2+ii][kr]=v0[ii]; Bsm[cs2+8+ii][kr]=v1[ii]; }
    }
    __syncthreads();
    int kb=(lane>>4)*8;
    u16x8 a0=*(const u16x8*)&Asm[wr*32+(lane&15)][kb];
    u16x8 a1=*(const u16x8*)&Asm[wr*32+16+(lane&15)][kb];
#pragma unroll
    for(int fn=0;fn<4;fn++){
      u16x8 bv=*(const u16x8*)&Bsm[wc*64+fn*16+(lane&15)][kb];
      mfma16(acc[0][fn],a0,bv);
      mfma16(acc[1][fn],a1,bv);
    }
    __syncthreads();
  }
  asm volatile("s_nop 7\ns_nop 7");
#pragma unroll
  for(int fm=0;fm<2;fm++)
#pragma unroll
  for(int fn=0;fn<4;fn++){
    int col=wc*64+fn*16+(lane&15);
    float bias=mb1[col];
#pragma unroll
    for(int j=0;j<4;j++){
      int row=wr*32+fm*16+(lane>>4)*4+j;
      int p=m0+row;
      if(p<58800) x1[(size_t)p*128+col]=f2bf(fmaxf(acc[fm][fn][j]+bias,0.f));
    }
  }
}

// ---------------- conv2(deconv, per parity class) fused with conv3 1x1 ----------------
__global__ __launch_bounds__(256) void k_conv2f(const u16* __restrict__ x1, const u16* __restrict__ B3t,
                                                const float* __restrict__ mbd, const float* __restrict__ mwo,
                                                const float* __restrict__ mbo, float* __restrict__ m3){
  __shared__ u16 Asm[64][48];
  __shared__ u16 Bsm[128][48];
  __shared__ u16 X2[64][144];
  __shared__ u16 B4[32][144];
  int m0=blockIdx.x*64, z=blockIdx.y;
  int ky=z>>1, kx=z&1;
  int tid=threadIdx.x, lane=tid&63, wid=tid>>6;
  int wr=wid>>1, wc=wid&1;
  for(int i=tid;i<32*128;i+=256){
    int n=i>>7, k=i&127;
    B4[n][k]=(n<21)? f2bf(mwo[n*128+k]) : (u16)0;
  }
  f32x4 acc[2][4]={};
  for(int it=0;it<4;it++){
    int c0=it*32;
    {
      int ri=tid>>2, cl=(tid&3)*8;
      int p=m0+ri;
      u16x8 v={0,0,0,0,0,0,0,0};
      if(p<58800) v=*(const u16x8*)(x1+(size_t)p*128+c0+cl);
      *(u16x8*)&Asm[ri][cl]=v;
    }
    {
      int n=tid>>1, hf=tid&1;
      const u16x8* s=(const u16x8*)(B3t+((size_t)z*128+n)*128+c0+hf*16);
      u16x8 v0=s[0], v1=s[1];
      *(u16x8*)&Bsm[n][hf*16]=v0;
      *(u16x8*)&Bsm[n][hf*16+8]=v1;
    }
    __syncthreads();
    int kb=(lane>>4)*8;
    u16x8 a0=*(const u16x8*)&Asm[wr*32+(lane&15)][kb];
    u16x8 a1=*(const u16x8*)&Asm[wr*32+16+(lane&15)][kb];
#pragma unroll
    for(int fn=0;fn<4;fn++){
      u16x8 bv=*(const u16x8*)&Bsm[wc*64+fn*16+(lane&15)][kb];
      mfma16(acc[0][fn],a0,bv);
      mfma16(acc[1][fn],a1,bv);
    }
    __syncthreads();
  }
  asm volatile("s_nop 7\ns_nop 7");
#pragma unroll
  for(int fm=0;fm<2;fm++)
#pragma unroll
  for(int fn=0;fn<4;fn++){
    int col=wc*64+fn*16+(lane&15);
    float bias=mbd[col];
#pragma unroll
    for(int j=0;j<4;j++){
      int row=wr*32+fm*16+(lane>>4)*4+j;
      X2[row][col]=f2bf(fmaxf(acc[fm][fn][j]+bias,0.f));
    }
  }
  __syncthreads();
  f32x4 acc2[2]={};
#pragma unroll
  for(int ks=0;ks<4;ks++){
    int kb=ks*32+(lane>>4)*8;
    u16x8 a=*(const u16x8*)&X2[wid*16+(lane&15)][kb];
    u16x8 b0=*(const u16x8*)&B4[(lane&15)][kb];
    u16x8 b1v=*(const u16x8*)&B4[16+(lane&15)][kb];
    mfma16(acc2[0],a,b0);
    mfma16(acc2[1],a,b1v);
  }
  asm volatile("s_nop 7\ns_nop 7");
#pragma unroll
  for(int fn=0;fn<2;fn++){
    int n=fn*16+(lane&15);
    if(n<21){
      float bias=mbo[n];
#pragma unroll
      for(int j=0;j<4;j++){
        int row=wid*16+(lane>>4)*4+j;
        int p=m0+row;
        if(p<58800){
          int r=p/196, q=p-r*196, iy=q/14, ix=q-iy*14;
          int oy=2*iy+(1-ky), ox=2*ix+(1-kx);
          m3[(((size_t)r*28+oy)*28+ox)*21+n]=acc2[fn][j]+bias;
        }
      }
    }
  }
}

// ---------------- per-ROI head: logits, softmax, box decode, det keys ----------------
__global__ void k_head(const float* __restrict__ h, const float* __restrict__ WT,
                       const float* __restrict__ bc, const float* __restrict__ br,
                       const float* __restrict__ rois300, float* __restrict__ bxb,
                       float* __restrict__ scm, u64* __restrict__ keys2, u32* __restrict__ cnt){
  __shared__ float hs[1024];
  __shared__ float lg[105];
  __shared__ float scs[21];
  int r=blockIdx.x, t=threadIdx.x;
  for(int i=t;i<1024;i+=256) hs[i]=h[(size_t)r*1024+i];
  __syncthreads();
  if(t<105){
    const float* wrow=WT+(size_t)t*1024;
    float s=0.f;
    for(int k=0;k<1024;k+=4){
      float4 wv=*(const float4*)(wrow+k);
      s+=hs[k]*wv.x; s+=hs[k+1]*wv.y; s+=hs[k+2]*wv.z; s+=hs[k+3]*wv.w;
    }
    lg[t]=s+((t<21)?bc[t]:br[t-21]);
  }
  __syncthreads();
  if(t==0){
    float m=lg[0];
    for(int c=1;c<21;c++) m=fmaxf(m,lg[c]);
    float sum=0.f;
    for(int c=0;c<21;c++){ float e=exp_cr(lg[c]-m); scs[c]=e; sum+=e; }
    for(int c=0;c<21;c++) scs[c]=scs[c]/sum;
  }
  __syncthreads();
  if(t<20){
    int c=t+1;
    float rx1=rois300[4*r],ry1=rois300[4*r+1],rx2=rois300[4*r+2],ry2=rois300[4*r+3];
    float w=rx2-rx1, hh=ry2-ry1;
    float cx=rx1+0.5f*w, cy=ry1+0.5f*hh;
    float dx=lg[21+c*4+0], dy=lg[21+c*4+1], dwv=lg[21+c*4+2], dhv=lg[21+c*4+3];
    float pcx=dx*w+cx, pcy=dy*hh+cy;
    float pw=w*exp_cr(fminf(dwv,4.f)), ph=hh*exp_cr(fminf(dhv,4.f));
    float bx1=fminf(fmaxf(pcx-0.5f*pw,0.f),2560.f);
    float by1=fminf(fmaxf(pcy-0.5f*ph,0.f),1600.f);
    float bx2=fminf(fmaxf(pcx+0.5f*pw,0.f),2560.f);
    float by2=fminf(fmaxf(pcy+0.5f*ph,0.f),1600.f);
    int e=r*20+t;
    bxb[4*e]=bx1; bxb[4*e+1]=by1; bxb[4*e+2]=bx2; bxb[4*e+3]=by2;
    float sc=scs[c];
    bool valid=(sc>0.5f)&&(bx2-bx1>=1.f)&&(by2-by1>=1.f);
    float sv=valid? sc : -INFINITY;
    scm[e]=sv;
    keys2[e]=((u64)fkey(sv)<<32)|(u64)(~(u32)e);
    if(valid) atomicAdd(&cnt[1],1u);
  }
}

__global__ void k_detprep(const u32* __restrict__ order, const float* __restrict__ scm,
                          const float* __restrict__ bxb, float* __restrict__ dv,
                          float* __restrict__ dbx, float* __restrict__ out){
  int i=blockIdx.x*256+threadIdx.x;
  if(i>=6000) return;
  u32 g=order[i];
  float4 b=*(const float4*)(bxb+4*g);
  *(float4*)(dbx+4*i)=b;
  dv[i]=scm[g];
  *(float4*)(out+6000+4*i)=b;
  out[30000+i]=(float)(g%20u);
}

__global__ void k_dml(const u32* __restrict__ order, const float* __restrict__ m3, float* __restrict__ out){
  int idx=blockIdx.x*256+threadIdx.x;
  if(idx>=4704000) return;
  int e=idx/784, q=idx-e*784;
  u32 g=order[e];
  int r=(int)(g/20u), c=(int)(g%20u)+1;
  out[42000+idx]=m3[((size_t)r*784+q)*21+c];
}

extern "C" void kernel_launch(void* const* d_in, const int* in_sizes, int n_in,
                              void* d_out, int out_size, void* d_ws, size_t ws_size,
                              hipStream_t stream){
  (void)in_sizes; (void)n_in; (void)out_size;
  const float* features =(const float*)d_in[0];
  const float* rpn_logits=(const float*)d_in[1];
  const float* rpn_deltas=(const float*)d_in[2];
  const float* anchors  =(const float*)d_in[3];
  const float* W1=(const float*)d_in[4];
  const float* b1=(const float*)d_in[5];
  const float* Wc=(const float*)d_in[6];
  const float* bc=(const float*)d_in[7];
  const float* Wr=(const float*)d_in[8];
  const float* br=(const float*)d_in[9];
  const float* mw1=(const float*)d_in[10];
  const float* mb1=(const float*)d_in[11];
  const float* mwd=(const float*)d_in[12];
  const float* mbd=(const float*)d_in[13];
  const float* mwo=(const float*)d_in[14];
  const float* mbo=(const float*)d_in[15];
  float* out=(float*)d_out;

  char* base=(char*)d_ws; size_t off=0;
  auto alloc=[&](size_t bytes)->void*{ off=(off+255)&~(size_t)255; void* p=base+off; off+=bytes; return p; };
  u32* hist     =(u32*)alloc(65536*4);
  u32* cnt      =(u32*)alloc(64);
  float* scores =(float*)alloc(144000*4);
  float* rois_all=(float*)alloc((size_t)144000*16);
  u64* keys1    =(u64*)alloc(8192*8);
  u32* selidx   =(u32*)alloc(6000*4);
  float* boxes6k=(float*)alloc(6000*16);
  u64* masks    =(u64*)alloc((size_t)6016*94*8);   // 16 slack rows: k_scan1 DMA reads full 64-row chunks
  float* rois300=(float*)alloc(300*16);
  u16* featT    =(u16*)alloc((size_t)16000*256*2);
  u16* roi7     =(u16*)alloc((size_t)300*49*256*2);
  u16* roi14    =(u16*)alloc((size_t)300*196*256*2);
  float* hbuf   =(float*)alloc((size_t)300*1024*4);
  float* WT     =(float*)alloc((size_t)105*1024*4);
  float* bxb    =(float*)alloc(6000*16);
  float* scm    =(float*)alloc(6000*4);
  u64* keys2    =(u64*)alloc(8192*8);
  u32* order    =(u32*)alloc(6000*4);
  float* dv     =(float*)alloc(6000*4);
  float* dbx    =(float*)alloc(6000*16);
  u16* x1       =(u16*)alloc((size_t)58800*128*2);
  u16* Bc1      =(u16*)alloc((size_t)2304*128*2);
  u16* B3t      =(u16*)alloc((size_t)4*128*128*2);
  float* m3     =(float*)alloc((size_t)58800*21*4);
  if(off > ws_size) return; // workspace too small; fail visibly

  hipMemsetAsync(hist,0,65536*4,stream);
  hipMemsetAsync(cnt,0,64,stream);

  k_prep<<<1152,256,0,stream>>>(mw1,mwd,Wc,Wr,Bc1,B3t,WT);
  k_featT<<<dim3(250,8),256,0,stream>>>(features,featT);

  k_rpn<<<563,256,0,stream>>>(rpn_logits,rpn_deltas,anchors,scores,rois_all,hist);
  k_findbin<<<1,1024,0,stream>>>(hist,cnt);
  k_compact<<<563,256,0,stream>>>(scores,cnt,keys1);
  k_sort8k<true><<<1,1024,0,stream>>>(keys1,cnt,0,selidx);
  k_gather6k<<<24,256,0,stream>>>(selidx,rois_all,boxes6k);
  k_masks<<<2048,256,0,stream>>>(boxes6k,nullptr,6000,0.7f,masks);
  k_scan1<<<1,512,0,stream>>>(masks,boxes6k,rois300);

  k_roialign<7><<<3675,256,0,stream>>>(rois300,featT,roi7);
  k_roialign<14><<<14700,256,0,stream>>>(rois300,featT,roi14);

  k_fc1<<<dim3(5,16),256,0,stream>>>(roi7,W1,b1,hbuf);
  k_conv1<<<919,256,0,stream>>>(roi14,Bc1,mb1,x1);
  k_conv2f<<<dim3(919,4),256,0,stream>>>(x1,B3t,mbd,mwo,mbo,m3);

  k_head<<<300,256,0,stream>>>(hbuf,WT,bc,br,rois300,bxb,scm,keys2,cnt);
  k_sort8k<false><<<1,1024,0,stream>>>(keys2,nullptr,6000,order);
  k_detprep<<<24,256,0,stream>>>(order,scm,bxb,dv,dbx,out);
  k_masks<<<512,256,0,stream>>>(dbx,cnt+1,0,0.5f,masks);
  k_scan2<<<1,64,0,stream>>>(masks,cnt,dv,out);
  k_dml<<<18375,256,0,stream>>>(order,m3,out);
}

// Round 4
// 1290.982 us; speedup vs baseline: 2.2780x; 1.0084x over previous
//
#include <hip/hip_runtime.h>
#include <stdint.h>

#pragma clang fp contract(off)

typedef unsigned int u32;
typedef unsigned short u16;
typedef unsigned long long u64;
typedef float f32x4 __attribute__((ext_vector_type(4)));
typedef u16 u16x8 __attribute__((ext_vector_type(8)));

#define DEV __device__ __forceinline__

DEV float bf2f(u16 u){ union{u32 i; float f;} v; v.i=((u32)u)<<16; return v.f; }
DEV u16 f2bf(float f){ union{float f; u32 i;} v; v.f=f; u32 b=v.i; return (u16)((b + 0x7fffu + ((b>>16)&1u))>>16); }
DEV u32 fkey(float f){ union{float f; u32 i;} v; v.f=f; u32 b=v.i; return (b&0x80000000u)? ~b : (b|0x80000000u); }
DEV float exp_cr(float x){ return (float)exp((double)x); }

DEV void mfma16(f32x4& d, u16x8 a, u16x8 b){
  asm volatile("v_mfma_f32_16x16x32_bf16 %0, %1, %2, %0" : "+v"(d) : "v"(a), "v"(b));
}

DEV void gload_lds16(const void* g, void* l){
  __builtin_amdgcn_global_load_lds((const __attribute__((address_space(1))) unsigned int*)g,
                                   (__attribute__((address_space(3))) unsigned int*)l, 16, 0, 0);
}

DEV u64 rfl64(u64 v){
  return ((u64)__builtin_amdgcn_readfirstlane((u32)(v>>32))<<32) |
         (u64)__builtin_amdgcn_readfirstlane((u32)v);
}

// ---------------- RPN: softmax score + decode + clip + filter + histogram ----------------
__global__ void k_rpn(const float* __restrict__ logits, const float* __restrict__ deltas,
                      const float* __restrict__ anchors, float* __restrict__ scores,
                      float* __restrict__ rois_all, u32* __restrict__ hist){
  int i=blockIdx.x*256+threadIdx.x;
  if(i>=144000) return;
  float l0=logits[2*i], l1=logits[2*i+1];
  float m=fmaxf(l0,l1);
  float e0=exp_cr(l0-m), e1=exp_cr(l1-m);
  float s=e1/(e0+e1);
  float a0=anchors[4*i],a1=anchors[4*i+1],a2=anchors[4*i+2],a3=anchors[4*i+3];
  float w=a2-a0, hh=a3-a1;
  float cx=a0+0.5f*w, cy=a1+0.5f*hh;
  float dx=deltas[4*i],dy=deltas[4*i+1],dwv=deltas[4*i+2],dhv=deltas[4*i+3];
  float pcx=dx*w+cx, pcy=dy*hh+cy;
  float pw=w*exp_cr(fminf(dwv,4.f)), ph=hh*exp_cr(fminf(dhv,4.f));
  float x1=fminf(fmaxf(pcx-0.5f*pw,0.f),2560.f);
  float y1=fminf(fmaxf(pcy-0.5f*ph,0.f),1600.f);
  float x2=fminf(fmaxf(pcx+0.5f*pw,0.f),2560.f);
  float y2=fminf(fmaxf(pcy+0.5f*ph,0.f),1600.f);
  float4 bb; bb.x=x1;bb.y=y1;bb.z=x2;bb.w=y2;
  *(float4*)(rois_all+4*i)=bb;
  bool ok=(x2-x1>=16.f)&&(y2-y1>=16.f);
  float sc=ok? s : -INFINITY;
  scores[i]=sc;
  if(ok) atomicAdd(&hist[fkey(sc)>>16],1u);
}

// ---------------- find 6000th-rank histogram bin ----------------
__global__ void k_findbin(const u32* __restrict__ hist, u32* __restrict__ cnt){
  __shared__ u32 cs[1024];
  int t=threadIdx.x;
  u32 s=0;
  for(int b=0;b<64;b++) s+=hist[t*64+b];
  cs[t]=s;
  __syncthreads();
  if(t==0){
    u32 acc=0; int tc=1023;
    for(; tc>=0; tc--){ if(acc+cs[tc]>=6000u) break; acc+=cs[tc]; }
    if(tc<0) tc=0;
    u32 B=(u32)tc*64u;
    for(int b=63;b>=0;b--){
      u32 hb=hist[tc*64+b];
      if(acc+hb>=6000u){ B=(u32)(tc*64+b); break; }
      acc+=hb;
    }
    cnt[2]=B;
  }
}

__global__ void k_compact(const float* __restrict__ scores, u32* __restrict__ cnt, u64* __restrict__ keys){
  int i=blockIdx.x*256+threadIdx.x;
  if(i>=144000) return;
  u32 u=fkey(scores[i]);
  if((u>>16) >= cnt[2]){
    u32 pos=atomicAdd(&cnt[0],1u);
    if(pos<8192u) keys[pos]=((u64)u<<32)|(u64)(~(u32)i);
  }
}

// ---------------- single-block bitonic sort (8192, descending), emit top-6000 indices ----------------
template<bool FROMCNT>
__global__ __launch_bounds__(1024) void k_sort8k(const u64* __restrict__ keys, const u32* __restrict__ cnt,
                                                 int n_fixed, u32* __restrict__ out_idx){
  __shared__ u64 K[8192];
  int n = FROMCNT ? (int)cnt[0] : n_fixed;
  if(n>8192) n=8192;
  for(int i=threadIdx.x;i<8192;i+=1024) K[i]=(i<n)? keys[i] : 0ull;
  __syncthreads();
  for(int k=2;k<=8192;k<<=1){
    for(int j=k>>1;j>0;j>>=1){
      for(int t=threadIdx.x;t<8192;t+=1024){
        int p=t^j;
        if(p>t){
          u64 a=K[t], b=K[p];
          bool up=((t&k)==0);
          if((a<b)==up){ K[t]=b; K[p]=a; }
        }
      }
      __syncthreads();
    }
  }
  for(int i=threadIdx.x;i<6000;i+=1024) out_idx[i]=~((u32)K[i]);
}

__global__ void k_gather6k(const u32* __restrict__ selidx, const float* __restrict__ rois_all,
                           float* __restrict__ boxes6k){
  int i=blockIdx.x*256+threadIdx.x;
  if(i>=6000) return;
  u32 g=selidx[i];
  float4 b=*(const float4*)(rois_all+4*g);
  *(float4*)(boxes6k+4*i)=b;
}

// ---------------- NMS bitmask build; TR=1 stores transposed+rotated per-chunk layout ----------------
template<int TR>
__global__ void k_masks(const float* __restrict__ boxes, const u32* __restrict__ limitPtr, int limitFixed,
                        float thresh, u64* __restrict__ masks){
  int limit = limitPtr? (int)*limitPtr : limitFixed;
  if(limit>6000) limit=6000;
  long total=(long)limit*94;
  int lane=threadIdx.x&63;
  long w0=(long)blockIdx.x*4 + (threadIdx.x>>6);
  long stride=(long)gridDim.x*4;
  for(long w=w0; w<total; w+=stride){
    int row=(int)(w/94), wrd=(int)(w-(long)row*94);
    int j=wrd*64+lane;
    float4 a=*(const float4*)(boxes+4*row);
    bool bit=false;
    if(j<limit && j>row){
      float4 b=*(const float4*)(boxes+4*j);
      float area_a=(a.z-a.x)*(a.w-a.y);
      float area_b=(b.z-b.x)*(b.w-b.y);
      float ltx=fmaxf(a.x,b.x), lty=fmaxf(a.y,b.y);
      float rbx=fminf(a.z,b.z), rby=fminf(a.w,b.w);
      float wv=fmaxf(rbx-ltx,0.f), hv=fmaxf(rby-lty,0.f);
      float inter=wv*hv;
      float iou=inter/(area_a+area_b-inter+1e-9f);
      bit = iou>thresh;
    }
    u64 mword=__ballot(bit);
    if(lane==0){
      if(TR) masks[(size_t)(row>>6)*6016 + (size_t)wrd*64 + (((row&63)+wrd)&63)]=mword;
      else   masks[(size_t)row*94+wrd]=mword;
    }
  }
}

// ---------------- chunked greedy NMS scan: reg-resident readlane chain, triple-buffer DMA ----------------
__global__ __launch_bounds__(512) void k_scan1(const u64* __restrict__ masksT, const float* __restrict__ boxes6k,
                                               float* __restrict__ rois300){
  __shared__ __align__(16) u64 stage[3][6144];
  __shared__ u64 remv[94];
  __shared__ u64 keepw[94];
  __shared__ u32 rsel[304];
  int tid=threadIdx.x, lane=tid&63, wvid=tid>>6;
  int w=tid&127, h=tid>>7;
  bool act=(w<94);
  if(tid<94) remv[tid]=0ull;
  const char* mb=(const char*)masksT;
  // prologue: DMA chunks 0 and 1 (48KB each; 6 x 1KB per wave)
#pragma unroll
  for(int k=0;k<6;k++){
    int ins=wvid+k*8;
    gload_lds16(mb+(size_t)ins*1024+lane*16, (char*)&stage[0][0]+ins*1024);
  }
#pragma unroll
  for(int k=0;k<6;k++){
    int ins=wvid+k*8;
    gload_lds16(mb+48128+(size_t)ins*1024+lane*16, (char*)&stage[1][0]+ins*1024);
  }
  for(int c=0;c<94;c++){
    const u64* sb=&stage[c%3][0];
    if(c<93) asm volatile("s_waitcnt vmcnt(6)" ::: "memory");
    else     asm volatile("s_waitcnt vmcnt(0)" ::: "memory");
    asm volatile("s_waitcnt lgkmcnt(0)" ::: "memory");
    __builtin_amdgcn_s_barrier();
    // issue depth-2 prefetch (chunk c+2)
    if(c<92){
      const char* src=mb+(size_t)(c+2)*48128;
      char* dst=(char*)&stage[(c+2)%3][0];
#pragma unroll
      for(int k=0;k<6;k++){
        int ins=wvid+k*8;
        gload_lds16(src+(size_t)ins*1024+lane*16, dst+ins*1024);
      }
    }
    // serial chain: wave 0 only, register-resident diag via readlane, ff1-skip
    if(wvid==0){
      u64 keep=~rfl64(remv[c]);
      if(c==93) keep&=0x0000FFFFFFFFFFFFull;
      u64 dg=sb[(size_t)c*64+((lane+c)&63)];
      u32 dlo=(u32)dg, dhi=(u32)(dg>>32);
      u64 avail=keep;
      while(avail){
        u32 i=__builtin_amdgcn_readfirstlane((u32)__builtin_ctzll(avail));
        u64 row=((u64)__builtin_amdgcn_readlane(dhi,i)<<32)|(u64)__builtin_amdgcn_readlane(dlo,i);
        keep&=~row;
        avail&=~row;
        avail&=avail-1ull;
      }
      if(lane==0) keepw[c]=keep;
    }
    asm volatile("s_waitcnt lgkmcnt(0)" ::: "memory");
    __builtin_amdgcn_s_barrier();
    // parallel remv update: thread (w,h) ORs its 16 kept rows' word w
    if(act){
      u64 kp=rfl64(keepw[c]);
      u64 racc=0ull;
#pragma unroll
      for(int j2=0;j2<16;j2++){
        int r=h*16+j2;
        u64 v=sb[(size_t)w*64+((r+w)&63)];
        racc|=v&((u64)0-((kp>>r)&1ull));
      }
      if(racc) atomicOr(&remv[w],racc);
    }
  }
  asm volatile("s_waitcnt lgkmcnt(0)" ::: "memory");
  __builtin_amdgcn_s_barrier();
  // selection: first 300 kept (index order), then pad with suppressed (index order)
  if(tid==0){
    int cntk=0;
    for(int c=0;c<94&&cntk<300;c++){
      u64 kw=keepw[c];
      while(kw&&cntk<300){ int b=__builtin_ctzll(kw); rsel[cntk++]=(u32)(c*64+b); kw&=kw-1; }
    }
    for(int c=0;c<94&&cntk<300;c++){
      u64 kw=~keepw[c];
      if(c==93) kw&=0x0000FFFFFFFFFFFFull;
      while(kw&&cntk<300){ int b=__builtin_ctzll(kw); rsel[cntk++]=(u32)(c*64+b); kw&=kw-1; }
    }
  }
  __builtin_amdgcn_s_barrier();
  for(int s2=tid;s2<300;s2+=512){
    u32 g=rsel[s2];
    float4 b=*(const float4*)(boxes6k+4*g);
    *(float4*)(rois300+4*s2)=b;
  }
}

__global__ __launch_bounds__(64) void k_scan2(const u64* __restrict__ masks, const u32* __restrict__ cnt,
                                              const float* __restrict__ dv, float* __restrict__ out){
  int lane=threadIdx.x;
  int V=(int)cnt[1]; if(V>6000)V=6000;
  bool ld=lane<47;
  const u64* mrow=masks+lane*2;
  u64 r0=0,r1=0;
  for(int i=0;i<V;i++){
    int w=i>>6;
    u64 v0=__shfl(r0,w>>1);
    u64 v1=__shfl(r1,w>>1);
    u64 word=(w&1)?v1:v0;
    if(!((word>>(i&63))&1ull)){
      if(ld){ r0|=mrow[(size_t)i*94]; r1|=mrow[(size_t)i*94+1]; }
    }
  }
  __shared__ u64 rem[94];
  if(ld){ rem[2*lane]=r0; rem[2*lane+1]=r1; }
  __syncthreads();
  for(int i=lane;i<6000;i+=64){
    bool kept=(i<V)&&!((rem[i>>6]>>(i&63))&1ull);
    out[i]=kept? dv[i]:0.0f;
    out[36000+i]=kept?1.0f:0.0f;
  }
}

// ---------------- feature transpose (C,H,W) f32 -> (H*W, C) bf16 ----------------
__global__ void k_featT(const float* __restrict__ feat, u16* __restrict__ featT){
  __shared__ float tile[32][65];
  int p0=blockIdx.x*64, c0=blockIdx.y*32;
  int t=threadIdx.x;
  int pp=t&63, cc=t>>6;
#pragma unroll
  for(int s=0;s<8;s++)
    tile[cc+s*4][pp]=feat[(size_t)(c0+cc+s*4)*16000+p0+pp];
  __syncthreads();
  int cw=t&31, pw=t>>5;
#pragma unroll
  for(int s=0;s<8;s++)
    featT[(size_t)(p0+pw+s*8)*256+c0+cw]=f2bf(tile[cw][pw+s*8]);
}

// ---------------- ROI align: one wave per sample point, 256 channels ----------------
template<int OUT>
__global__ void k_roialign(const float* __restrict__ rois, const u16* __restrict__ featT,
                           u16* __restrict__ outbuf){
  int wid=threadIdx.x>>6, lane=threadIdx.x&63;
  int gw=blockIdx.x*4+wid;
  if(gw>=300*OUT*OUT) return;
  int r=gw/(OUT*OUT), q=gw-r*(OUT*OUT), py=q/OUT, px=q-py*OUT;
  float x1=rois[4*r]*0.0625f;
  float y1=rois[4*r+1]*0.0625f;
  float x2=rois[4*r+2]*0.0625f;
  float y2=rois[4*r+3]*0.0625f;
  float bw=(x2-x1)/(float)OUT, bh=(y2-y1)/(float)OUT;
  float xx=x1+((float)px+0.5f)*bw-0.5f;
  float yy=y1+((float)py+0.5f)*bh-0.5f;
  float x0f=fminf(fmaxf(floorf(xx),0.f),158.f);
  float y0f=fminf(fmaxf(floorf(yy),0.f),98.f);
  float fx=fminf(fmaxf(xx-x0f,0.f),1.f);
  float fy=fminf(fmaxf(yy-y0f,0.f),1.f);
  int x0=(int)x0f, y0=(int)y0f;
  float w00=(1.f-fy)*(1.f-fx), w01=(1.f-fy)*fx, w10=fy*(1.f-fx), w11=fy*fx;
  const u16* p00=featT+((size_t)(y0*160+x0))*256+lane*4;
  ushort4 u00=*(const ushort4*)p00;
  ushort4 u01=*(const ushort4*)(p00+256);
  ushort4 u10=*(const ushort4*)(p00+40960);
  ushort4 u11=*(const ushort4*)(p00+41216);
  ushort4 o;
  o.x=f2bf(((bf2f(u00.x)*w00+bf2f(u01.x)*w01)+bf2f(u10.x)*w10)+bf2f(u11.x)*w11);
  o.y=f2bf(((bf2f(u00.y)*w00+bf2f(u01.y)*w01)+bf2f(u10.y)*w10)+bf2f(u11.y)*w11);
  o.z=f2bf(((bf2f(u00.z)*w00+bf2f(u01.z)*w01)+bf2f(u10.z)*w10)+bf2f(u11.z)*w11);
  o.w=f2bf(((bf2f(u00.w)*w00+bf2f(u01.w)*w01)+bf2f(u10.w)*w10)+bf2f(u11.w)*w11);
  *(ushort4*)(outbuf+(size_t)gw*256+lane*4)=o;
}

// ---------------- weight prep ----------------
__global__ void k_prep(const float* __restrict__ mw1, const float* __restrict__ mwd,
                       const float* __restrict__ Wc, const float* __restrict__ Wr,
                       u16* __restrict__ Bc1, u16* __restrict__ B3t, float* __restrict__ WT){
  int i=blockIdx.x*256+threadIdx.x;
  if(i<294912){
    int o=i/2304, rem=i-o*2304, c=rem/9, t=rem-(rem/9)*9;
    Bc1[((size_t)t*256+c)*128+o]=f2bf(mw1[i]);
  }
  if(i<65536){
    int co=i>>9, ci=(i>>2)&127, ky=(i>>1)&1, kxx=i&1;
    int z=ky*2+kxx;
    B3t[((size_t)z*128+co)*128+ci]=f2bf(mwd[i]);
  }
  if(i<107520){
    int j=i>>10, k=i&1023;
    WT[(size_t)j*1024+k]=(j<21)? Wc[(size_t)k*21+j] : Wr[(size_t)k*84+(j-21)];
  }
}

// ---------------- FC1: (300 x 12544) @ (12544 x 1024) bf16 MFMA, bias+relu ----------------
__global__ __launch_bounds__(256) void k_fc1(const u16* __restrict__ roi7, const float* __restrict__ W1,
                                             const float* __restrict__ b1, float* __restrict__ h){
  __shared__ u16 Asm[64][80];
  __shared__ u16 Bsm[64][80];
  int m0=blockIdx.x*64, n0=blockIdx.y*64;
  int tid=threadIdx.x, lane=tid&63, wid=tid>>6;
  int wr=wid>>1, wc=wid&1;
  f32x4 acc[2][2]={};
  for(int k0=0;k0<12544;k0+=64){
    {
      int row=tid>>2, seg=(tid&3)*16;
      int m=m0+row;
      u16x8 v0={0,0,0,0,0,0,0,0}, v1={0,0,0,0,0,0,0,0};
      if(m<300){
        const u16x8* s=(const u16x8*)(roi7+(size_t)m*12544+k0+seg);
        v0=s[0]; v1=s[1];
      }
      *(u16x8*)&Asm[row][seg]=v0;
      *(u16x8*)&Asm[row][seg+8]=v1;
    }
    {
      int kk=tid>>2, nseg=(tid&3)*16;
      int kg=k0+kk, p=kg>>8, c=kg&255;
      const float* src=W1+(size_t)(c*49+p)*1024+n0+nseg;
      float fv[16];
      *(float4*)(fv+0)=((const float4*)src)[0];
      *(float4*)(fv+4)=((const float4*)src)[1];
      *(float4*)(fv+8)=((const float4*)src)[2];
      *(float4*)(fv+12)=((const float4*)src)[3];
#pragma unroll
      for(int ii=0;ii<16;ii++) Bsm[nseg+ii][kk]=f2bf(fv[ii]);
    }
    __syncthreads();
#pragma unroll
    for(int ks=0;ks<2;ks++){
      int kb=ks*32+(lane>>4)*8;
      u16x8 a0=*(const u16x8*)&Asm[wr*32+(lane&15)][kb];
      u16x8 a1=*(const u16x8*)&Asm[wr*32+16+(lane&15)][kb];
      u16x8 b0=*(const u16x8*)&Bsm[wc*32+(lane&15)][kb];
      u16x8 b1v=*(const u16x8*)&Bsm[wc*32+16+(lane&15)][kb];
      mfma16(acc[0][0],a0,b0); mfma16(acc[0][1],a0,b1v);
      mfma16(acc[1][0],a1,b0); mfma16(acc[1][1],a1,b1v);
    }
    __syncthreads();
  }
  asm volatile("s_nop 7\ns_nop 7");
#pragma unroll
  for(int fm=0;fm<2;fm++)
#pragma unroll
  for(int fn=0;fn<2;fn++){
    int col=n0+wc*32+fn*16+(lane&15);
    float bias=b1[col];
#pragma unroll
    for(int j=0;j<4;j++){
      int row=m0+wr*32+fm*16+(lane>>4)*4+j;
      if(row<300) h[(size_t)row*1024+col]=fmaxf(acc[fm][fn][j]+bias,0.f);
    }
  }
}

// ---------------- conv1 3x3 pad1 as implicit GEMM: rows=300*196, K=2304, N=128 ----------------
__global__ __launch_bounds__(256) void k_conv1(const u16* __restrict__ roi14, const u16* __restrict__ Bc1,
                                               const float* __restrict__ mb1, u16* __restrict__ x1){
  __shared__ u16 Asm[64][48];
  __shared__ u16 Bsm[128][48];
  __shared__ int rowinf[64];
  int m0=blockIdx.x*64;
  int tid=threadIdx.x, lane=tid&63, wid=tid>>6;
  int wr=wid>>1, wc=wid&1;
  if(tid<64){
    int p=m0+tid;
    if(p<58800){ int r=p/196, q=p-r*196, y=q/14, x=q-y*14; rowinf[tid]=(r<<8)|(y<<4)|x; }
    else rowinf[tid]=-1;
  }
  __syncthreads();
  f32x4 acc[2][4]={};
  for(int it=0; it<72; ++it){
    int kg=it*32;
    int tap=kg>>8, c0=kg&255;
    int ky=tap/3, kx=tap-ky*3;
    {
      int ri=tid>>2, cl=(tid&3)*8;
      int rb=rowinf[ri];
      u16x8 v={0,0,0,0,0,0,0,0};
      if(rb>=0){
        int rr=rb>>8, y=(rb>>4)&15, x=rb&15;
        int yy=y+ky-1, xx=x+kx-1;
        if(yy>=0&&yy<14&&xx>=0&&xx<14)
          v=*(const u16x8*)(roi14+((size_t)((rr*14+yy)*14+xx))*256+c0+cl);
      }
      *(u16x8*)&Asm[ri][cl]=v;
    }
    {
      int kr=tid&31, cs2=(tid>>5)*16;
      const u16x8* s=(const u16x8*)(Bc1+(size_t)(kg+kr)*128+cs2);
      u16x8 v0=s[0], v1=s[1];
#pragma unroll
      for(int ii=0;ii<8;ii++){ Bsm[cs2+ii][kr]=v0[ii]; Bsm[cs2+8+ii][kr]=v1[ii]; }
    }
    __syncthreads();
    int kb=(lane>>4)*8;
    u16x8 a0=*(const u16x8*)&Asm[wr*32+(lane&15)][kb];
    u16x8 a1=*(const u16x8*)&Asm[wr*32+16+(lane&15)][kb];
#pragma unroll
    for(int fn=0;fn<4;fn++){
      u16x8 bv=*(const u16x8*)&Bsm[wc*64+fn*16+(lane&15)][kb];
      mfma16(acc[0][fn],a0,bv);
      mfma16(acc[1][fn],a1,bv);
    }
    __syncthreads();
  }
  asm volatile("s_nop 7\ns_nop 7");
#pragma unroll
  for(int fm=0;fm<2;fm++)
#pragma unroll
  for(int fn=0;fn<4;fn++){
    int col=wc*64+fn*16+(lane&15);
    float bias=mb1[col];
#pragma unroll
    for(int j=0;j<4;j++){
      int row=wr*32+fm*16+(lane>>4)*4+j;
      int p=m0+row;
      if(p<58800) x1[(size_t)p*128+col]=f2bf(fmaxf(acc[fm][fn][j]+bias,0.f));
    }
  }
}

// ---------------- conv2(deconv, per parity class) fused with conv3 1x1 ----------------
// m3 layout: [r][class][28][28]
__global__ __launch_bounds__(256) void k_conv2f(const u16* __restrict__ x1, const u16* __restrict__ B3t,
                                                const float* __restrict__ mbd, const float* __restrict__ mwo,
                                                const float* __restrict__ mbo, float* __restrict__ m3){
  __shared__ u16 Asm[64][48];
  __shared__ u16 Bsm[128][48];
  __shared__ u16 X2[64][144];
  __shared__ u16 B4[32][144];
  int m0=blockIdx.x*64, z=blockIdx.y;
  int ky=z>>1, kx=z&1;
  int tid=threadIdx.x, lane=tid&63, wid=tid>>6;
  int wr=wid>>1, wc=wid&1;
  for(int i=tid;i<32*128;i+=256){
    int n=i>>7, k=i&127;
    B4[n][k]=(n<21)? f2bf(mwo[n*128+k]) : (u16)0;
  }
  f32x4 acc[2][4]={};
  for(int it=0;it<4;it++){
    int c0=it*32;
    {
      int ri=tid>>2, cl=(tid&3)*8;
      int p=m0+ri;
      u16x8 v={0,0,0,0,0,0,0,0};
      if(p<58800) v=*(const u16x8*)(x1+(size_t)p*128+c0+cl);
      *(u16x8*)&Asm[ri][cl]=v;
    }
    {
      int n=tid>>1, hf=tid&1;
      const u16x8* s=(const u16x8*)(B3t+((size_t)z*128+n)*128+c0+hf*16);
      u16x8 v0=s[0], v1=s[1];
      *(u16x8*)&Bsm[n][hf*16]=v0;
      *(u16x8*)&Bsm[n][hf*16+8]=v1;
    }
    __syncthreads();
    int kb=(lane>>4)*8;
    u16x8 a0=*(const u16x8*)&Asm[wr*32+(lane&15)][kb];
    u16x8 a1=*(const u16x8*)&Asm[wr*32+16+(lane&15)][kb];
#pragma unroll
    for(int fn=0;fn<4;fn++){
      u16x8 bv=*(const u16x8*)&Bsm[wc*64+fn*16+(lane&15)][kb];
      mfma16(acc[0][fn],a0,bv);
      mfma16(acc[1][fn],a1,bv);
    }
    __syncthreads();
  }
  asm volatile("s_nop 7\ns_nop 7");
#pragma unroll
  for(int fm=0;fm<2;fm++)
#pragma unroll
  for(int fn=0;fn<4;fn++){
    int col=wc*64+fn*16+(lane&15);
    float bias=mbd[col];
#pragma unroll
    for(int j=0;j<4;j++){
      int row=wr*32+fm*16+(lane>>4)*4+j;
      X2[row][col]=f2bf(fmaxf(acc[fm][fn][j]+bias,0.f));
    }
  }
  __syncthreads();
  f32x4 acc2[2]={};
#pragma unroll
  for(int ks=0;ks<4;ks++){
    int kb=ks*32+(lane>>4)*8;
    u16x8 a=*(const u16x8*)&X2[wid*16+(lane&15)][kb];
    u16x8 b0=*(const u16x8*)&B4[(lane&15)][kb];
    u16x8 b1v=*(const u16x8*)&B4[16+(lane&15)][kb];
    mfma16(acc2[0],a,b0);
    mfma16(acc2[1],a,b1v);
  }
  asm volatile("s_nop 7\ns_nop 7");
#pragma unroll
  for(int fn=0;fn<2;fn++){
    int n=fn*16+(lane&15);
    if(n<21){
      float bias=mbo[n];
#pragma unroll
      for(int j=0;j<4;j++){
        int row=wid*16+(lane>>4)*4+j;
        int p=m0+row;
        if(p<58800){
          int r=p/196, q=p-r*196, iy=q/14, ix=q-iy*14;
          int oy=2*iy+(1-ky), ox=2*ix+(1-kx);
          m3[((size_t)r*21+n)*784 + oy*28+ox]=acc2[fn][j]+bias;
        }
      }
    }
  }
}

// ---------------- per-ROI head: logits, softmax, box decode, det keys ----------------
__global__ void k_head(const float* __restrict__ h, const float* __restrict__ WT,
                       const float* __restrict__ bc, const float* __restrict__ br,
                       const float* __restrict__ rois300, float* __restrict__ bxb,
                       float* __restrict__ scm, u64* __restrict__ keys2, u32* __restrict__ cnt){
  __shared__ float hs[1024];
  __shared__ float lg[105];
  __shared__ float scs[21];
  int r=blockIdx.x, t=threadIdx.x;
  for(int i=t;i<1024;i+=256) hs[i]=h[(size_t)r*1024+i];
  __syncthreads();
  if(t<105){
    const float* wrow=WT+(size_t)t*1024;
    float s=0.f;
    for(int k=0;k<1024;k+=4){
      float4 wv=*(const float4*)(wrow+k);
      s+=hs[k]*wv.x; s+=hs[k+1]*wv.y; s+=hs[k+2]*wv.z; s+=hs[k+3]*wv.w;
    }
    lg[t]=s+((t<21)?bc[t]:br[t-21]);
  }
  __syncthreads();
  if(t==0){
    float m=lg[0];
    for(int c=1;c<21;c++) m=fmaxf(m,lg[c]);
    float sum=0.f;
    for(int c=0;c<21;c++){ float e=exp_cr(lg[c]-m); scs[c]=e; sum+=e; }
    for(int c=0;c<21;c++) scs[c]=scs[c]/sum;
  }
  __syncthreads();
  if(t<20){
    int c=t+1;
    float rx1=rois300[4*r],ry1=rois300[4*r+1],rx2=rois300[4*r+2],ry2=rois300[4*r+3];
    float w=rx2-rx1, hh=ry2-ry1;
    float cx=rx1+0.5f*w, cy=ry1+0.5f*hh;
    float dx=lg[21+c*4+0], dy=lg[21+c*4+1], dwv=lg[21+c*4+2], dhv=lg[21+c*4+3];
    float pcx=dx*w+cx, pcy=dy*hh+cy;
    float pw=w*exp_cr(fminf(dwv,4.f)), ph=hh*exp_cr(fminf(dhv,4.f));
    float bx1=fminf(fmaxf(pcx-0.5f*pw,0.f),2560.f);
    float by1=fminf(fmaxf(pcy-0.5f*ph,0.f),1600.f);
    float bx2=fminf(fmaxf(pcx+0.5f*pw,0.f),2560.f);
    float by2=fminf(fmaxf(pcy+0.5f*ph,0.f),1600.f);
    int e=r*20+t;
    bxb[4*e]=bx1; bxb[4*e+1]=by1; bxb[4*e+2]=bx2; bxb[4*e+3]=by2;
    float sc=scs[c];
    bool valid=(sc>0.5f)&&(bx2-bx1>=1.f)&&(by2-by1>=1.f);
    float sv=valid? sc : -INFINITY;
    scm[e]=sv;
    keys2[e]=((u64)fkey(sv)<<32)|(u64)(~(u32)e);
    if(valid) atomicAdd(&cnt[1],1u);
  }
}

__global__ void k_detprep(const u32* __restrict__ order, const float* __restrict__ scm,
                          const float* __restrict__ bxb, float* __restrict__ dv,
                          float* __restrict__ dbx, float* __restrict__ out){
  int i=blockIdx.x*256+threadIdx.x;
  if(i>=6000) return;
  u32 g=order[i];
  float4 b=*(const float4*)(bxb+4*g);
  *(float4*)(dbx+4*i)=b;
  dv[i]=scm[g];
  *(float4*)(out+6000+4*i)=b;
  out[30000+i]=(float)(g%20u);
}

__global__ void k_dml(const u32* __restrict__ order, const float* __restrict__ m3, float* __restrict__ out){
  int idx=blockIdx.x*256+threadIdx.x;
  if(idx>=4704000) return;
  int e=idx/784, q=idx-e*784;
  u32 g=order[e];
  int r=(int)(g/20u), c=(int)(g%20u)+1;
  out[42000+idx]=m3[((size_t)r*21+c)*784+q];
}

extern "C" void kernel_launch(void* const* d_in, const int* in_sizes, int n_in,
                              void* d_out, int out_size, void* d_ws, size_t ws_size,
                              hipStream_t stream){
  (void)in_sizes; (void)n_in; (void)out_size;
  const float* features =(const float*)d_in[0];
  const float* rpn_logits=(const float*)d_in[1];
  const float* rpn_deltas=(const float*)d_in[2];
  const float* anchors  =(const float*)d_in[3];
  const float* W1=(const float*)d_in[4];
  const float* b1=(const float*)d_in[5];
  const float* Wc=(const float*)d_in[6];
  const float* bc=(const float*)d_in[7];
  const float* Wr=(const float*)d_in[8];
  const float* br=(const float*)d_in[9];
  const float* mw1=(const float*)d_in[10];
  const float* mb1=(const float*)d_in[11];
  const float* mwd=(const float*)d_in[12];
  const float* mbd=(const float*)d_in[13];
  const float* mwo=(const float*)d_in[14];
  const float* mbo=(const float*)d_in[15];
  float* out=(float*)d_out;

  char* base=(char*)d_ws; size_t off=0;
  auto alloc=[&](size_t bytes)->void*{ off=(off+255)&~(size_t)255; void* p=base+off; off+=bytes; return p; };
  u32* hist     =(u32*)alloc(65536*4);
  u32* cnt      =(u32*)alloc(64);
  float* scores =(float*)alloc(144000*4);
  float* rois_all=(float*)alloc((size_t)144000*16);
  u64* keys1    =(u64*)alloc(8192*8);
  u32* selidx   =(u32*)alloc(6000*4);
  float* boxes6k=(float*)alloc(6000*16);
  u64* masksT   =(u64*)alloc((size_t)94*6016*8 + 1024);  // transposed+rotated chunks + DMA slack
  u64* masks    =(u64*)alloc((size_t)6000*94*8);          // row-major (det NMS)
  float* rois300=(float*)alloc(300*16);
  u16* featT    =(u16*)alloc((size_t)16000*256*2);
  u16* roi7     =(u16*)alloc((size_t)300*49*256*2);
  u16* roi14    =(u16*)alloc((size_t)300*196*256*2);
  float* hbuf   =(float*)alloc((size_t)300*1024*4);
  float* WT     =(float*)alloc((size_t)105*1024*4);
  float* bxb    =(float*)alloc(6000*16);
  float* scm    =(float*)alloc(6000*4);
  u64* keys2    =(u64*)alloc(8192*8);
  u32* order    =(u32*)alloc(6000*4);
  float* dv     =(float*)alloc(6000*4);
  float* dbx    =(float*)alloc(6000*16);
  u16* x1       =(u16*)alloc((size_t)58800*128*2);
  u16* Bc1      =(u16*)alloc((size_t)2304*128*2);
  u16* B3t      =(u16*)alloc((size_t)4*128*128*2);
  float* m3     =(float*)alloc((size_t)58800*21*4);
  if(off > ws_size) return; // workspace too small; fail visibly

  hipMemsetAsync(hist,0,65536*4,stream);
  hipMemsetAsync(cnt,0,64,stream);

  k_prep<<<1152,256,0,stream>>>(mw1,mwd,Wc,Wr,Bc1,B3t,WT);
  k_featT<<<dim3(250,8),256,0,stream>>>(features,featT);

  k_rpn<<<563,256,0,stream>>>(rpn_logits,rpn_deltas,anchors,scores,rois_all,hist);
  k_findbin<<<1,1024,0,stream>>>(hist,cnt);
  k_compact<<<563,256,0,stream>>>(scores,cnt,keys1);
  k_sort8k<true><<<1,1024,0,stream>>>(keys1,cnt,0,selidx);
  k_gather6k<<<24,256,0,stream>>>(selidx,rois_all,boxes6k);
  k_masks<1><<<2048,256,0,stream>>>(boxes6k,nullptr,6000,0.7f,masksT);
  k_scan1<<<1,512,0,stream>>>(masksT,boxes6k,rois300);

  k_roialign<7><<<3675,256,0,stream>>>(rois300,featT,roi7);
  k_roialign<14><<<14700,256,0,stream>>>(rois300,featT,roi14);

  k_fc1<<<dim3(5,16),256,0,stream>>>(roi7,W1,b1,hbuf);
  k_conv1<<<919,256,0,stream>>>(roi14,Bc1,mb1,x1);
  k_conv2f<<<dim3(919,4),256,0,stream>>>(x1,B3t,mbd,mwo,mbo,m3);

  k_head<<<300,256,0,stream>>>(hbuf,WT,bc,br,rois300,bxb,scm,keys2,cnt);
  k_sort8k<false><<<1,1024,0,stream>>>(keys2,nullptr,6000,order);
  k_detprep<<<24,256,0,stream>>>(order,scm,bxb,dv,dbx,out);
  k_masks<0><<<512,256,0,stream>>>(dbx,cnt+1,0,0.5f,masks);
  k_scan2<<<1,64,0,stream>>>(masks,cnt,dv,out);
  k_dml<<<18375,256,0,stream>>>(order,m3,out);
}

// Round 5
// 985.244 us; speedup vs baseline: 2.9849x; 1.3103x over previous
//
#include <hip/hip_runtime.h>
#include <stdint.h>

#pragma clang fp contract(off)

typedef unsigned int u32;
typedef unsigned short u16;
typedef unsigned long long u64;
typedef float f32x4 __attribute__((ext_vector_type(4)));
typedef u16 u16x8 __attribute__((ext_vector_type(8)));

#define DEV __device__ __forceinline__

DEV float bf2f(u16 u){ union{u32 i; float f;} v; v.i=((u32)u)<<16; return v.f; }
DEV u16 f2bf(float f){ union{float f; u32 i;} v; v.f=f; u32 b=v.i; return (u16)((b + 0x7fffu + ((b>>16)&1u))>>16); }
DEV u32 fkey(float f){ union{float f; u32 i;} v; v.f=f; u32 b=v.i; return (b&0x80000000u)? ~b : (b|0x80000000u); }
DEV float exp_cr(float x){ return (float)exp((double)x); }

DEV void mfma16(f32x4& d, u16x8 a, u16x8 b){
  asm volatile("v_mfma_f32_16x16x32_bf16 %0, %1, %2, %0" : "+v"(d) : "v"(a), "v"(b));
}

DEV void gload_lds16(const void* g, void* l){
  __builtin_amdgcn_global_load_lds((const __attribute__((address_space(1))) unsigned int*)g,
                                   (__attribute__((address_space(3))) unsigned int*)l, 16, 0, 0);
}

DEV u64 rfl64(u64 v){
  return ((u64)__builtin_amdgcn_readfirstlane((u32)(v>>32))<<32) |
         (u64)__builtin_amdgcn_readfirstlane((u32)v);
}

// ---------------- RPN: softmax score + decode + clip + filter + histogram ----------------
__global__ void k_rpn(const float* __restrict__ logits, const float* __restrict__ deltas,
                      const float* __restrict__ anchors, float* __restrict__ scores,
                      float* __restrict__ rois_all, u32* __restrict__ hist){
  int i=blockIdx.x*256+threadIdx.x;
  if(i>=144000) return;
  float l0=logits[2*i], l1=logits[2*i+1];
  float m=fmaxf(l0,l1);
  float e0=exp_cr(l0-m), e1=exp_cr(l1-m);
  float s=e1/(e0+e1);
  float a0=anchors[4*i],a1=anchors[4*i+1],a2=anchors[4*i+2],a3=anchors[4*i+3];
  float w=a2-a0, hh=a3-a1;
  float cx=a0+0.5f*w, cy=a1+0.5f*hh;
  float dx=deltas[4*i],dy=deltas[4*i+1],dwv=deltas[4*i+2],dhv=deltas[4*i+3];
  float pcx=dx*w+cx, pcy=dy*hh+cy;
  float pw=w*exp_cr(fminf(dwv,4.f)), ph=hh*exp_cr(fminf(dhv,4.f));
  float x1=fminf(fmaxf(pcx-0.5f*pw,0.f),2560.f);
  float y1=fminf(fmaxf(pcy-0.5f*ph,0.f),1600.f);
  float x2=fminf(fmaxf(pcx+0.5f*pw,0.f),2560.f);
  float y2=fminf(fmaxf(pcy+0.5f*ph,0.f),1600.f);
  float4 bb; bb.x=x1;bb.y=y1;bb.z=x2;bb.w=y2;
  *(float4*)(rois_all+4*i)=bb;
  bool ok=(x2-x1>=16.f)&&(y2-y1>=16.f);
  float sc=ok? s : -INFINITY;
  scores[i]=sc;
  if(ok) atomicAdd(&hist[fkey(sc)>>16],1u);
}

// ---------------- find 6000th-rank histogram bin ----------------
__global__ void k_findbin(const u32* __restrict__ hist, u32* __restrict__ cnt){
  __shared__ u32 cs[1024];
  int t=threadIdx.x;
  u32 s=0;
  for(int b=0;b<64;b++) s+=hist[t*64+b];
  cs[t]=s;
  __syncthreads();
  if(t==0){
    u32 acc=0; int tc=1023;
    for(; tc>=0; tc--){ if(acc+cs[tc]>=6000u) break; acc+=cs[tc]; }
    if(tc<0) tc=0;
    u32 B=(u32)tc*64u;
    for(int b=63;b>=0;b--){
      u32 hb=hist[tc*64+b];
      if(acc+hb>=6000u){ B=(u32)(tc*64+b); break; }
      acc+=hb;
    }
    cnt[2]=B;
  }
}

__global__ void k_compact(const float* __restrict__ scores, u32* __restrict__ cnt, u64* __restrict__ keys){
  int i=blockIdx.x*256+threadIdx.x;
  if(i>=144000) return;
  u32 u=fkey(scores[i]);
  if((u>>16) >= cnt[2]){
    u32 pos=atomicAdd(&cnt[0],1u);
    if(pos<8192u) keys[pos]=((u64)u<<32)|(u64)(~(u32)i);
  }
}

// ---------------- single-block bitonic sort (8192, descending), emit top-6000 indices ----------------
template<bool FROMCNT>
__global__ __launch_bounds__(1024) void k_sort8k(const u64* __restrict__ keys, const u32* __restrict__ cnt,
                                                 int n_fixed, u32* __restrict__ out_idx){
  __shared__ u64 K[8192];
  int n = FROMCNT ? (int)cnt[0] : n_fixed;
  if(n>8192) n=8192;
  for(int i=threadIdx.x;i<8192;i+=1024) K[i]=(i<n)? keys[i] : 0ull;
  __syncthreads();
  for(int k=2;k<=8192;k<<=1){
    for(int j=k>>1;j>0;j>>=1){
      for(int t=threadIdx.x;t<8192;t+=1024){
        int p=t^j;
        if(p>t){
          u64 a=K[t], b=K[p];
          bool up=((t&k)==0);
          if((a<b)==up){ K[t]=b; K[p]=a; }
        }
      }
      __syncthreads();
    }
  }
  for(int i=threadIdx.x;i<6000;i+=1024) out_idx[i]=~((u32)K[i]);
}

__global__ void k_gather6k(const u32* __restrict__ selidx, const float* __restrict__ rois_all,
                           float* __restrict__ boxes6k){
  int i=blockIdx.x*256+threadIdx.x;
  if(i>=6000) return;
  u32 g=selidx[i];
  float4 b=*(const float4*)(rois_all+4*g);
  *(float4*)(boxes6k+4*i)=b;
}

// ---------------- NMS bitmask build; TR=1 stores transposed+rotated per-chunk layout ----------------
template<int TR>
__global__ void k_masks(const float* __restrict__ boxes, const u32* __restrict__ limitPtr, int limitFixed,
                        float thresh, u64* __restrict__ masks){
  int limit = limitPtr? (int)*limitPtr : limitFixed;
  if(limit>6000) limit=6000;
  long total=(long)limit*94;
  int lane=threadIdx.x&63;
  long w0=(long)blockIdx.x*4 + (threadIdx.x>>6);
  long stride=(long)gridDim.x*4;
  for(long w=w0; w<total; w+=stride){
    int row=(int)(w/94), wrd=(int)(w-(long)row*94);
    int j=wrd*64+lane;
    float4 a=*(const float4*)(boxes+4*row);
    bool bit=false;
    if(j<limit && j>row){
      float4 b=*(const float4*)(boxes+4*j);
      float area_a=(a.z-a.x)*(a.w-a.y);
      float area_b=(b.z-b.x)*(b.w-b.y);
      float ltx=fmaxf(a.x,b.x), lty=fmaxf(a.y,b.y);
      float rbx=fminf(a.z,b.z), rby=fminf(a.w,b.w);
      float wv=fmaxf(rbx-ltx,0.f), hv=fmaxf(rby-lty,0.f);
      float inter=wv*hv;
      float iou=inter/(area_a+area_b-inter+1e-9f);
      bit = iou>thresh;
    }
    u64 mword=__ballot(bit);
    if(lane==0){
      if(TR) masks[(size_t)(row>>6)*6016 + (size_t)wrd*64 + (((row&63)+wrd)&63)]=mword;
      else   masks[(size_t)row*94+wrd]=mword;
    }
  }
}

// ---------------- chunked greedy NMS scan with EARLY EXIT at 300 kept ----------------
__global__ __launch_bounds__(512) void k_scan1(const u64* __restrict__ masksT, const float* __restrict__ boxes6k,
                                               float* __restrict__ rois300){
  __shared__ __align__(16) u64 stage[3][6144];
  __shared__ u64 remv[94];
  __shared__ u64 keepw[94];
  __shared__ u32 rsel[304];
  int tid=threadIdx.x, lane=tid&63, wvid=tid>>6;
  int w=tid&127, h=tid>>7;
  bool act=(w<94);
  if(tid<94) remv[tid]=0ull;
  const char* mb=(const char*)masksT;
  // prologue: DMA chunks 0 and 1 (48KB each; 6 x 1KB per wave)
#pragma unroll
  for(int k=0;k<6;k++){
    int ins=wvid+k*8;
    gload_lds16(mb+(size_t)ins*1024+lane*16, (char*)&stage[0][0]+ins*1024);
  }
#pragma unroll
  for(int k=0;k<6;k++){
    int ins=wvid+k*8;
    gload_lds16(mb+48128+(size_t)ins*1024+lane*16, (char*)&stage[1][0]+ins*1024);
  }
  int tot=0;
  for(int c=0;c<94;c++){
    const u64* sb=&stage[c%3][0];
    if(c<93) asm volatile("s_waitcnt vmcnt(6)" ::: "memory");
    else     asm volatile("s_waitcnt vmcnt(0)" ::: "memory");
    asm volatile("s_waitcnt lgkmcnt(0)" ::: "memory");
    __builtin_amdgcn_s_barrier();
    // issue depth-2 prefetch (chunk c+2)
    if(c<92){
      const char* src=mb+(size_t)(c+2)*48128;
      char* dst=(char*)&stage[(c+2)%3][0];
#pragma unroll
      for(int k=0;k<6;k++){
        int ins=wvid+k*8;
        gload_lds16(src+(size_t)ins*1024+lane*16, dst+ins*1024);
      }
    }
    // serial chain: wave 0 only, register-resident diag via readlane, ff1-skip
    if(wvid==0){
      u64 keep=~rfl64(remv[c]);
      if(c==93) keep&=0x0000FFFFFFFFFFFFull;
      u64 dg=sb[(size_t)c*64+((lane+c)&63)];
      u32 dlo=(u32)dg, dhi=(u32)(dg>>32);
      u64 avail=keep;
      while(avail){
        u32 i=__builtin_amdgcn_readfirstlane((u32)__builtin_ctzll(avail));
        u64 row=((u64)__builtin_amdgcn_readlane(dhi,i)<<32)|(u64)__builtin_amdgcn_readlane(dlo,i);
        keep&=~row;
        avail&=~row;
        avail&=avail-1ull;
      }
      if(lane==0) keepw[c]=keep;
    }
    asm volatile("s_waitcnt lgkmcnt(0)" ::: "memory");
    __builtin_amdgcn_s_barrier();
    // all threads read this chunk's keep word (uniform)
    u64 kp=rfl64(keepw[c]);
    // parallel remv update: thread (w,h) ORs its 16 kept rows' word w
    if(act){
      u64 racc=0ull;
#pragma unroll
      for(int j2=0;j2<16;j2++){
        int r=h*16+j2;
        u64 v=sb[(size_t)w*64+((r+w)&63)];
        racc|=v&((u64)0-((kp>>r)&1ull));
      }
      if(racc) atomicOr(&remv[w],racc);
    }
    // EARLY EXIT: decisions beyond the 300th kept box are never observed downstream
    tot+=(int)__popcll(kp);
    if(tot>=300) break;
  }
  asm volatile("s_waitcnt vmcnt(0) lgkmcnt(0)" ::: "memory");
  __builtin_amdgcn_s_barrier();
  // selection: first 300 kept (index order), then pad with suppressed (index order)
  if(tid==0){
    int cntk=0;
    for(int c=0;c<94&&cntk<300;c++){
      u64 kw=keepw[c];
      while(kw&&cntk<300){ int b=__builtin_ctzll(kw); rsel[cntk++]=(u32)(c*64+b); kw&=kw-1; }
    }
    for(int c=0;c<94&&cntk<300;c++){
      u64 kw=~keepw[c];
      if(c==93) kw&=0x0000FFFFFFFFFFFFull;
      while(kw&&cntk<300){ int b=__builtin_ctzll(kw); rsel[cntk++]=(u32)(c*64+b); kw&=kw-1; }
    }
  }
  __builtin_amdgcn_s_barrier();
  for(int s2=tid;s2<300;s2+=512){
    u32 g=rsel[s2];
    float4 b=*(const float4*)(boxes6k+4*g);
    *(float4*)(rois300+4*s2)=b;
  }
}

__global__ __launch_bounds__(64) void k_scan2(const u64* __restrict__ masks, const u32* __restrict__ cnt,
                                              const float* __restrict__ dv, float* __restrict__ out){
  int lane=threadIdx.x;
  int V=(int)cnt[1]; if(V>6000)V=6000;
  bool ld=lane<47;
  const u64* mrow=masks+lane*2;
  u64 r0=0,r1=0;
  for(int i=0;i<V;i++){
    int w=i>>6;
    u64 v0=__shfl(r0,w>>1);
    u64 v1=__shfl(r1,w>>1);
    u64 word=(w&1)?v1:v0;
    if(!((word>>(i&63))&1ull)){
      if(ld){ r0|=mrow[(size_t)i*94]; r1|=mrow[(size_t)i*94+1]; }
    }
  }
  __shared__ u64 rem[94];
  if(ld){ rem[2*lane]=r0; rem[2*lane+1]=r1; }
  __syncthreads();
  for(int i=lane;i<6000;i+=64){
    bool kept=(i<V)&&!((rem[i>>6]>>(i&63))&1ull);
    out[i]=kept? dv[i]:0.0f;
    out[36000+i]=kept?1.0f:0.0f;
  }
}

// ---------------- feature transpose (C,H,W) f32 -> (H*W, C) bf16 ----------------
__global__ void k_featT(const float* __restrict__ feat, u16* __restrict__ featT){
  __shared__ float tile[32][65];
  int p0=blockIdx.x*64, c0=blockIdx.y*32;
  int t=threadIdx.x;
  int pp=t&63, cc=t>>6;
#pragma unroll
  for(int s=0;s<8;s++)
    tile[cc+s*4][pp]=feat[(size_t)(c0+cc+s*4)*16000+p0+pp];
  __syncthreads();
  int cw=t&31, pw=t>>5;
#pragma unroll
  for(int s=0;s<8;s++)
    featT[(size_t)(p0+pw+s*8)*256+c0+cw]=f2bf(tile[cw][pw+s*8]);
}

// ---------------- ROI align: one wave per sample point, 256 channels ----------------
template<int OUT>
__global__ void k_roialign(const float* __restrict__ rois, const u16* __restrict__ featT,
                           u16* __restrict__ outbuf){
  int wid=threadIdx.x>>6, lane=threadIdx.x&63;
  int gw=blockIdx.x*4+wid;
  if(gw>=300*OUT*OUT) return;
  int r=gw/(OUT*OUT), q=gw-r*(OUT*OUT), py=q/OUT, px=q-py*OUT;
  float x1=rois[4*r]*0.0625f;
  float y1=rois[4*r+1]*0.0625f;
  float x2=rois[4*r+2]*0.0625f;
  float y2=rois[4*r+3]*0.0625f;
  float bw=(x2-x1)/(float)OUT, bh=(y2-y1)/(float)OUT;
  float xx=x1+((float)px+0.5f)*bw-0.5f;
  float yy=y1+((float)py+0.5f)*bh-0.5f;
  float x0f=fminf(fmaxf(floorf(xx),0.f),158.f);
  float y0f=fminf(fmaxf(floorf(yy),0.f),98.f);
  float fx=fminf(fmaxf(xx-x0f,0.f),1.f);
  float fy=fminf(fmaxf(yy-y0f,0.f),1.f);
  int x0=(int)x0f, y0=(int)y0f;
  float w00=(1.f-fy)*(1.f-fx), w01=(1.f-fy)*fx, w10=fy*(1.f-fx), w11=fy*fx;
  const u16* p00=featT+((size_t)(y0*160+x0))*256+lane*4;
  ushort4 u00=*(const ushort4*)p00;
  ushort4 u01=*(const ushort4*)(p00+256);
  ushort4 u10=*(const ushort4*)(p00+40960);
  ushort4 u11=*(const ushort4*)(p00+41216);
  ushort4 o;
  o.x=f2bf(((bf2f(u00.x)*w00+bf2f(u01.x)*w01)+bf2f(u10.x)*w10)+bf2f(u11.x)*w11);
  o.y=f2bf(((bf2f(u00.y)*w00+bf2f(u01.y)*w01)+bf2f(u10.y)*w10)+bf2f(u11.y)*w11);
  o.z=f2bf(((bf2f(u00.z)*w00+bf2f(u01.z)*w01)+bf2f(u10.z)*w10)+bf2f(u11.z)*w11);
  o.w=f2bf(((bf2f(u00.w)*w00+bf2f(u01.w)*w01)+bf2f(u10.w)*w10)+bf2f(u11.w)*w11);
  *(ushort4*)(outbuf+(size_t)gw*256+lane*4)=o;
}

// ---------------- weight prep ----------------
__global__ void k_prep(const float* __restrict__ mw1, const float* __restrict__ mwd,
                       const float* __restrict__ Wc, const float* __restrict__ Wr,
                       u16* __restrict__ Bc1, u16* __restrict__ B3t, float* __restrict__ WT){
  int i=blockIdx.x*256+threadIdx.x;
  if(i<294912){
    int o=i/2304, rem=i-o*2304, c=rem/9, t=rem-(rem/9)*9;
    Bc1[((size_t)t*256+c)*128+o]=f2bf(mw1[i]);
  }
  if(i<65536){
    int co=i>>9, ci=(i>>2)&127, ky=(i>>1)&1, kxx=i&1;
    int z=ky*2+kxx;
    B3t[((size_t)z*128+co)*128+ci]=f2bf(mwd[i]);
  }
  if(i<107520){
    int j=i>>10, k=i&1023;
    WT[(size_t)j*1024+k]=(j<21)? Wc[(size_t)k*21+j] : Wr[(size_t)k*84+(j-21)];
  }
}

// ---------------- FC1: (300 x 12544) @ (12544 x 1024) bf16 MFMA, bias+relu ----------------
__global__ __launch_bounds__(256) void k_fc1(const u16* __restrict__ roi7, const float* __restrict__ W1,
                                             const float* __restrict__ b1, float* __restrict__ h){
  __shared__ u16 Asm[64][80];
  __shared__ u16 Bsm[64][80];
  int m0=blockIdx.x*64, n0=blockIdx.y*64;
  int tid=threadIdx.x, lane=tid&63, wid=tid>>6;
  int wr=wid>>1, wc=wid&1;
  f32x4 acc[2][2]={};
  for(int k0=0;k0<12544;k0+=64){
    {
      int row=tid>>2, seg=(tid&3)*16;
      int m=m0+row;
      u16x8 v0={0,0,0,0,0,0,0,0}, v1={0,0,0,0,0,0,0,0};
      if(m<300){
        const u16x8* s=(const u16x8*)(roi7+(size_t)m*12544+k0+seg);
        v0=s[0]; v1=s[1];
      }
      *(u16x8*)&Asm[row][seg]=v0;
      *(u16x8*)&Asm[row][seg+8]=v1;
    }
    {
      int kk=tid>>2, nseg=(tid&3)*16;
      int kg=k0+kk, p=kg>>8, c=kg&255;
      const float* src=W1+(size_t)(c*49+p)*1024+n0+nseg;
      float fv[16];
      *(float4*)(fv+0)=((const float4*)src)[0];
      *(float4*)(fv+4)=((const float4*)src)[1];
      *(float4*)(fv+8)=((const float4*)src)[2];
      *(float4*)(fv+12)=((const float4*)src)[3];
#pragma unroll
      for(int ii=0;ii<16;ii++) Bsm[nseg+ii][kk]=f2bf(fv[ii]);
    }
    __syncthreads();
#pragma unroll
    for(int ks=0;ks<2;ks++){
      int kb=ks*32+(lane>>4)*8;
      u16x8 a0=*(const u16x8*)&Asm[wr*32+(lane&15)][kb];
      u16x8 a1=*(const u16x8*)&Asm[wr*32+16+(lane&15)][kb];
      u16x8 b0=*(const u16x8*)&Bsm[wc*32+(lane&15)][kb];
      u16x8 b1v=*(const u16x8*)&Bsm[wc*32+16+(lane&15)][kb];
      mfma16(acc[0][0],a0,b0); mfma16(acc[0][1],a0,b1v);
      mfma16(acc[1][0],a1,b0); mfma16(acc[1][1],a1,b1v);
    }
    __syncthreads();
  }
  asm volatile("s_nop 7\ns_nop 7");
#pragma unroll
  for(int fm=0;fm<2;fm++)
#pragma unroll
  for(int fn=0;fn<2;fn++){
    int col=n0+wc*32+fn*16+(lane&15);
    float bias=b1[col];
#pragma unroll
    for(int j=0;j<4;j++){
      int row=m0+wr*32+fm*16+(lane>>4)*4+j;
      if(row<300) h[(size_t)row*1024+col]=fmaxf(acc[fm][fn][j]+bias,0.f);
    }
  }
}

// ---------------- conv1 3x3 pad1 as implicit GEMM: rows=300*196, K=2304, N=128 ----------------
__global__ __launch_bounds__(256) void k_conv1(const u16* __restrict__ roi14, const u16* __restrict__ Bc1,
                                               const float* __restrict__ mb1, u16* __restrict__ x1){
  __shared__ u16 Asm[64][48];
  __shared__ u16 Bsm[128][48];
  __shared__ int rowinf[64];
  int m0=blockIdx.x*64;
  int tid=threadIdx.x, lane=tid&63, wid=tid>>6;
  int wr=wid>>1, wc=wid&1;
  if(tid<64){
    int p=m0+tid;
    if(p<58800){ int r=p/196, q=p-r*196, y=q/14, x=q-y*14; rowinf[tid]=(r<<8)|(y<<4)|x; }
    else rowinf[tid]=-1;
  }
  __syncthreads();
  f32x4 acc[2][4]={};
  for(int it=0; it<72; ++it){
    int kg=it*32;
    int tap=kg>>8, c0=kg&255;
    int ky=tap/3, kx=tap-ky*3;
    {
      int ri=tid>>2, cl=(tid&3)*8;
      int rb=rowinf[ri];
      u16x8 v={0,0,0,0,0,0,0,0};
      if(rb>=0){
        int rr=rb>>8, y=(rb>>4)&15, x=rb&15;
        int yy=y+ky-1, xx=x+kx-1;
        if(yy>=0&&yy<14&&xx>=0&&xx<14)
          v=*(const u16x8*)(roi14+((size_t)((rr*14+yy)*14+xx))*256+c0+cl);
      }
      *(u16x8*)&Asm[ri][cl]=v;
    }
    {
      int kr=tid&31, cs2=(tid>>5)*16;
      const u16x8* s=(const u16x8*)(Bc1+(size_t)(kg+kr)*128+cs2);
      u16x8 v0=s[0], v1=s[1];
#pragma unroll
      for(int ii=0;ii<8;ii++){ Bsm[cs2+ii][kr]=v0[ii]; Bsm[cs2+8+ii][kr]=v1[ii]; }
    }
    __syncthreads();
    int kb=(lane>>4)*8;
    u16x8 a0=*(const u16x8*)&Asm[wr*32+(lane&15)][kb];
    u16x8 a1=*(const u16x8*)&Asm[wr*32+16+(lane&15)][kb];
#pragma unroll
    for(int fn=0;fn<4;fn++){
      u16x8 bv=*(const u16x8*)&Bsm[wc*64+fn*16+(lane&15)][kb];
      mfma16(acc[0][fn],a0,bv);
      mfma16(acc[1][fn],a1,bv);
    }
    __syncthreads();
  }
  asm volatile("s_nop 7\ns_nop 7");
#pragma unroll
  for(int fm=0;fm<2;fm++)
#pragma unroll
  for(int fn=0;fn<4;fn++){
    int col=wc*64+fn*16+(lane&15);
    float bias=mb1[col];
#pragma unroll
    for(int j=0;j<4;j++){
      int row=wr*32+fm*16+(lane>>4)*4+j;
      int p=m0+row;
      if(p<58800) x1[(size_t)p*128+col]=f2bf(fmaxf(acc[fm][fn][j]+bias,0.f));
    }
  }
}

// ---------------- conv2(deconv, per parity class) fused with conv3 1x1 ----------------
// m3 layout: [r][class][28][28]
__global__ __launch_bounds__(256) void k_conv2f(const u16* __restrict__ x1, const u16* __restrict__ B3t,
                                                const float* __restrict__ mbd, const float* __restrict__ mwo,
                                                const float* __restrict__ mbo, float* __restrict__ m3){
  __shared__ u16 Asm[64][48];
  __shared__ u16 Bsm[128][48];
  __shared__ u16 X2[64][144];
  __shared__ u16 B4[32][144];
  int m0=blockIdx.x*64, z=blockIdx.y;
  int ky=z>>1, kx=z&1;
  int tid=threadIdx.x, lane=tid&63, wid=tid>>6;
  int wr=wid>>1, wc=wid&1;
  for(int i=tid;i<32*128;i+=256){
    int n=i>>7, k=i&127;
    B4[n][k]=(n<21)? f2bf(mwo[n*128+k]) : (u16)0;
  }
  f32x4 acc[2][4]={};
  for(int it=0;it<4;it++){
    int c0=it*32;
    {
      int ri=tid>>2, cl=(tid&3)*8;
      int p=m0+ri;
      u16x8 v={0,0,0,0,0,0,0,0};
      if(p<58800) v=*(const u16x8*)(x1+(size_t)p*128+c0+cl);
      *(u16x8*)&Asm[ri][cl]=v;
    }
    {
      int n=tid>>1, hf=tid&1;
      const u16x8* s=(const u16x8*)(B3t+((size_t)z*128+n)*128+c0+hf*16);
      u16x8 v0=s[0], v1=s[1];
      *(u16x8*)&Bsm[n][hf*16]=v0;
      *(u16x8*)&Bsm[n][hf*16+8]=v1;
    }
    __syncthreads();
    int kb=(lane>>4)*8;
    u16x8 a0=*(const u16x8*)&Asm[wr*32+(lane&15)][kb];
    u16x8 a1=*(const u16x8*)&Asm[wr*32+16+(lane&15)][kb];
#pragma unroll
    for(int fn=0;fn<4;fn++){
      u16x8 bv=*(const u16x8*)&Bsm[wc*64+fn*16+(lane&15)][kb];
      mfma16(acc[0][fn],a0,bv);
      mfma16(acc[1][fn],a1,bv);
    }
    __syncthreads();
  }
  asm volatile("s_nop 7\ns_nop 7");
#pragma unroll
  for(int fm=0;fm<2;fm++)
#pragma unroll
  for(int fn=0;fn<4;fn++){
    int col=wc*64+fn*16+(lane&15);
    float bias=mbd[col];
#pragma unroll
    for(int j=0;j<4;j++){
      int row=wr*32+fm*16+(lane>>4)*4+j;
      X2[row][col]=f2bf(fmaxf(acc[fm][fn][j]+bias,0.f));
    }
  }
  __syncthreads();
  f32x4 acc2[2]={};
#pragma unroll
  for(int ks=0;ks<4;ks++){
    int kb=ks*32+(lane>>4)*8;
    u16x8 a=*(const u16x8*)&X2[wid*16+(lane&15)][kb];
    u16x8 b0=*(const u16x8*)&B4[(lane&15)][kb];
    u16x8 b1v=*(const u16x8*)&B4[16+(lane&15)][kb];
    mfma16(acc2[0],a,b0);
    mfma16(acc2[1],a,b1v);
  }
  asm volatile("s_nop 7\ns_nop 7");
#pragma unroll
  for(int fn=0;fn<2;fn++){
    int n=fn*16+(lane&15);
    if(n<21){
      float bias=mbo[n];
#pragma unroll
      for(int j=0;j<4;j++){
        int row=wid*16+(lane>>4)*4+j;
        int p=m0+row;
        if(p<58800){
          int r=p/196, q=p-r*196, iy=q/14, ix=q-iy*14;
          int oy=2*iy+(1-ky), ox=2*ix+(1-kx);
          m3[((size_t)r*21+n)*784 + oy*28+ox]=acc2[fn][j]+bias;
        }
      }
    }
  }
}

// ---------------- per-ROI head: logits, softmax, box decode, det keys ----------------
__global__ void k_head(const float* __restrict__ h, const float* __restrict__ WT,
                       const float* __restrict__ bc, const float* __restrict__ br,
                       const float* __restrict__ rois300, float* __restrict__ bxb,
                       float* __restrict__ scm, u64* __restrict__ keys2, u32* __restrict__ cnt){
  __shared__ float hs[1024];
  __shared__ float lg[105];
  __shared__ float scs[21];
  int r=blockIdx.x, t=threadIdx.x;
  for(int i=t;i<1024;i+=256) hs[i]=h[(size_t)r*1024+i];
  __syncthreads();
  if(t<105){
    const float* wrow=WT+(size_t)t*1024;
    float s=0.f;
    for(int k=0;k<1024;k+=4){
      float4 wv=*(const float4*)(wrow+k);
      s+=hs[k]*wv.x; s+=hs[k+1]*wv.y; s+=hs[k+2]*wv.z; s+=hs[k+3]*wv.w;
    }
    lg[t]=s+((t<21)?bc[t]:br[t-21]);
  }
  __syncthreads();
  if(t==0){
    float m=lg[0];
    for(int c=1;c<21;c++) m=fmaxf(m,lg[c]);
    float sum=0.f;
    for(int c=0;c<21;c++){ float e=exp_cr(lg[c]-m); scs[c]=e; sum+=e; }
    for(int c=0;c<21;c++) scs[c]=scs[c]/sum;
  }
  __syncthreads();
  if(t<20){
    int c=t+1;
    float rx1=rois300[4*r],ry1=rois300[4*r+1],rx2=rois300[4*r+2],ry2=rois300[4*r+3];
    float w=rx2-rx1, hh=ry2-ry1;
    float cx=rx1+0.5f*w, cy=ry1+0.5f*hh;
    float dx=lg[21+c*4+0], dy=lg[21+c*4+1], dwv=lg[21+c*4+2], dhv=lg[21+c*4+3];
    float pcx=dx*w+cx, pcy=dy*hh+cy;
    float pw=w*exp_cr(fminf(dwv,4.f)), ph=hh*exp_cr(fminf(dhv,4.f));
    float bx1=fminf(fmaxf(pcx-0.5f*pw,0.f),2560.f);
    float by1=fminf(fmaxf(pcy-0.5f*ph,0.f),1600.f);
    float bx2=fminf(fmaxf(pcx+0.5f*pw,0.f),2560.f);
    float by2=fminf(fmaxf(pcy+0.5f*ph,0.f),1600.f);
    int e=r*20+t;
    bxb[4*e]=bx1; bxb[4*e+1]=by1; bxb[4*e+2]=bx2; bxb[4*e+3]=by2;
    float sc=scs[c];
    bool valid=(sc>0.5f)&&(bx2-bx1>=1.f)&&(by2-by1>=1.f);
    float sv=valid? sc : -INFINITY;
    scm[e]=sv;
    keys2[e]=((u64)fkey(sv)<<32)|(u64)(~(u32)e);
    if(valid) atomicAdd(&cnt[1],1u);
  }
}

__global__ void k_detprep(const u32* __restrict__ order, const float* __restrict__ scm,
                          const float* __restrict__ bxb, float* __restrict__ dv,
                          float* __restrict__ dbx, float* __restrict__ out){
  int i=blockIdx.x*256+threadIdx.x;
  if(i>=6000) return;
  u32 g=order[i];
  float4 b=*(const float4*)(bxb+4*g);
  *(float4*)(dbx+4*i)=b;
  dv[i]=scm[g];
  *(float4*)(out+6000+4*i)=b;
  out[30000+i]=(float)(g%20u);
}

__global__ void k_dml(const u32* __restrict__ order, const float* __restrict__ m3, float* __restrict__ out){
  int idx=blockIdx.x*256+threadIdx.x;
  if(idx>=4704000) return;
  int e=idx/784, q=idx-e*784;
  u32 g=order[e];
  int r=(int)(g/20u), c=(int)(g%20u)+1;
  out[42000+idx]=m3[((size_t)r*21+c)*784+q];
}

extern "C" void kernel_launch(void* const* d_in, const int* in_sizes, int n_in,
                              void* d_out, int out_size, void* d_ws, size_t ws_size,
                              hipStream_t stream){
  (void)in_sizes; (void)n_in; (void)out_size;
  const float* features =(const float*)d_in[0];
  const float* rpn_logits=(const float*)d_in[1];
  const float* rpn_deltas=(const float*)d_in[2];
  const float* anchors  =(const float*)d_in[3];
  const float* W1=(const float*)d_in[4];
  const float* b1=(const float*)d_in[5];
  const float* Wc=(const float*)d_in[6];
  const float* bc=(const float*)d_in[7];
  const float* Wr=(const float*)d_in[8];
  const float* br=(const float*)d_in[9];
  const float* mw1=(const float*)d_in[10];
  const float* mb1=(const float*)d_in[11];
  const float* mwd=(const float*)d_in[12];
  const float* mbd=(const float*)d_in[13];
  const float* mwo=(const float*)d_in[14];
  const float* mbo=(const float*)d_in[15];
  float* out=(float*)d_out;

  char* base=(char*)d_ws; size_t off=0;
  auto alloc=[&](size_t bytes)->void*{ off=(off+255)&~(size_t)255; void* p=base+off; off+=bytes; return p; };
  u32* hist     =(u32*)alloc(65536*4);
  u32* cnt      =(u32*)alloc(64);
  float* scores =(float*)alloc(144000*4);
  float* rois_all=(float*)alloc((size_t)144000*16);
  u64* keys1    =(u64*)alloc(8192*8);
  u32* selidx   =(u32*)alloc(6000*4);
  float* boxes6k=(float*)alloc(6000*16);
  u64* masksT   =(u64*)alloc((size_t)94*6016*8 + 1024);  // transposed+rotated chunks + DMA slack
  u64* masks    =(u64*)alloc((size_t)6000*94*8);          // row-major (det NMS)
  float* rois300=(float*)alloc(300*16);
  u16* featT    =(u16*)alloc((size_t)16000*256*2);
  u16* roi7     =(u16*)alloc((size_t)300*49*256*2);
  u16* roi14    =(u16*)alloc((size_t)300*196*256*2);
  float* hbuf   =(float*)alloc((size_t)300*1024*4);
  float* WT     =(float*)alloc((size_t)105*1024*4);
  float* bxb    =(float*)alloc(6000*16);
  float* scm    =(float*)alloc(6000*4);
  u64* keys2    =(u64*)alloc(8192*8);
  u32* order    =(u32*)alloc(6000*4);
  float* dv     =(float*)alloc(6000*4);
  float* dbx    =(float*)alloc(6000*16);
  u16* x1       =(u16*)alloc((size_t)58800*128*2);
  u16* Bc1      =(u16*)alloc((size_t)2304*128*2);
  u16* B3t      =(u16*)alloc((size_t)4*128*128*2);
  float* m3     =(float*)alloc((size_t)58800*21*4);
  if(off > ws_size) return; // workspace too small; fail visibly

  hipMemsetAsync(hist,0,65536*4,stream);
  hipMemsetAsync(cnt,0,64,stream);

  k_prep<<<1152,256,0,stream>>>(mw1,mwd,Wc,Wr,Bc1,B3t,WT);
  k_featT<<<dim3(250,8),256,0,stream>>>(features,featT);

  k_rpn<<<563,256,0,stream>>>(rpn_logits,rpn_deltas,anchors,scores,rois_all,hist);
  k_findbin<<<1,1024,0,stream>>>(hist,cnt);
  k_compact<<<563,256,0,stream>>>(scores,cnt,keys1);
  k_sort8k<true><<<1,1024,0,stream>>>(keys1,cnt,0,selidx);
  k_gather6k<<<24,256,0,stream>>>(selidx,rois_all,boxes6k);
  k_masks<1><<<2048,256,0,stream>>>(boxes6k,nullptr,6000,0.7f,masksT);
  k_scan1<<<1,512,0,stream>>>(masksT,boxes6k,rois300);

  k_roialign<7><<<3675,256,0,stream>>>(rois300,featT,roi7);
  k_roialign<14><<<14700,256,0,stream>>>(rois300,featT,roi14);

  k_fc1<<<dim3(5,16),256,0,stream>>>(roi7,W1,b1,hbuf);
  k_conv1<<<919,256,0,stream>>>(roi14,Bc1,mb1,x1);
  k_conv2f<<<dim3(919,4),256,0,stream>>>(x1,B3t,mbd,mwo,mbo,m3);

  k_head<<<300,256,0,stream>>>(hbuf,WT,bc,br,rois300,bxb,scm,keys2,cnt);
  k_sort8k<false><<<1,1024,0,stream>>>(keys2,nullptr,6000,order);
  k_detprep<<<24,256,0,stream>>>(order,scm,bxb,dv,dbx,out);
  k_masks<0><<<512,256,0,stream>>>(dbx,cnt+1,0,0.5f,masks);
  k_scan2<<<1,64,0,stream>>>(masks,cnt,dv,out);
  k_dml<<<18375,256,0,stream>>>(order,m3,out);
}

// Round 6
// 866.009 us; speedup vs baseline: 3.3959x; 1.1377x over previous
//
#include <hip/hip_runtime.h>
#include <stdint.h>

#pragma clang fp contract(off)

typedef unsigned int u32;
typedef unsigned short u16;
typedef unsigned long long u64;
typedef float f32x4 __attribute__((ext_vector_type(4)));
typedef u16 u16x8 __attribute__((ext_vector_type(8)));

#define DEV __device__ __forceinline__

DEV float bf2f(u16 u){ union{u32 i; float f;} v; v.i=((u32)u)<<16; return v.f; }
DEV u16 f2bf(float f){ union{float f; u32 i;} v; v.f=f; u32 b=v.i; return (u16)((b + 0x7fffu + ((b>>16)&1u))>>16); }
DEV u32 fkey(float f){ union{float f; u32 i;} v; v.f=f; u32 b=v.i; return (b&0x80000000u)? ~b : (b|0x80000000u); }
DEV float exp_cr(float x){ return (float)exp((double)x); }

DEV void mfma16(f32x4& d, u16x8 a, u16x8 b){
  asm volatile("v_mfma_f32_16x16x32_bf16 %0, %1, %2, %0" : "+v"(d) : "v"(a), "v"(b));
}

DEV void gload_lds16(const void* g, void* l){
  __builtin_amdgcn_global_load_lds((const __attribute__((address_space(1))) unsigned int*)g,
                                   (__attribute__((address_space(3))) unsigned int*)l, 16, 0, 0);
}

DEV u64 rfl64(u64 v){
  return ((u64)__builtin_amdgcn_readfirstlane((u32)(v>>32))<<32) |
         (u64)__builtin_amdgcn_readfirstlane((u32)v);
}

// ---------------- RPN: softmax score + decode + clip + filter + histogram ----------------
__global__ void k_rpn(const float* __restrict__ logits, const float* __restrict__ deltas,
                      const float* __restrict__ anchors, float* __restrict__ scores,
                      float* __restrict__ rois_all, u32* __restrict__ hist){
  int i=blockIdx.x*256+threadIdx.x;
  if(i>=144000) return;
  float l0=logits[2*i], l1=logits[2*i+1];
  float m=fmaxf(l0,l1);
  float e0=exp_cr(l0-m), e1=exp_cr(l1-m);
  float s=e1/(e0+e1);
  float a0=anchors[4*i],a1=anchors[4*i+1],a2=anchors[4*i+2],a3=anchors[4*i+3];
  float w=a2-a0, hh=a3-a1;
  float cx=a0+0.5f*w, cy=a1+0.5f*hh;
  float dx=deltas[4*i],dy=deltas[4*i+1],dwv=deltas[4*i+2],dhv=deltas[4*i+3];
  float pcx=dx*w+cx, pcy=dy*hh+cy;
  float pw=w*exp_cr(fminf(dwv,4.f)), ph=hh*exp_cr(fminf(dhv,4.f));
  float x1=fminf(fmaxf(pcx-0.5f*pw,0.f),2560.f);
  float y1=fminf(fmaxf(pcy-0.5f*ph,0.f),1600.f);
  float x2=fminf(fmaxf(pcx+0.5f*pw,0.f),2560.f);
  float y2=fminf(fmaxf(pcy+0.5f*ph,0.f),1600.f);
  float4 bb; bb.x=x1;bb.y=y1;bb.z=x2;bb.w=y2;
  *(float4*)(rois_all+4*i)=bb;
  bool ok=(x2-x1>=16.f)&&(y2-y1>=16.f);
  float sc=ok? s : -INFINITY;
  scores[i]=sc;
  if(ok) atomicAdd(&hist[fkey(sc)>>16],1u);
}

// ---------------- find 6000th-rank histogram bin ----------------
__global__ void k_findbin(const u32* __restrict__ hist, u32* __restrict__ cnt){
  __shared__ u32 cs[1024];
  int t=threadIdx.x;
  u32 s=0;
  for(int b=0;b<64;b++) s+=hist[t*64+b];
  cs[t]=s;
  __syncthreads();
  if(t==0){
    u32 acc=0; int tc=1023;
    for(; tc>=0; tc--){ if(acc+cs[tc]>=6000u) break; acc+=cs[tc]; }
    if(tc<0) tc=0;
    u32 B=(u32)tc*64u;
    for(int b=63;b>=0;b--){
      u32 hb=hist[tc*64+b];
      if(acc+hb>=6000u){ B=(u32)(tc*64+b); break; }
      acc+=hb;
    }
    cnt[2]=B;
  }
}

__global__ void k_compact(const float* __restrict__ scores, u32* __restrict__ cnt, u64* __restrict__ keys){
  int i=blockIdx.x*256+threadIdx.x;
  if(i>=144000) return;
  u32 u=fkey(scores[i]);
  if((u>>16) >= cnt[2]){
    u32 pos=atomicAdd(&cnt[0],1u);
    if(pos<8192u) keys[pos]=((u64)u<<32)|(u64)(~(u32)i);
  }
}

// ---------------- single-block bitonic sort (8192, descending), emit top-6000 indices ----------------
template<bool FROMCNT>
__global__ __launch_bounds__(1024) void k_sort8k(const u64* __restrict__ keys, const u32* __restrict__ cnt,
                                                 int n_fixed, u32* __restrict__ out_idx){
  __shared__ u64 K[8192];
  int n = FROMCNT ? (int)cnt[0] : n_fixed;
  if(n>8192) n=8192;
  for(int i=threadIdx.x;i<8192;i+=1024) K[i]=(i<n)? keys[i] : 0ull;
  __syncthreads();
  for(int k=2;k<=8192;k<<=1){
    for(int j=k>>1;j>0;j>>=1){
      for(int t=threadIdx.x;t<8192;t+=1024){
        int p=t^j;
        if(p>t){
          u64 a=K[t], b=K[p];
          bool up=((t&k)==0);
          if((a<b)==up){ K[t]=b; K[p]=a; }
        }
      }
      __syncthreads();
    }
  }
  for(int i=threadIdx.x;i<6000;i+=1024) out_idx[i]=~((u32)K[i]);
}

__global__ void k_gather6k(const u32* __restrict__ selidx, const float* __restrict__ rois_all,
                           float* __restrict__ boxes6k){
  int i=blockIdx.x*256+threadIdx.x;
  if(i>=6000) return;
  u32 g=selidx[i];
  float4 b=*(const float4*)(rois_all+4*g);
  *(float4*)(boxes6k+4*i)=b;
}

// ---------------- NMS bitmask build; TR=1 stores transposed+rotated per-chunk layout ----------------
template<int TR>
__global__ void k_masks(const float* __restrict__ boxes, const u32* __restrict__ limitPtr, int limitFixed,
                        float thresh, u64* __restrict__ masks){
  int limit = limitPtr? (int)*limitPtr : limitFixed;
  if(limit>6000) limit=6000;
  long total=(long)limit*94;
  int lane=threadIdx.x&63;
  long w0=(long)blockIdx.x*4 + (threadIdx.x>>6);
  long stride=(long)gridDim.x*4;
  for(long w=w0; w<total; w+=stride){
    int row=(int)(w/94), wrd=(int)(w-(long)row*94);
    int j=wrd*64+lane;
    float4 a=*(const float4*)(boxes+4*row);
    bool bit=false;
    if(j<limit && j>row){
      float4 b=*(const float4*)(boxes+4*j);
      float area_a=(a.z-a.x)*(a.w-a.y);
      float area_b=(b.z-b.x)*(b.w-b.y);
      float ltx=fmaxf(a.x,b.x), lty=fmaxf(a.y,b.y);
      float rbx=fminf(a.z,b.z), rby=fminf(a.w,b.w);
      float wv=fmaxf(rbx-ltx,0.f), hv=fmaxf(rby-lty,0.f);
      float inter=wv*hv;
      float iou=inter/(area_a+area_b-inter+1e-9f);
      bit = iou>thresh;
    }
    u64 mword=__ballot(bit);
    if(lane==0){
      if(TR) masks[(size_t)(row>>6)*6016 + (size_t)wrd*64 + (((row&63)+wrd)&63)]=mword;
      else   masks[(size_t)row*94+wrd]=mword;
    }
  }
}

// ---------------- chunked greedy NMS scan with EARLY EXIT at 300 kept ----------------
__global__ __launch_bounds__(512) void k_scan1(const u64* __restrict__ masksT, const float* __restrict__ boxes6k,
                                               float* __restrict__ rois300){
  __shared__ __align__(16) u64 stage[3][6144];
  __shared__ u64 remv[94];
  __shared__ u64 keepw[94];
  __shared__ u32 rsel[304];
  int tid=threadIdx.x, lane=tid&63, wvid=tid>>6;
  int w=tid&127, h=tid>>7;
  bool act=(w<94);
  if(tid<94) remv[tid]=0ull;
  const char* mb=(const char*)masksT;
  // prologue: DMA chunks 0 and 1 (48KB each; 6 x 1KB per wave)
#pragma unroll
  for(int k=0;k<6;k++){
    int ins=wvid+k*8;
    gload_lds16(mb+(size_t)ins*1024+lane*16, (char*)&stage[0][0]+ins*1024);
  }
#pragma unroll
  for(int k=0;k<6;k++){
    int ins=wvid+k*8;
    gload_lds16(mb+48128+(size_t)ins*1024+lane*16, (char*)&stage[1][0]+ins*1024);
  }
  int tot=0;
  for(int c=0;c<94;c++){
    const u64* sb=&stage[c%3][0];
    if(c<93) asm volatile("s_waitcnt vmcnt(6)" ::: "memory");
    else     asm volatile("s_waitcnt vmcnt(0)" ::: "memory");
    asm volatile("s_waitcnt lgkmcnt(0)" ::: "memory");
    __builtin_amdgcn_s_barrier();
    // issue depth-2 prefetch (chunk c+2)
    if(c<92){
      const char* src=mb+(size_t)(c+2)*48128;
      char* dst=(char*)&stage[(c+2)%3][0];
#pragma unroll
      for(int k=0;k<6;k++){
        int ins=wvid+k*8;
        gload_lds16(src+(size_t)ins*1024+lane*16, dst+ins*1024);
      }
    }
    // serial chain: wave 0 only, register-resident diag via readlane, ff1-skip
    if(wvid==0){
      u64 keep=~rfl64(remv[c]);
      if(c==93) keep&=0x0000FFFFFFFFFFFFull;
      u64 dg=sb[(size_t)c*64+((lane+c)&63)];
      u32 dlo=(u32)dg, dhi=(u32)(dg>>32);
      u64 avail=keep;
      while(avail){
        u32 i=__builtin_amdgcn_readfirstlane((u32)__builtin_ctzll(avail));
        u64 row=((u64)__builtin_amdgcn_readlane(dhi,i)<<32)|(u64)__builtin_amdgcn_readlane(dlo,i);
        keep&=~row;
        avail&=~row;
        avail&=avail-1ull;
      }
      if(lane==0) keepw[c]=keep;
    }
    asm volatile("s_waitcnt lgkmcnt(0)" ::: "memory");
    __builtin_amdgcn_s_barrier();
    // all threads read this chunk's keep word (uniform)
    u64 kp=rfl64(keepw[c]);
    // parallel remv update: thread (w,h) ORs its 16 kept rows' word w
    if(act){
      u64 racc=0ull;
#pragma unroll
      for(int j2=0;j2<16;j2++){
        int r=h*16+j2;
        u64 v=sb[(size_t)w*64+((r+w)&63)];
        racc|=v&((u64)0-((kp>>r)&1ull));
      }
      if(racc) atomicOr(&remv[w],racc);
    }
    // EARLY EXIT: decisions beyond the 300th kept box are never observed downstream
    tot+=(int)__popcll(kp);
    if(tot>=300) break;
  }
  asm volatile("s_waitcnt vmcnt(0) lgkmcnt(0)" ::: "memory");
  __builtin_amdgcn_s_barrier();
  // selection: first 300 kept (index order), then pad with suppressed (index order)
  if(tid==0){
    int cntk=0;
    for(int c=0;c<94&&cntk<300;c++){
      u64 kw=keepw[c];
      while(kw&&cntk<300){ int b=__builtin_ctzll(kw); rsel[cntk++]=(u32)(c*64+b); kw&=kw-1; }
    }
    for(int c=0;c<94&&cntk<300;c++){
      u64 kw=~keepw[c];
      if(c==93) kw&=0x0000FFFFFFFFFFFFull;
      while(kw&&cntk<300){ int b=__builtin_ctzll(kw); rsel[cntk++]=(u32)(c*64+b); kw&=kw-1; }
    }
  }
  __builtin_amdgcn_s_barrier();
  for(int s2=tid;s2<300;s2+=512){
    u32 g=rsel[s2];
    float4 b=*(const float4*)(boxes6k+4*g);
    *(float4*)(rois300+4*s2)=b;
  }
}

__global__ __launch_bounds__(64) void k_scan2(const u64* __restrict__ masks, const u32* __restrict__ cnt,
                                              const float* __restrict__ dv, float* __restrict__ out){
  int lane=threadIdx.x;
  int V=(int)cnt[1]; if(V>6000)V=6000;
  bool ld=lane<47;
  const u64* mrow=masks+lane*2;
  u64 r0=0,r1=0;
  for(int i=0;i<V;i++){
    int w=i>>6;
    u64 v0=__shfl(r0,w>>1);
    u64 v1=__shfl(r1,w>>1);
    u64 word=(w&1)?v1:v0;
    if(!((word>>(i&63))&1ull)){
      if(ld){ r0|=mrow[(size_t)i*94]; r1|=mrow[(size_t)i*94+1]; }
    }
  }
  __shared__ u64 rem[94];
  if(ld){ rem[2*lane]=r0; rem[2*lane+1]=r1; }
  __syncthreads();
  for(int i=lane;i<6000;i+=64){
    bool kept=(i<V)&&!((rem[i>>6]>>(i&63))&1ull);
    out[i]=kept? dv[i]:0.0f;
    out[36000+i]=kept?1.0f:0.0f;
  }
}

// ---------------- feature transpose (C,H,W) f32 -> (H*W, C) bf16 ----------------
__global__ void k_featT(const float* __restrict__ feat, u16* __restrict__ featT){
  __shared__ float tile[32][65];
  int p0=blockIdx.x*64, c0=blockIdx.y*32;
  int t=threadIdx.x;
  int pp=t&63, cc=t>>6;
#pragma unroll
  for(int s=0;s<8;s++)
    tile[cc+s*4][pp]=feat[(size_t)(c0+cc+s*4)*16000+p0+pp];
  __syncthreads();
  int cw=t&31, pw=t>>5;
#pragma unroll
  for(int s=0;s<8;s++)
    featT[(size_t)(p0+pw+s*8)*256+c0+cw]=f2bf(tile[cw][pw+s*8]);
}

// ---------------- ROI align: one wave per sample point, 256 channels ----------------
template<int OUT>
__global__ void k_roialign(const float* __restrict__ rois, const u16* __restrict__ featT,
                           u16* __restrict__ outbuf){
  int wid=threadIdx.x>>6, lane=threadIdx.x&63;
  int gw=blockIdx.x*4+wid;
  if(gw>=300*OUT*OUT) return;
  int r=gw/(OUT*OUT), q=gw-r*(OUT*OUT), py=q/OUT, px=q-py*OUT;
  float x1=rois[4*r]*0.0625f;
  float y1=rois[4*r+1]*0.0625f;
  float x2=rois[4*r+2]*0.0625f;
  float y2=rois[4*r+3]*0.0625f;
  float bw=(x2-x1)/(float)OUT, bh=(y2-y1)/(float)OUT;
  float xx=x1+((float)px+0.5f)*bw-0.5f;
  float yy=y1+((float)py+0.5f)*bh-0.5f;
  float x0f=fminf(fmaxf(floorf(xx),0.f),158.f);
  float y0f=fminf(fmaxf(floorf(yy),0.f),98.f);
  float fx=fminf(fmaxf(xx-x0f,0.f),1.f);
  float fy=fminf(fmaxf(yy-y0f,0.f),1.f);
  int x0=(int)x0f, y0=(int)y0f;
  float w00=(1.f-fy)*(1.f-fx), w01=(1.f-fy)*fx, w10=fy*(1.f-fx), w11=fy*fx;
  const u16* p00=featT+((size_t)(y0*160+x0))*256+lane*4;
  ushort4 u00=*(const ushort4*)p00;
  ushort4 u01=*(const ushort4*)(p00+256);
  ushort4 u10=*(const ushort4*)(p00+40960);
  ushort4 u11=*(const ushort4*)(p00+41216);
  ushort4 o;
  o.x=f2bf(((bf2f(u00.x)*w00+bf2f(u01.x)*w01)+bf2f(u10.x)*w10)+bf2f(u11.x)*w11);
  o.y=f2bf(((bf2f(u00.y)*w00+bf2f(u01.y)*w01)+bf2f(u10.y)*w10)+bf2f(u11.y)*w11);
  o.z=f2bf(((bf2f(u00.z)*w00+bf2f(u01.z)*w01)+bf2f(u10.z)*w10)+bf2f(u11.z)*w11);
  o.w=f2bf(((bf2f(u00.w)*w00+bf2f(u01.w)*w01)+bf2f(u10.w)*w10)+bf2f(u11.w)*w11);
  *(ushort4*)(outbuf+(size_t)gw*256+lane*4)=o;
}

// ---------------- weight prep ----------------
__global__ void k_prep(const float* __restrict__ mw1, const float* __restrict__ mwd,
                       const float* __restrict__ Wc, const float* __restrict__ Wr,
                       u16* __restrict__ Bc1, u16* __restrict__ B3t, float* __restrict__ WT){
  int i=blockIdx.x*256+threadIdx.x;
  if(i<294912){
    int o=i/2304, rem=i-o*2304, c=rem/9, t=rem-(rem/9)*9;
    Bc1[((size_t)t*256+c)*128+o]=f2bf(mw1[i]);
  }
  if(i<65536){
    int co=i>>9, ci=(i>>2)&127, ky=(i>>1)&1, kxx=i&1;
    int z=ky*2+kxx;
    B3t[((size_t)z*128+co)*128+ci]=f2bf(mwd[i]);
  }
  if(i<107520){
    int j=i>>10, k=i&1023;
    WT[(size_t)j*1024+k]=(j<21)? Wc[(size_t)k*21+j] : Wr[(size_t)k*84+(j-21)];
  }
}

// ---------------- FC1 split-K: grid(KS=14, NS=16); each block: all 300 rows x 64 cols x 896 k ----------------
// A (roi7, bf16 [m][k]) read directly from global as MFMA fragments; B staged via LDS transpose (dbuf).
__global__ __launch_bounds__(256) void k_fc1b(const u16* __restrict__ roi7, const float* __restrict__ W1,
                                              float* __restrict__ hp){
  __shared__ u16 Bsm[2][64][72];
  int ks=blockIdx.x, bn=blockIdx.y;
  int kbase=ks*896, n0=bn*64;
  int tid=threadIdx.x, lane=tid&63, wid=tid>>6;
  int wr=wid>>1, wc=wid&1;
  f32x4 acc[5][2][2]={};
  auto stageB=[&](int it,int buf){
    int r=tid>>2, cs=(tid&3)*16;
    int kg=kbase+it*64+r;
    int p=kg>>8, c=kg&255;
    const float* src=W1+(size_t)(c*49+p)*1024+n0+cs;
    float fv[16];
    *(float4*)(fv+0)=((const float4*)src)[0];
    *(float4*)(fv+4)=((const float4*)src)[1];
    *(float4*)(fv+8)=((const float4*)src)[2];
    *(float4*)(fv+12)=((const float4*)src)[3];
#pragma unroll
    for(int ii=0;ii<16;ii++) Bsm[buf][cs+ii][r]=f2bf(fv[ii]);
  };
  stageB(0,0);
  __syncthreads();
  int buf=0;
  for(int it=0;it<14;it++){
    int kk=kbase+it*64;
    // read all B fragments for this iter first
    u16x8 bfr[2][2];
#pragma unroll
    for(int ks2=0;ks2<2;ks2++){
      int kb=ks2*32+(lane>>4)*8;
#pragma unroll
      for(int fn=0;fn<2;fn++)
        bfr[ks2][fn]=*(const u16x8*)&Bsm[buf][wc*32+fn*16+(lane&15)][kb];
    }
    // stage next B while computing
    if(it<13) stageB(it+1,buf^1);
    // MFMA with A fragments loaded directly from global (roi7 is k-contiguous)
#pragma unroll
    for(int ks2=0;ks2<2;ks2++){
      int kb=ks2*32+(lane>>4)*8;
#pragma unroll
      for(int mt=0;mt<5;mt++){
#pragma unroll
        for(int fm=0;fm<2;fm++){
          int m=mt*64+wr*32+fm*16+(lane&15);
          u16x8 av={0,0,0,0,0,0,0,0};
          if(m<300) av=*(const u16x8*)(roi7+(size_t)m*12544+kk+kb);
          mfma16(acc[mt][fm][0],av,bfr[ks2][0]);
          mfma16(acc[mt][fm][1],av,bfr[ks2][1]);
        }
      }
    }
    __syncthreads();
    buf^=1;
  }
  asm volatile("s_nop 7\ns_nop 7");
  size_t base=((size_t)(ks*16+bn))*300*64;
#pragma unroll
  for(int mt=0;mt<5;mt++)
#pragma unroll
  for(int fm=0;fm<2;fm++)
#pragma unroll
  for(int fn=0;fn<2;fn++){
    int col=wc*32+fn*16+(lane&15);
#pragma unroll
    for(int j=0;j<4;j++){
      int row=mt*64+wr*32+fm*16+(lane>>4)*4+j;
      if(row<300) hp[base+(size_t)row*64+col]=acc[mt][fm][fn][j];
    }
  }
}

// reduce 14 k-split partials + bias + relu -> h[300][1024]
__global__ void k_fc1red(const float* __restrict__ hp, const float* __restrict__ b1,
                         float* __restrict__ h){
  int i=blockIdx.x*256+threadIdx.x;
  if(i>=300*1024) return;
  int r=i>>10, n=i&1023;
  int bn=n>>6, c64=n&63;
  float s=b1[n];
#pragma unroll
  for(int ks=0;ks<14;ks++)
    s+=hp[((size_t)(ks*16+bn)*300+r)*64+c64];
  h[(size_t)r*1024+n]=fmaxf(s,0.f);
}

// ---------------- conv1 3x3 pad1 as implicit GEMM: rows=300*196, K=2304, N=128 ----------------
__global__ __launch_bounds__(256) void k_conv1(const u16* __restrict__ roi14, const u16* __restrict__ Bc1,
                                               const float* __restrict__ mb1, u16* __restrict__ x1){
  __shared__ u16 Asm[64][48];
  __shared__ u16 Bsm[128][48];
  __shared__ int rowinf[64];
  int m0=blockIdx.x*64;
  int tid=threadIdx.x, lane=tid&63, wid=tid>>6;
  int wr=wid>>1, wc=wid&1;
  if(tid<64){
    int p=m0+tid;
    if(p<58800){ int r=p/196, q=p-r*196, y=q/14, x=q-y*14; rowinf[tid]=(r<<8)|(y<<4)|x; }
    else rowinf[tid]=-1;
  }
  __syncthreads();
  f32x4 acc[2][4]={};
  for(int it=0; it<72; ++it){
    int kg=it*32;
    int tap=kg>>8, c0=kg&255;
    int ky=tap/3, kx=tap-ky*3;
    {
      int ri=tid>>2, cl=(tid&3)*8;
      int rb=rowinf[ri];
      u16x8 v={0,0,0,0,0,0,0,0};
      if(rb>=0){
        int rr=rb>>8, y=(rb>>4)&15, x=rb&15;
        int yy=y+ky-1, xx=x+kx-1;
        if(yy>=0&&yy<14&&xx>=0&&xx<14)
          v=*(const u16x8*)(roi14+((size_t)((rr*14+yy)*14+xx))*256+c0+cl);
      }
      *(u16x8*)&Asm[ri][cl]=v;
    }
    {
      int kr=tid&31, cs2=(tid>>5)*16;
      const u16x8* s=(const u16x8*)(Bc1+(size_t)(kg+kr)*128+cs2);
      u16x8 v0=s[0], v1=s[1];
#pragma unroll
      for(int ii=0;ii<8;ii++){ Bsm[cs2+ii][kr]=v0[ii]; Bsm[cs2+8+ii][kr]=v1[ii]; }
    }
    __syncthreads();
    int kb=(lane>>4)*8;
    u16x8 a0=*(const u16x8*)&Asm[wr*32+(lane&15)][kb];
    u16x8 a1=*(const u16x8*)&Asm[wr*32+16+(lane&15)][kb];
#pragma unroll
    for(int fn=0;fn<4;fn++){
      u16x8 bv=*(const u16x8*)&Bsm[wc*64+fn*16+(lane&15)][kb];
      mfma16(acc[0][fn],a0,bv);
      mfma16(acc[1][fn],a1,bv);
    }
    __syncthreads();
  }
  asm volatile("s_nop 7\ns_nop 7");
#pragma unroll
  for(int fm=0;fm<2;fm++)
#pragma unroll
  for(int fn=0;fn<4;fn++){
    int col=wc*64+fn*16+(lane&15);
    float bias=mb1[col];
#pragma unroll
    for(int j=0;j<4;j++){
      int row=wr*32+fm*16+(lane>>4)*4+j;
      int p=m0+row;
      if(p<58800) x1[(size_t)p*128+col]=f2bf(fmaxf(acc[fm][fn][j]+bias,0.f));
    }
  }
}

// ---------------- conv2(deconv, per parity class) fused with conv3 1x1 ----------------
// m3 layout: [r][class][28][28]
__global__ __launch_bounds__(256) void k_conv2f(const u16* __restrict__ x1, const u16* __restrict__ B3t,
                                                const float* __restrict__ mbd, const float* __restrict__ mwo,
                                                const float* __restrict__ mbo, float* __restrict__ m3){
  __shared__ u16 Asm[64][48];
  __shared__ u16 Bsm[128][48];
  __shared__ u16 X2[64][144];
  __shared__ u16 B4[32][144];
  int m0=blockIdx.x*64, z=blockIdx.y;
  int ky=z>>1, kx=z&1;
  int tid=threadIdx.x, lane=tid&63, wid=tid>>6;
  int wr=wid>>1, wc=wid&1;
  for(int i=tid;i<32*128;i+=256){
    int n=i>>7, k=i&127;
    B4[n][k]=(n<21)? f2bf(mwo[n*128+k]) : (u16)0;
  }
  f32x4 acc[2][4]={};
  for(int it=0;it<4;it++){
    int c0=it*32;
    {
      int ri=tid>>2, cl=(tid&3)*8;
      int p=m0+ri;
      u16x8 v={0,0,0,0,0,0,0,0};
      if(p<58800) v=*(const u16x8*)(x1+(size_t)p*128+c0+cl);
      *(u16x8*)&Asm[ri][cl]=v;
    }
    {
      int n=tid>>1, hf=tid&1;
      const u16x8* s=(const u16x8*)(B3t+((size_t)z*128+n)*128+c0+hf*16);
      u16x8 v0=s[0], v1=s[1];
      *(u16x8*)&Bsm[n][hf*16]=v0;
      *(u16x8*)&Bsm[n][hf*16+8]=v1;
    }
    __syncthreads();
    int kb=(lane>>4)*8;
    u16x8 a0=*(const u16x8*)&Asm[wr*32+(lane&15)][kb];
    u16x8 a1=*(const u16x8*)&Asm[wr*32+16+(lane&15)][kb];
#pragma unroll
    for(int fn=0;fn<4;fn++){
      u16x8 bv=*(const u16x8*)&Bsm[wc*64+fn*16+(lane&15)][kb];
      mfma16(acc[0][fn],a0,bv);
      mfma16(acc[1][fn],a1,bv);
    }
    __syncthreads();
  }
  asm volatile("s_nop 7\ns_nop 7");
#pragma unroll
  for(int fm=0;fm<2;fm++)
#pragma unroll
  for(int fn=0;fn<4;fn++){
    int col=wc*64+fn*16+(lane&15);
    float bias=mbd[col];
#pragma unroll
    for(int j=0;j<4;j++){
      int row=wr*32+fm*16+(lane>>4)*4+j;
      X2[row][col]=f2bf(fmaxf(acc[fm][fn][j]+bias,0.f));
    }
  }
  __syncthreads();
  f32x4 acc2[2]={};
#pragma unroll
  for(int ks=0;ks<4;ks++){
    int kb=ks*32+(lane>>4)*8;
    u16x8 a=*(const u16x8*)&X2[wid*16+(lane&15)][kb];
    u16x8 b0=*(const u16x8*)&B4[(lane&15)][kb];
    u16x8 b1v=*(const u16x8*)&B4[16+(lane&15)][kb];
    mfma16(acc2[0],a,b0);
    mfma16(acc2[1],a,b1v);
  }
  asm volatile("s_nop 7\ns_nop 7");
#pragma unroll
  for(int fn=0;fn<2;fn++){
    int n=fn*16+(lane&15);
    if(n<21){
      float bias=mbo[n];
#pragma unroll
      for(int j=0;j<4;j++){
        int row=wid*16+(lane>>4)*4+j;
        int p=m0+row;
        if(p<58800){
          int r=p/196, q=p-r*196, iy=q/14, ix=q-iy*14;
          int oy=2*iy+(1-ky), ox=2*ix+(1-kx);
          m3[((size_t)r*21+n)*784 + oy*28+ox]=acc2[fn][j]+bias;
        }
      }
    }
  }
}

// ---------------- per-ROI head: logits, softmax, box decode, det keys ----------------
__global__ void k_head(const float* __restrict__ h, const float* __restrict__ WT,
                       const float* __restrict__ bc, const float* __restrict__ br,
                       const float* __restrict__ rois300, float* __restrict__ bxb,
                       float* __restrict__ scm, u64* __restrict__ keys2, u32* __restrict__ cnt){
  __shared__ float hs[1024];
  __shared__ float lg[105];
  __shared__ float scs[21];
  int r=blockIdx.x, t=threadIdx.x;
  for(int i=t;i<1024;i+=256) hs[i]=h[(size_t)r*1024+i];
  __syncthreads();
  if(t<105){
    const float* wrow=WT+(size_t)t*1024;
    float s=0.f;
    for(int k=0;k<1024;k+=4){
      float4 wv=*(const float4*)(wrow+k);
      s+=hs[k]*wv.x; s+=hs[k+1]*wv.y; s+=hs[k+2]*wv.z; s+=hs[k+3]*wv.w;
    }
    lg[t]=s+((t<21)?bc[t]:br[t-21]);
  }
  __syncthreads();
  if(t==0){
    float m=lg[0];
    for(int c=1;c<21;c++) m=fmaxf(m,lg[c]);
    float sum=0.f;
    for(int c=0;c<21;c++){ float e=exp_cr(lg[c]-m); scs[c]=e; sum+=e; }
    for(int c=0;c<21;c++) scs[c]=scs[c]/sum;
  }
  __syncthreads();
  if(t<20){
    int c=t+1;
    float rx1=rois300[4*r],ry1=rois300[4*r+1],rx2=rois300[4*r+2],ry2=rois300[4*r+3];
    float w=rx2-rx1, hh=ry2-ry1;
    float cx=rx1+0.5f*w, cy=ry1+0.5f*hh;
    float dx=lg[21+c*4+0], dy=lg[21+c*4+1], dwv=lg[21+c*4+2], dhv=lg[21+c*4+3];
    float pcx=dx*w+cx, pcy=dy*hh+cy;
    float pw=w*exp_cr(fminf(dwv,4.f)), ph=hh*exp_cr(fminf(dhv,4.f));
    float bx1=fminf(fmaxf(pcx-0.5f*pw,0.f),2560.f);
    float by1=fminf(fmaxf(pcy-0.5f*ph,0.f),1600.f);
    float bx2=fminf(fmaxf(pcx+0.5f*pw,0.f),2560.f);
    float by2=fminf(fmaxf(pcy+0.5f*ph,0.f),1600.f);
    int e=r*20+t;
    bxb[4*e]=bx1; bxb[4*e+1]=by1; bxb[4*e+2]=bx2; bxb[4*e+3]=by2;
    float sc=scs[c];
    bool valid=(sc>0.5f)&&(bx2-bx1>=1.f)&&(by2-by1>=1.f);
    float sv=valid? sc : -INFINITY;
    scm[e]=sv;
    keys2[e]=((u64)fkey(sv)<<32)|(u64)(~(u32)e);
    if(valid) atomicAdd(&cnt[1],1u);
  }
}

__global__ void k_detprep(const u32* __restrict__ order, const float* __restrict__ scm,
                          const float* __restrict__ bxb, float* __restrict__ dv,
                          float* __restrict__ dbx, float* __restrict__ out){
  int i=blockIdx.x*256+threadIdx.x;
  if(i>=6000) return;
  u32 g=order[i];
  float4 b=*(const float4*)(bxb+4*g);
  *(float4*)(dbx+4*i)=b;
  dv[i]=scm[g];
  *(float4*)(out+6000+4*i)=b;
  out[30000+i]=(float)(g%20u);
}

__global__ void k_dml(const u32* __restrict__ order, const float* __restrict__ m3, float* __restrict__ out){
  int idx=blockIdx.x*256+threadIdx.x;
  if(idx>=4704000) return;
  int e=idx/784, q=idx-e*784;
  u32 g=order[e];
  int r=(int)(g/20u), c=(int)(g%20u)+1;
  out[42000+idx]=m3[((size_t)r*21+c)*784+q];
}

extern "C" void kernel_launch(void* const* d_in, const int* in_sizes, int n_in,
                              void* d_out, int out_size, void* d_ws, size_t ws_size,
                              hipStream_t stream){
  (void)in_sizes; (void)n_in; (void)out_size;
  const float* features =(const float*)d_in[0];
  const float* rpn_logits=(const float*)d_in[1];
  const float* rpn_deltas=(const float*)d_in[2];
  const float* anchors  =(const float*)d_in[3];
  const float* W1=(const float*)d_in[4];
  const float* b1=(const float*)d_in[5];
  const float* Wc=(const float*)d_in[6];
  const float* bc=(const float*)d_in[7];
  const float* Wr=(const float*)d_in[8];
  const float* br=(const float*)d_in[9];
  const float* mw1=(const float*)d_in[10];
  const float* mb1=(const float*)d_in[11];
  const float* mwd=(const float*)d_in[12];
  const float* mbd=(const float*)d_in[13];
  const float* mwo=(const float*)d_in[14];
  const float* mbo=(const float*)d_in[15];
  float* out=(float*)d_out;

  char* base=(char*)d_ws; size_t off=0;
  auto alloc=[&](size_t bytes)->void*{ off=(off+255)&~(size_t)255; void* p=base+off; off+=bytes; return p; };
  u32* hist     =(u32*)alloc(65536*4);
  u32* cnt      =(u32*)alloc(64);
  float* scores =(float*)alloc(144000*4);
  float* rois_all=(float*)alloc((size_t)144000*16);
  u64* keys1    =(u64*)alloc(8192*8);
  u32* selidx   =(u32*)alloc(6000*4);
  float* boxes6k=(float*)alloc(6000*16);
  u64* masksT   =(u64*)alloc((size_t)94*6016*8 + 1024);  // transposed+rotated chunks + DMA slack
  u64* masks    =(u64*)alloc((size_t)6000*94*8);          // row-major (det NMS)
  float* rois300=(float*)alloc(300*16);
  u16* featT    =(u16*)alloc((size_t)16000*256*2);
  u16* roi7     =(u16*)alloc((size_t)300*49*256*2);
  u16* roi14    =(u16*)alloc((size_t)300*196*256*2);
  float* hbuf   =(float*)alloc((size_t)300*1024*4);
  float* hp     =(float*)alloc((size_t)224*300*64*4);     // fc1 split-K partials
  float* WT     =(float*)alloc((size_t)105*1024*4);
  float* bxb    =(float*)alloc(6000*16);
  float* scm    =(float*)alloc(6000*4);
  u64* keys2    =(u64*)alloc(8192*8);
  u32* order    =(u32*)alloc(6000*4);
  float* dv     =(float*)alloc(6000*4);
  float* dbx    =(float*)alloc(6000*16);
  u16* x1       =(u16*)alloc((size_t)58800*128*2);
  u16* Bc1      =(u16*)alloc((size_t)2304*128*2);
  u16* B3t      =(u16*)alloc((size_t)4*128*128*2);
  float* m3     =(float*)alloc((size_t)58800*21*4);
  if(off > ws_size) return; // workspace too small; fail visibly

  hipMemsetAsync(hist,0,65536*4,stream);
  hipMemsetAsync(cnt,0,64,stream);

  k_prep<<<1152,256,0,stream>>>(mw1,mwd,Wc,Wr,Bc1,B3t,WT);
  k_featT<<<dim3(250,8),256,0,stream>>>(features,featT);

  k_rpn<<<563,256,0,stream>>>(rpn_logits,rpn_deltas,anchors,scores,rois_all,hist);
  k_findbin<<<1,1024,0,stream>>>(hist,cnt);
  k_compact<<<563,256,0,stream>>>(scores,cnt,keys1);
  k_sort8k<true><<<1,1024,0,stream>>>(keys1,cnt,0,selidx);
  k_gather6k<<<24,256,0,stream>>>(selidx,rois_all,boxes6k);
  k_masks<1><<<2048,256,0,stream>>>(boxes6k,nullptr,6000,0.7f,masksT);
  k_scan1<<<1,512,0,stream>>>(masksT,boxes6k,rois300);

  k_roialign<7><<<3675,256,0,stream>>>(rois300,featT,roi7);
  k_roialign<14><<<14700,256,0,stream>>>(rois300,featT,roi14);

  k_fc1b<<<dim3(14,16),256,0,stream>>>(roi7,W1,hp);
  k_fc1red<<<1200,256,0,stream>>>(hp,b1,hbuf);
  k_conv1<<<919,256,0,stream>>>(roi14,Bc1,mb1,x1);
  k_conv2f<<<dim3(919,4),256,0,stream>>>(x1,B3t,mbd,mwo,mbo,m3);

  k_head<<<300,256,0,stream>>>(hbuf,WT,bc,br,rois300,bxb,scm,keys2,cnt);
  k_sort8k<false><<<1,1024,0,stream>>>(keys2,nullptr,6000,order);
  k_detprep<<<24,256,0,stream>>>(order,scm,bxb,dv,dbx,out);
  k_masks<0><<<512,256,0,stream>>>(dbx,cnt+1,0,0.5f,masks);
  k_scan2<<<1,64,0,stream>>>(masks,cnt,dv,out);
  k_dml<<<18375,256,0,stream>>>(order,m3,out);
}

// Round 7
// 732.248 us; speedup vs baseline: 4.0162x; 1.1827x over previous
//
#include <hip/hip_runtime.h>
#include <stdint.h>

#pragma clang fp contract(off)

typedef unsigned int u32;
typedef unsigned short u16;
typedef unsigned long long u64;
typedef float f32x4 __attribute__((ext_vector_type(4)));
typedef u16 u16x8 __attribute__((ext_vector_type(8)));

#define DEV __device__ __forceinline__

DEV float bf2f(u16 u){ union{u32 i; float f;} v; v.i=((u32)u)<<16; return v.f; }
DEV u16 f2bf(float f){ union{float f; u32 i;} v; v.f=f; u32 b=v.i; return (u16)((b + 0x7fffu + ((b>>16)&1u))>>16); }
DEV u32 fkey(float f){ union{float f; u32 i;} v; v.f=f; u32 b=v.i; return (b&0x80000000u)? ~b : (b|0x80000000u); }
DEV float exp_cr(float x){ return (float)exp((double)x); }

DEV void mfma16(f32x4& d, u16x8 a, u16x8 b){
  asm volatile("v_mfma_f32_16x16x32_bf16 %0, %1, %2, %0" : "+v"(d) : "v"(a), "v"(b));
}

DEV void gload_lds16(const void* g, void* l){
  __builtin_amdgcn_global_load_lds((const __attribute__((address_space(1))) unsigned int*)g,
                                   (__attribute__((address_space(3))) unsigned int*)l, 16, 0, 0);
}

DEV u64 rfl64(u64 v){
  return ((u64)__builtin_amdgcn_readfirstlane((u32)(v>>32))<<32) |
         (u64)__builtin_amdgcn_readfirstlane((u32)v);
}

// ---------------- RPN: softmax score + decode + clip + filter + histogram ----------------
__global__ void k_rpn(const float* __restrict__ logits, const float* __restrict__ deltas,
                      const float* __restrict__ anchors, float* __restrict__ scores,
                      float* __restrict__ rois_all, u32* __restrict__ hist){
  int i=blockIdx.x*256+threadIdx.x;
  if(i>=144000) return;
  float l0=logits[2*i], l1=logits[2*i+1];
  float m=fmaxf(l0,l1);
  float e0=exp_cr(l0-m), e1=exp_cr(l1-m);
  float s=e1/(e0+e1);
  float a0=anchors[4*i],a1=anchors[4*i+1],a2=anchors[4*i+2],a3=anchors[4*i+3];
  float w=a2-a0, hh=a3-a1;
  float cx=a0+0.5f*w, cy=a1+0.5f*hh;
  float dx=deltas[4*i],dy=deltas[4*i+1],dwv=deltas[4*i+2],dhv=deltas[4*i+3];
  float pcx=dx*w+cx, pcy=dy*hh+cy;
  float pw=w*exp_cr(fminf(dwv,4.f)), ph=hh*exp_cr(fminf(dhv,4.f));
  float x1=fminf(fmaxf(pcx-0.5f*pw,0.f),2560.f);
  float y1=fminf(fmaxf(pcy-0.5f*ph,0.f),1600.f);
  float x2=fminf(fmaxf(pcx+0.5f*pw,0.f),2560.f);
  float y2=fminf(fmaxf(pcy+0.5f*ph,0.f),1600.f);
  float4 bb; bb.x=x1;bb.y=y1;bb.z=x2;bb.w=y2;
  *(float4*)(rois_all+4*i)=bb;
  bool ok=(x2-x1>=16.f)&&(y2-y1>=16.f);
  float sc=ok? s : -INFINITY;
  scores[i]=sc;
  if(ok) atomicAdd(&hist[fkey(sc)>>16],1u);
}

// ---------------- find 6000th-rank bin B + descending base ranks per bin ----------------
__global__ __launch_bounds__(1024) void k_findbin(const u32* __restrict__ hist, u32* __restrict__ cnt,
                                                  u32* __restrict__ base){
  __shared__ u32 cs[1024];
  __shared__ u32 hb[1024];
  int t=threadIdx.x;
  u32 s=0;
  for(int b=0;b<64;b++) s+=hist[t*64+b];
  cs[t]=s;
  __syncthreads();
  if(t==0){
    u32 acc=0;
    for(int i=1023;i>=0;i--){ hb[i]=acc; acc+=cs[i]; }
    acc=0; int tc=1023;
    for(; tc>=0; tc--){ if(acc+cs[tc]>=6000u) break; acc+=cs[tc]; }
    if(tc<0) tc=0;
    u32 B=(u32)tc*64u;
    for(int b=63;b>=0;b--){
      u32 hbv=hist[tc*64+b];
      if(acc+hbv>=6000u){ B=(u32)(tc*64+b); break; }
      acc+=hbv;
    }
    cnt[2]=B;
  }
  __syncthreads();
  u32 run=hb[t];
  for(int b=63;b>=0;b--){ base[t*64+b]=run; run+=hist[t*64+b]; }
}

// ---------------- bucket candidates into rank-slices ----------------
__global__ void k_bucket(const float* __restrict__ scores, const u32* __restrict__ cnt,
                         const u32* __restrict__ base, u32* __restrict__ cntbin,
                         u64* __restrict__ bucket){
  int i=blockIdx.x*256+threadIdx.x;
  if(i>=144000) return;
  u32 u=fkey(scores[i]);
  u32 bin=u>>16;
  if(bin>=cnt[2]){
    u32 pos=base[bin]+atomicAdd(&cntbin[bin],1u);
    if(pos<8192u) bucket[pos]=((u64)u<<32)|(u64)(~(u32)i);
  }
}

// ---------------- exact within-bin rank (count-larger), emit selidx ----------------
__global__ __launch_bounds__(256) void k_binsort(const u32* __restrict__ cnt, const u32* __restrict__ base,
                                                 const u32* __restrict__ hist, const u64* __restrict__ bucket,
                                                 u32* __restrict__ selidx){
  __shared__ u64 SL[4096];
  u32 B=cnt[2];
  for(u32 bin=B+blockIdx.x; bin<65536u; bin+=gridDim.x){
    u32 m=hist[bin];
    if(m==0u) continue;
    u32 bs=base[bin];
    if(bs>=6000u) continue;
    if(bs+m>8192u) m=8192u-bs;
    if(m==1u){ if(threadIdx.x==0) selidx[bs]=~(u32)bucket[bs]; continue; }
    if(m<=4096u){
      for(u32 i=threadIdx.x;i<m;i+=256) SL[i]=bucket[bs+i];
      __syncthreads();
      for(u32 i=threadIdx.x;i<m;i+=256){
        u64 k=SL[i]; u32 r=0;
        for(u32 j=0;j<m;j++) r+=(SL[j]>k);
        if(bs+r<6000u) selidx[bs+r]=~(u32)k;
      }
      __syncthreads();
    } else {
      for(u32 i=threadIdx.x;i<m;i+=256){
        u64 k=bucket[bs+i]; u32 r=0;
        for(u32 j=0;j<m;j++) r+=(bucket[bs+j]>k);
        if(bs+r<6000u) selidx[bs+r]=~(u32)k;
      }
    }
  }
}

__global__ void k_gather6k(const u32* __restrict__ selidx, const float* __restrict__ rois_all,
                           float* __restrict__ boxes6k){
  int i=blockIdx.x*256+threadIdx.x;
  if(i>=6000) return;
  u32 g=selidx[i];
  float4 b=*(const float4*)(rois_all+4*g);
  *(float4*)(boxes6k+4*i)=b;
}

// ---------------- NMS bitmask build; TR=1 stores transposed+rotated per-chunk layout ----------------
template<int TR>
__global__ void k_masks(const float* __restrict__ boxes, const u32* __restrict__ limitPtr, int limitFixed,
                        float thresh, u64* __restrict__ masks){
  int limit = limitPtr? (int)*limitPtr : limitFixed;
  if(limit>6000) limit=6000;
  long total=(long)limit*94;
  int lane=threadIdx.x&63;
  long w0=(long)blockIdx.x*4 + (threadIdx.x>>6);
  long stride=(long)gridDim.x*4;
  for(long w=w0; w<total; w+=stride){
    int row=(int)(w/94), wrd=(int)(w-(long)row*94);
    int j=wrd*64+lane;
    float4 a=*(const float4*)(boxes+4*row);
    bool bit=false;
    if(j<limit && j>row){
      float4 b=*(const float4*)(boxes+4*j);
      float area_a=(a.z-a.x)*(a.w-a.y);
      float area_b=(b.z-b.x)*(b.w-b.y);
      float ltx=fmaxf(a.x,b.x), lty=fmaxf(a.y,b.y);
      float rbx=fminf(a.z,b.z), rby=fminf(a.w,b.w);
      float wv=fmaxf(rbx-ltx,0.f), hv=fmaxf(rby-lty,0.f);
      float inter=wv*hv;
      float iou=inter/(area_a+area_b-inter+1e-9f);
      bit = iou>thresh;
    }
    u64 mword=__ballot(bit);
    if(lane==0){
      if(TR) masks[(size_t)(row>>6)*6016 + (size_t)wrd*64 + (((row&63)+wrd)&63)]=mword;
      else   masks[(size_t)row*94+wrd]=mword;
    }
  }
}

// ---------------- chunked greedy NMS scan with EARLY EXIT at 300 kept ----------------
__global__ __launch_bounds__(512) void k_scan1(const u64* __restrict__ masksT, const float* __restrict__ boxes6k,
                                               float* __restrict__ rois300){
  __shared__ __align__(16) u64 stage[3][6144];
  __shared__ u64 remv[94];
  __shared__ u64 keepw[94];
  __shared__ u32 rsel[304];
  int tid=threadIdx.x, lane=tid&63, wvid=tid>>6;
  int w=tid&127, h=tid>>7;
  bool act=(w<94);
  if(tid<94) remv[tid]=0ull;
  const char* mb=(const char*)masksT;
#pragma unroll
  for(int k=0;k<6;k++){
    int ins=wvid+k*8;
    gload_lds16(mb+(size_t)ins*1024+lane*16, (char*)&stage[0][0]+ins*1024);
  }
#pragma unroll
  for(int k=0;k<6;k++){
    int ins=wvid+k*8;
    gload_lds16(mb+48128+(size_t)ins*1024+lane*16, (char*)&stage[1][0]+ins*1024);
  }
  int tot=0;
  for(int c=0;c<94;c++){
    const u64* sb=&stage[c%3][0];
    if(c<93) asm volatile("s_waitcnt vmcnt(6)" ::: "memory");
    else     asm volatile("s_waitcnt vmcnt(0)" ::: "memory");
    asm volatile("s_waitcnt lgkmcnt(0)" ::: "memory");
    __builtin_amdgcn_s_barrier();
    if(c<92){
      const char* src=mb+(size_t)(c+2)*48128;
      char* dst=(char*)&stage[(c+2)%3][0];
#pragma unroll
      for(int k=0;k<6;k++){
        int ins=wvid+k*8;
        gload_lds16(src+(size_t)ins*1024+lane*16, dst+ins*1024);
      }
    }
    if(wvid==0){
      u64 keep=~rfl64(remv[c]);
      if(c==93) keep&=0x0000FFFFFFFFFFFFull;
      u64 dg=sb[(size_t)c*64+((lane+c)&63)];
      u32 dlo=(u32)dg, dhi=(u32)(dg>>32);
      u64 avail=keep;
      while(avail){
        u32 i=__builtin_amdgcn_readfirstlane((u32)__builtin_ctzll(avail));
        u64 row=((u64)__builtin_amdgcn_readlane(dhi,i)<<32)|(u64)__builtin_amdgcn_readlane(dlo,i);
        keep&=~row;
        avail&=~row;
        avail&=avail-1ull;
      }
      if(lane==0) keepw[c]=keep;
    }
    asm volatile("s_waitcnt lgkmcnt(0)" ::: "memory");
    __builtin_amdgcn_s_barrier();
    u64 kp=rfl64(keepw[c]);
    if(act){
      u64 racc=0ull;
#pragma unroll
      for(int j2=0;j2<16;j2++){
        int r=h*16+j2;
        u64 v=sb[(size_t)w*64+((r+w)&63)];
        racc|=v&((u64)0-((kp>>r)&1ull));
      }
      if(racc) atomicOr(&remv[w],racc);
    }
    tot+=(int)__popcll(kp);
    if(tot>=300) break;
  }
  asm volatile("s_waitcnt vmcnt(0) lgkmcnt(0)" ::: "memory");
  __builtin_amdgcn_s_barrier();
  if(tid==0){
    int cntk=0;
    for(int c=0;c<94&&cntk<300;c++){
      u64 kw=keepw[c];
      while(kw&&cntk<300){ int b=__builtin_ctzll(kw); rsel[cntk++]=(u32)(c*64+b); kw&=kw-1; }
    }
    for(int c=0;c<94&&cntk<300;c++){
      u64 kw=~keepw[c];
      if(c==93) kw&=0x0000FFFFFFFFFFFFull;
      while(kw&&cntk<300){ int b=__builtin_ctzll(kw); rsel[cntk++]=(u32)(c*64+b); kw&=kw-1; }
    }
  }
  __builtin_amdgcn_s_barrier();
  for(int s2=tid;s2<300;s2+=512){
    u32 g=rsel[s2];
    float4 b=*(const float4*)(boxes6k+4*g);
    *(float4*)(rois300+4*s2)=b;
  }
}

__global__ __launch_bounds__(64) void k_scan2(const u64* __restrict__ masks, const u32* __restrict__ cnt,
                                              const float* __restrict__ dv, float* __restrict__ out){
  int lane=threadIdx.x;
  int V=(int)cnt[1]; if(V>6000)V=6000;
  bool ld=lane<47;
  const u64* mrow=masks+lane*2;
  u64 r0=0,r1=0;
  for(int i=0;i<V;i++){
    int w=i>>6;
    u64 v0=__shfl(r0,w>>1);
    u64 v1=__shfl(r1,w>>1);
    u64 word=(w&1)?v1:v0;
    if(!((word>>(i&63))&1ull)){
      if(ld){ r0|=mrow[(size_t)i*94]; r1|=mrow[(size_t)i*94+1]; }
    }
  }
  __shared__ u64 rem[94];
  if(ld){ rem[2*lane]=r0; rem[2*lane+1]=r1; }
  __syncthreads();
  for(int i=lane;i<6000;i+=64){
    bool kept=(i<V)&&!((rem[i>>6]>>(i&63))&1ull);
    out[i]=kept? dv[i]:0.0f;
    out[36000+i]=kept?1.0f:0.0f;
  }
}

// ---------------- feature transpose (C,H,W) f32 -> (H*W, C) bf16 ----------------
__global__ void k_featT(const float* __restrict__ feat, u16* __restrict__ featT){
  __shared__ float tile[32][65];
  int p0=blockIdx.x*64, c0=blockIdx.y*32;
  int t=threadIdx.x;
  int pp=t&63, cc=t>>6;
#pragma unroll
  for(int s=0;s<8;s++)
    tile[cc+s*4][pp]=feat[(size_t)(c0+cc+s*4)*16000+p0+pp];
  __syncthreads();
  int cw=t&31, pw=t>>5;
#pragma unroll
  for(int s=0;s<8;s++)
    featT[(size_t)(p0+pw+s*8)*256+c0+cw]=f2bf(tile[cw][pw+s*8]);
}

// ---------------- ROI align: one wave per sample point, 256 channels ----------------
template<int OUT>
__global__ void k_roialign(const float* __restrict__ rois, const u16* __restrict__ featT,
                           u16* __restrict__ outbuf){
  int wid=threadIdx.x>>6, lane=threadIdx.x&63;
  int gw=blockIdx.x*4+wid;
  if(gw>=300*OUT*OUT) return;
  int r=gw/(OUT*OUT), q=gw-r*(OUT*OUT), py=q/OUT, px=q-py*OUT;
  float x1=rois[4*r]*0.0625f;
  float y1=rois[4*r+1]*0.0625f;
  float x2=rois[4*r+2]*0.0625f;
  float y2=rois[4*r+3]*0.0625f;
  float bw=(x2-x1)/(float)OUT, bh=(y2-y1)/(float)OUT;
  float xx=x1+((float)px+0.5f)*bw-0.5f;
  float yy=y1+((float)py+0.5f)*bh-0.5f;
  float x0f=fminf(fmaxf(floorf(xx),0.f),158.f);
  float y0f=fminf(fmaxf(floorf(yy),0.f),98.f);
  float fx=fminf(fmaxf(xx-x0f,0.f),1.f);
  float fy=fminf(fmaxf(yy-y0f,0.f),1.f);
  int x0=(int)x0f, y0=(int)y0f;
  float w00=(1.f-fy)*(1.f-fx), w01=(1.f-fy)*fx, w10=fy*(1.f-fx), w11=fy*fx;
  const u16* p00=featT+((size_t)(y0*160+x0))*256+lane*4;
  ushort4 u00=*(const ushort4*)p00;
  ushort4 u01=*(const ushort4*)(p00+256);
  ushort4 u10=*(const ushort4*)(p00+40960);
  ushort4 u11=*(const ushort4*)(p00+41216);
  ushort4 o;
  o.x=f2bf(((bf2f(u00.x)*w00+bf2f(u01.x)*w01)+bf2f(u10.x)*w10)+bf2f(u11.x)*w11);
  o.y=f2bf(((bf2f(u00.y)*w00+bf2f(u01.y)*w01)+bf2f(u10.y)*w10)+bf2f(u11.y)*w11);
  o.z=f2bf(((bf2f(u00.z)*w00+bf2f(u01.z)*w01)+bf2f(u10.z)*w10)+bf2f(u11.z)*w11);
  o.w=f2bf(((bf2f(u00.w)*w00+bf2f(u01.w)*w01)+bf2f(u10.w)*w10)+bf2f(u11.w)*w11);
  *(ushort4*)(outbuf+(size_t)gw*256+lane*4)=o;
}

// ---------------- weight prep ----------------
__global__ void k_prep(const float* __restrict__ mw1, const float* __restrict__ mwd,
                       const float* __restrict__ Wc, const float* __restrict__ Wr,
                       u16* __restrict__ Bc1, u16* __restrict__ B3t, float* __restrict__ WT){
  int i=blockIdx.x*256+threadIdx.x;
  if(i<294912){
    int o=i/2304, rem=i-o*2304, c=rem/9, t=rem-(rem/9)*9;
    Bc1[((size_t)t*256+c)*128+o]=f2bf(mw1[i]);
  }
  if(i<65536){
    int co=i>>9, ci=(i>>2)&127, ky=(i>>1)&1, kxx=i&1;
    int z=ky*2+kxx;
    B3t[((size_t)z*128+co)*128+ci]=f2bf(mwd[i]);
  }
  if(i<107520){
    int j=i>>10, k=i&1023;
    WT[(size_t)j*1024+k]=(j<21)? Wc[(size_t)k*21+j] : Wr[(size_t)k*84+(j-21)];
  }
}

// ---------------- FC1 split-K: grid(KS=14, NS=16) ----------------
__global__ __launch_bounds__(256) void k_fc1b(const u16* __restrict__ roi7, const float* __restrict__ W1,
                                              float* __restrict__ hp){
  __shared__ u16 Bsm[2][64][72];
  int ks=blockIdx.x, bn=blockIdx.y;
  int kbase=ks*896, n0=bn*64;
  int tid=threadIdx.x, lane=tid&63, wid=tid>>6;
  int wr=wid>>1, wc=wid&1;
  f32x4 acc[5][2][2]={};
  auto stageB=[&](int it,int buf){
    int r=tid>>2, cs=(tid&3)*16;
    int kg=kbase+it*64+r;
    int p=kg>>8, c=kg&255;
    const float* src=W1+(size_t)(c*49+p)*1024+n0+cs;
    float fv[16];
    *(float4*)(fv+0)=((const float4*)src)[0];
    *(float4*)(fv+4)=((const float4*)src)[1];
    *(float4*)(fv+8)=((const float4*)src)[2];
    *(float4*)(fv+12)=((const float4*)src)[3];
#pragma unroll
    for(int ii=0;ii<16;ii++) Bsm[buf][cs+ii][r]=f2bf(fv[ii]);
  };
  stageB(0,0);
  __syncthreads();
  int buf=0;
  for(int it=0;it<14;it++){
    int kk=kbase+it*64;
    u16x8 bfr[2][2];
#pragma unroll
    for(int ks2=0;ks2<2;ks2++){
      int kb=ks2*32+(lane>>4)*8;
#pragma unroll
      for(int fn=0;fn<2;fn++)
        bfr[ks2][fn]=*(const u16x8*)&Bsm[buf][wc*32+fn*16+(lane&15)][kb];
    }
    if(it<13) stageB(it+1,buf^1);
#pragma unroll
    for(int ks2=0;ks2<2;ks2++){
      int kb=ks2*32+(lane>>4)*8;
#pragma unroll
      for(int mt=0;mt<5;mt++){
#pragma unroll
        for(int fm=0;fm<2;fm++){
          int m=mt*64+wr*32+fm*16+(lane&15);
          u16x8 av={0,0,0,0,0,0,0,0};
          if(m<300) av=*(const u16x8*)(roi7+(size_t)m*12544+kk+kb);
          mfma16(acc[mt][fm][0],av,bfr[ks2][0]);
          mfma16(acc[mt][fm][1],av,bfr[ks2][1]);
        }
      }
    }
    __syncthreads();
    buf^=1;
  }
  asm volatile("s_nop 7\ns_nop 7");
  size_t base=((size_t)(ks*16+bn))*300*64;
#pragma unroll
  for(int mt=0;mt<5;mt++)
#pragma unroll
  for(int fm=0;fm<2;fm++)
#pragma unroll
  for(int fn=0;fn<2;fn++){
    int col=wc*32+fn*16+(lane&15);
#pragma unroll
    for(int j=0;j<4;j++){
      int row=mt*64+wr*32+fm*16+(lane>>4)*4+j;
      if(row<300) hp[base+(size_t)row*64+col]=acc[mt][fm][fn][j];
    }
  }
}

__global__ void k_fc1red(const float* __restrict__ hp, const float* __restrict__ b1,
                         float* __restrict__ h){
  int i=blockIdx.x*256+threadIdx.x;
  if(i>=300*1024) return;
  int r=i>>10, n=i&1023;
  int bn=n>>6, c64=n&63;
  float s=b1[n];
#pragma unroll
  for(int ks=0;ks<14;ks++)
    s+=hp[((size_t)(ks*16+bn)*300+r)*64+c64];
  h[(size_t)r*1024+n]=fmaxf(s,0.f);
}

// ---------------- conv1 3x3 pad1 as implicit GEMM ----------------
__global__ __launch_bounds__(256) void k_conv1(const u16* __restrict__ roi14, const u16* __restrict__ Bc1,
                                               const float* __restrict__ mb1, u16* __restrict__ x1){
  __shared__ u16 Asm[64][48];
  __shared__ u16 Bsm[128][48];
  __shared__ int rowinf[64];
  int m0=blockIdx.x*64;
  int tid=threadIdx.x, lane=tid&63, wid=tid>>6;
  int wr=wid>>1, wc=wid&1;
  if(tid<64){
    int p=m0+tid;
    if(p<58800){ int r=p/196, q=p-r*196, y=q/14, x=q-y*14; rowinf[tid]=(r<<8)|(y<<4)|x; }
    else rowinf[tid]=-1;
  }
  __syncthreads();
  f32x4 acc[2][4]={};
  for(int it=0; it<72; ++it){
    int kg=it*32;
    int tap=kg>>8, c0=kg&255;
    int ky=tap/3, kx=tap-ky*3;
    {
      int ri=tid>>2, cl=(tid&3)*8;
      int rb=rowinf[ri];
      u16x8 v={0,0,0,0,0,0,0,0};
      if(rb>=0){
        int rr=rb>>8, y=(rb>>4)&15, x=rb&15;
        int yy=y+ky-1, xx=x+kx-1;
        if(yy>=0&&yy<14&&xx>=0&&xx<14)
          v=*(const u16x8*)(roi14+((size_t)((rr*14+yy)*14+xx))*256+c0+cl);
      }
      *(u16x8*)&Asm[ri][cl]=v;
    }
    {
      int kr=tid&31, cs2=(tid>>5)*16;
      const u16x8* s=(const u16x8*)(Bc1+(size_t)(kg+kr)*128+cs2);
      u16x8 v0=s[0], v1=s[1];
#pragma unroll
      for(int ii=0;ii<8;ii++){ Bsm[cs2+ii][kr]=v0[ii]; Bsm[cs2+8+ii][kr]=v1[ii]; }
    }
    __syncthreads();
    int kb=(lane>>4)*8;
    u16x8 a0=*(const u16x8*)&Asm[wr*32+(lane&15)][kb];
    u16x8 a1=*(const u16x8*)&Asm[wr*32+16+(lane&15)][kb];
#pragma unroll
    for(int fn=0;fn<4;fn++){
      u16x8 bv=*(const u16x8*)&Bsm[wc*64+fn*16+(lane&15)][kb];
      mfma16(acc[0][fn],a0,bv);
      mfma16(acc[1][fn],a1,bv);
    }
    __syncthreads();
  }
  asm volatile("s_nop 7\ns_nop 7");
#pragma unroll
  for(int fm=0;fm<2;fm++)
#pragma unroll
  for(int fn=0;fn<4;fn++){
    int col=wc*64+fn*16+(lane&15);
    float bias=mb1[col];
#pragma unroll
    for(int j=0;j<4;j++){
      int row=wr*32+fm*16+(lane>>4)*4+j;
      int p=m0+row;
      if(p<58800) x1[(size_t)p*128+col]=f2bf(fmaxf(acc[fm][fn][j]+bias,0.f));
    }
  }
}

// ---------------- conv2(deconv, per parity class) fused with conv3 1x1 ----------------
// m3 layout: [r][class][28][28]
__global__ __launch_bounds__(256) void k_conv2f(const u16* __restrict__ x1, const u16* __restrict__ B3t,
                                                const float* __restrict__ mbd, const float* __restrict__ mwo,
                                                const float* __restrict__ mbo, float* __restrict__ m3){
  __shared__ u16 Asm[64][48];
  __shared__ u16 Bsm[128][48];
  __shared__ u16 X2[64][144];
  __shared__ u16 B4[32][144];
  int m0=blockIdx.x*64, z=blockIdx.y;
  int ky=z>>1, kx=z&1;
  int tid=threadIdx.x, lane=tid&63, wid=tid>>6;
  int wr=wid>>1, wc=wid&1;
  for(int i=tid;i<32*128;i+=256){
    int n=i>>7, k=i&127;
    B4[n][k]=(n<21)? f2bf(mwo[n*128+k]) : (u16)0;
  }
  f32x4 acc[2][4]={};
  for(int it=0;it<4;it++){
    int c0=it*32;
    {
      int ri=tid>>2, cl=(tid&3)*8;
      int p=m0+ri;
      u16x8 v={0,0,0,0,0,0,0,0};
      if(p<58800) v=*(const u16x8*)(x1+(size_t)p*128+c0+cl);
      *(u16x8*)&Asm[ri][cl]=v;
    }
    {
      int n=tid>>1, hf=tid&1;
      const u16x8* s=(const u16x8*)(B3t+((size_t)z*128+n)*128+c0+hf*16);
      u16x8 v0=s[0], v1=s[1];
      *(u16x8*)&Bsm[n][hf*16]=v0;
      *(u16x8*)&Bsm[n][hf*16+8]=v1;
    }
    __syncthreads();
    int kb=(lane>>4)*8;
    u16x8 a0=*(const u16x8*)&Asm[wr*32+(lane&15)][kb];
    u16x8 a1=*(const u16x8*)&Asm[wr*32+16+(lane&15)][kb];
#pragma unroll
    for(int fn=0;fn<4;fn++){
      u16x8 bv=*(const u16x8*)&Bsm[wc*64+fn*16+(lane&15)][kb];
      mfma16(acc[0][fn],a0,bv);
      mfma16(acc[1][fn],a1,bv);
    }
    __syncthreads();
  }
  asm volatile("s_nop 7\ns_nop 7");
#pragma unroll
  for(int fm=0;fm<2;fm++)
#pragma unroll
  for(int fn=0;fn<4;fn++){
    int col=wc*64+fn*16+(lane&15);
    float bias=mbd[col];
#pragma unroll
    for(int j=0;j<4;j++){
      int row=wr*32+fm*16+(lane>>4)*4+j;
      X2[row][col]=f2bf(fmaxf(acc[fm][fn][j]+bias,0.f));
    }
  }
  __syncthreads();
  f32x4 acc2[2]={};
#pragma unroll
  for(int ks=0;ks<4;ks++){
    int kb=ks*32+(lane>>4)*8;
    u16x8 a=*(const u16x8*)&X2[wid*16+(lane&15)][kb];
    u16x8 b0=*(const u16x8*)&B4[(lane&15)][kb];
    u16x8 b1v=*(const u16x8*)&B4[16+(lane&15)][kb];
    mfma16(acc2[0],a,b0);
    mfma16(acc2[1],a,b1v);
  }
  asm volatile("s_nop 7\ns_nop 7");
#pragma unroll
  for(int fn=0;fn<2;fn++){
    int n=fn*16+(lane&15);
    if(n<21){
      float bias=mbo[n];
#pragma unroll
      for(int j=0;j<4;j++){
        int row=wid*16+(lane>>4)*4+j;
        int p=m0+row;
        if(p<58800){
          int r=p/196, q=p-r*196, iy=q/14, ix=q-iy*14;
          int oy=2*iy+(1-ky), ox=2*ix+(1-kx);
          m3[((size_t)r*21+n)*784 + oy*28+ox]=acc2[fn][j]+bias;
        }
      }
    }
  }
}

// ---------------- per-ROI head: logits, softmax, box decode ----------------
__global__ void k_head(const float* __restrict__ h, const float* __restrict__ WT,
                       const float* __restrict__ bc, const float* __restrict__ br,
                       const float* __restrict__ rois300, float* __restrict__ bxb,
                       float* __restrict__ scm, u32* __restrict__ cnt){
  __shared__ float hs[1024];
  __shared__ float lg[105];
  __shared__ float scs[21];
  int r=blockIdx.x, t=threadIdx.x;
  for(int i=t;i<1024;i+=256) hs[i]=h[(size_t)r*1024+i];
  __syncthreads();
  if(t<105){
    const float* wrow=WT+(size_t)t*1024;
    float s=0.f;
    for(int k=0;k<1024;k+=4){
      float4 wv=*(const float4*)(wrow+k);
      s+=hs[k]*wv.x; s+=hs[k+1]*wv.y; s+=hs[k+2]*wv.z; s+=hs[k+3]*wv.w;
    }
    lg[t]=s+((t<21)?bc[t]:br[t-21]);
  }
  __syncthreads();
  if(t==0){
    float m=lg[0];
    for(int c=1;c<21;c++) m=fmaxf(m,lg[c]);
    float sum=0.f;
    for(int c=0;c<21;c++){ float e=exp_cr(lg[c]-m); scs[c]=e; sum+=e; }
    for(int c=0;c<21;c++) scs[c]=scs[c]/sum;
  }
  __syncthreads();
  if(t<20){
    int c=t+1;
    float rx1=rois300[4*r],ry1=rois300[4*r+1],rx2=rois300[4*r+2],ry2=rois300[4*r+3];
    float w=rx2-rx1, hh=ry2-ry1;
    float cx=rx1+0.5f*w, cy=ry1+0.5f*hh;
    float dx=lg[21+c*4+0], dy=lg[21+c*4+1], dwv=lg[21+c*4+2], dhv=lg[21+c*4+3];
    float pcx=dx*w+cx, pcy=dy*hh+cy;
    float pw=w*exp_cr(fminf(dwv,4.f)), ph=hh*exp_cr(fminf(dhv,4.f));
    float bx1=fminf(fmaxf(pcx-0.5f*pw,0.f),2560.f);
    float by1=fminf(fmaxf(pcy-0.5f*ph,0.f),1600.f);
    float bx2=fminf(fmaxf(pcx+0.5f*pw,0.f),2560.f);
    float by2=fminf(fmaxf(pcy+0.5f*ph,0.f),1600.f);
    int e=r*20+t;
    bxb[4*e]=bx1; bxb[4*e+1]=by1; bxb[4*e+2]=bx2; bxb[4*e+3]=by2;
    float sc=scs[c];
    bool valid=(sc>0.5f)&&(bx2-bx1>=1.f)&&(by2-by1>=1.f);
    float sv=valid? sc : -INFINITY;
    scm[e]=sv;
    if(valid) atomicAdd(&cnt[1],1u);
  }
}

// ---------------- detection order: exact rank without a sort ----------------
// order = [valid sorted by (score desc, idx asc)] ++ [invalid by idx asc]
__global__ __launch_bounds__(1024) void k_detsort(const float* __restrict__ scm, u32* __restrict__ order){
  __shared__ float ss[6000];
  __shared__ u32 tp[1025];
  int t=threadIdx.x;
  for(int i=t;i<6000;i+=1024) ss[i]=scm[i];
  __syncthreads();
  int e0=t*6, e1=e0+6; if(e1>6000) e1=6000; if(e0>6000) e0=6000;
  u32 c=0;
  for(int e=e0;e<e1;e++) c+=(ss[e]!=-INFINITY);
  tp[t]=c;
  __syncthreads();
  if(t==0){
    u32 run=0;
    for(int i=0;i<1024;i++){ u32 cc=tp[i]; tp[i]=run; run+=cc; }
    tp[1024]=run;
  }
  __syncthreads();
  u32 V=tp[1024];
  u32 pv=tp[t];
  for(int e=e0;e<e1;e++){
    float se=ss[e];
    if(se!=-INFINITY){
      u32 r=0;
      for(int j=0;j<6000;j++){
        float sj=ss[j];
        r+=(sj>se)||((sj==se)&&(j<e));
      }
      order[r]=(u32)e;
      pv++;
    } else {
      order[V+(u32)e-pv]=(u32)e;
    }
  }
}

__global__ void k_detprep(const u32* __restrict__ order, const float* __restrict__ scm,
                          const float* __restrict__ bxb, float* __restrict__ dv,
                          float* __restrict__ dbx, float* __restrict__ out){
  int i=blockIdx.x*256+threadIdx.x;
  if(i>=6000) return;
  u32 g=order[i];
  float4 b=*(const float4*)(bxb+4*g);
  *(float4*)(dbx+4*i)=b;
  dv[i]=scm[g];
  *(float4*)(out+6000+4*i)=b;
  out[30000+i]=(float)(g%20u);
}

__global__ void k_dml(const u32* __restrict__ order, const float* __restrict__ m3, float* __restrict__ out){
  int idx=blockIdx.x*256+threadIdx.x;
  if(idx>=4704000) return;
  int e=idx/784, q=idx-e*784;
  u32 g=order[e];
  int r=(int)(g/20u), c=(int)(g%20u)+1;
  out[42000+idx]=m3[((size_t)r*21+c)*784+q];
}

extern "C" void kernel_launch(void* const* d_in, const int* in_sizes, int n_in,
                              void* d_out, int out_size, void* d_ws, size_t ws_size,
                              hipStream_t stream){
  (void)in_sizes; (void)n_in; (void)out_size;
  const float* features =(const float*)d_in[0];
  const float* rpn_logits=(const float*)d_in[1];
  const float* rpn_deltas=(const float*)d_in[2];
  const float* anchors  =(const float*)d_in[3];
  const float* W1=(const float*)d_in[4];
  const float* b1=(const float*)d_in[5];
  const float* Wc=(const float*)d_in[6];
  const float* bc=(const float*)d_in[7];
  const float* Wr=(const float*)d_in[8];
  const float* br=(const float*)d_in[9];
  const float* mw1=(const float*)d_in[10];
  const float* mb1=(const float*)d_in[11];
  const float* mwd=(const float*)d_in[12];
  const float* mbd=(const float*)d_in[13];
  const float* mwo=(const float*)d_in[14];
  const float* mbo=(const float*)d_in[15];
  float* out=(float*)d_out;

  char* base_=(char*)d_ws; size_t off=0;
  auto alloc=[&](size_t bytes)->void*{ off=(off+255)&~(size_t)255; void* p=base_+off; off+=bytes; return p; };
  u32* hist     =(u32*)alloc(65536*4);
  u32* binbase  =(u32*)alloc(65536*4);
  u32* cntbin   =(u32*)alloc(65536*4);
  u32* cnt      =(u32*)alloc(64);
  float* scores =(float*)alloc(144000*4);
  float* rois_all=(float*)alloc((size_t)144000*16);
  u64* bucket   =(u64*)alloc(8192*8);
  u32* selidx   =(u32*)alloc(6000*4);
  float* boxes6k=(float*)alloc(6000*16);
  u64* masksT   =(u64*)alloc((size_t)94*6016*8 + 1024);
  u64* masks    =(u64*)alloc((size_t)6000*94*8);
  float* rois300=(float*)alloc(300*16);
  u16* featT    =(u16*)alloc((size_t)16000*256*2);
  u16* roi7     =(u16*)alloc((size_t)300*49*256*2);
  u16* roi14    =(u16*)alloc((size_t)300*196*256*2);
  float* hbuf   =(float*)alloc((size_t)300*1024*4);
  float* hp     =(float*)alloc((size_t)224*300*64*4);
  float* WT     =(float*)alloc((size_t)105*1024*4);
  float* bxb    =(float*)alloc(6000*16);
  float* scm    =(float*)alloc(6000*4);
  u32* order    =(u32*)alloc(6000*4);
  float* dv     =(float*)alloc(6000*4);
  float* dbx    =(float*)alloc(6000*16);
  u16* x1       =(u16*)alloc((size_t)58800*128*2);
  u16* Bc1      =(u16*)alloc((size_t)2304*128*2);
  u16* B3t      =(u16*)alloc((size_t)4*128*128*2);
  float* m3     =(float*)alloc((size_t)58800*21*4);
  if(off > ws_size) return;

  hipMemsetAsync(hist,0,65536*4,stream);
  hipMemsetAsync(cntbin,0,65536*4,stream);
  hipMemsetAsync(cnt,0,64,stream);

  k_prep<<<1152,256,0,stream>>>(mw1,mwd,Wc,Wr,Bc1,B3t,WT);
  k_featT<<<dim3(250,8),256,0,stream>>>(features,featT);

  k_rpn<<<563,256,0,stream>>>(rpn_logits,rpn_deltas,anchors,scores,rois_all,hist);
  k_findbin<<<1,1024,0,stream>>>(hist,cnt,binbase);
  k_bucket<<<563,256,0,stream>>>(scores,cnt,binbase,cntbin,bucket);
  k_binsort<<<2048,256,0,stream>>>(cnt,binbase,hist,bucket,selidx);
  k_gather6k<<<24,256,0,stream>>>(selidx,rois_all,boxes6k);
  k_masks<1><<<2048,256,0,stream>>>(boxes6k,nullptr,6000,0.7f,masksT);
  k_scan1<<<1,512,0,stream>>>(masksT,boxes6k,rois300);

  k_roialign<7><<<3675,256,0,stream>>>(rois300,featT,roi7);
  k_roialign<14><<<14700,256,0,stream>>>(rois300,featT,roi14);

  k_fc1b<<<dim3(14,16),256,0,stream>>>(roi7,W1,hp);
  k_fc1red<<<1200,256,0,stream>>>(hp,b1,hbuf);
  k_conv1<<<919,256,0,stream>>>(roi14,Bc1,mb1,x1);
  k_conv2f<<<dim3(919,4),256,0,stream>>>(x1,B3t,mbd,mwo,mbo,m3);

  k_head<<<300,256,0,stream>>>(hbuf,WT,bc,br,rois300,bxb,scm,cnt);
  k_detsort<<<1,1024,0,stream>>>(scm,order);
  k_detprep<<<24,256,0,stream>>>(order,scm,bxb,dv,dbx,out);
  k_masks<0><<<512,256,0,stream>>>(dbx,cnt+1,0,0.5f,masks);
  k_scan2<<<1,64,0,stream>>>(masks,cnt,dv,out);
  k_dml<<<18375,256,0,stream>>>(order,m3,out);
}